// Round 7
// baseline (496.029 us; speedup 1.0000x reference)
//
#include <hip/hip_runtime.h>

typedef unsigned int u32;
typedef unsigned short u16;
typedef __attribute__((ext_vector_type(8))) _Float16 half8;
typedef __attribute__((ext_vector_type(4))) float f32x4;

#define ROWS  524288   // B*N
#define BROWS 4096     // B
#define EPS   1e-5f

// ---- stats: 64 shards of 1024 floats; block-coop summing ----
#define S_U   0
#define S_O1  8
#define S_A1  72
#define S_O12 136
#define S_A2  200
#define S_X   264
#define S_X1  328
#define S_X2  392
#define S_X3  456
#define SHARD 1024
#define NSH   64

#define XSTR 40   // LDS row stride in u16 (80 B: 16B-aligned for uint4 rows)

__device__ __forceinline__ float bl(u32 u){ return __uint_as_float(u << 16); }
__device__ __forceinline__ float bh(u32 u){ return __uint_as_float(u & 0xFFFF0000u); }
__device__ __forceinline__ float b2f(u16 h){ return __uint_as_float(((u32)h) << 16); }
__device__ __forceinline__ u16 f2b(float f){
  u32 u = __float_as_uint(f);
  return (u16)((u + 0x7FFFu + ((u >> 16) & 1u)) >> 16);   // RNE (bf16, output only)
}
__device__ __forceinline__ u16 f2h(float f){ _Float16 h = (_Float16)f; return __builtin_bit_cast(u16, h); }
__device__ __forceinline__ float h2f(u16 x){ return (float)__builtin_bit_cast(_Float16, x); }
__device__ __forceinline__ u32 pack2h(float a, float b){
  auto v = __builtin_amdgcn_cvt_pkrtz(a, b);
  return __builtin_bit_cast(u32, v);
}
__device__ __forceinline__ float lo16(u32 w){ return h2f((u16)(w & 0xFFFF)); }
__device__ __forceinline__ float hi16(u32 w){ return h2f((u16)(w >> 16)); }
__device__ __forceinline__ void unpk4(uint2 v, float* d){
  d[0]=lo16(v.x); d[1]=hi16(v.x); d[2]=lo16(v.y); d[3]=hi16(v.y);
}

// Padé(5,4) tanh: no v_exp; err <= ~1e-3, clamped to [-1,1].
__device__ __forceinline__ float tanh_fast(float x){
  float x2 = x*x;
  float num = fmaf(x2 + 105.0f, x2, 945.0f) * x;
  float den = fmaf(fmaf(x2, 15.0f, 420.0f), x2, 945.0f);
  float v = num * __builtin_amdgcn_rcpf(den);
  return fminf(1.0f, fmaxf(-1.0f, v));
}

// sum over the 16-lane subgroup
__device__ __forceinline__ float red16(float v){
  v += __shfl_xor(v, 1);
  v += __shfl_xor(v, 2);
  v += __shfl_xor(v, 4);
  v += __shfl_xor(v, 8);
  return v;
}

template<bool F32>
__device__ __forceinline__ float rdp(const void* p, int i){
  if (F32) return ((const float*)p)[i];
  return b2f(((const u16*)p)[i]);
}
template<bool F32>
__device__ __forceinline__ void load_u4(const void* u, int r, float* f){
  if (F32){
    float4 v = ((const float4*)u)[r];
    f[0]=v.x; f[1]=v.y; f[2]=v.z; f[3]=v.w;
  } else {
    uint2 v = ((const uint2*)u)[r];
    f[0]=bl(v.x); f[1]=bh(v.x); f[2]=bl(v.y); f[3]=bh(v.y);
  }
}

// ---- per-block inline dtype detect ----
__device__ __forceinline__ int detect_u(const u16* __restrict__ u, int tid, int* sf){
  if (tid < 64){
    int bad = 0;
#pragma unroll
    for (int i = 0; i < 4; ++i){
      int e = (u[tid*4 + i] >> 7) & 0xFF;
      bad += (e >= 0x90) ? 1 : 0;
    }
#pragma unroll
    for (int off = 32; off >= 1; off >>= 1) bad += __shfl_down(bad, off);
    if (tid == 0) *sf = (bad >= 4) ? 1 : 0;
  }
  __syncthreads();
  return *sf;
}

// ---------------- stats of u (4 cols) ----------------
template<bool F32>
__device__ __forceinline__ void stats_u_body(const void* __restrict__ u, float* __restrict__ S){
  int tid = blockIdx.x*blockDim.x + threadIdx.x;
  int nt  = gridDim.x*blockDim.x;
  float s[4]={0,0,0,0}, q[4]={0,0,0,0};
  for (int r = tid; r < ROWS; r += nt){
    float f[4]; load_u4<F32>(u, r, f);
#pragma unroll
    for (int k=0;k<4;++k){ s[k]+=f[k]; q[k]+=f[k]*f[k]; }
  }
#pragma unroll
  for (int off=32; off>=1; off>>=1){
#pragma unroll
    for (int k=0;k<4;++k){ s[k]+=__shfl_down(s[k],off); q[k]+=__shfl_down(q[k],off); }
  }
  if ((threadIdx.x & 63) == 0){
    float* Sh = S + (blockIdx.x & (NSH-1))*SHARD;
#pragma unroll
    for (int k=0;k<4;++k){ atomicAdd(&Sh[S_U+k], s[k]); atomicAdd(&Sh[S_U+4+k], q[k]); }
  }
}
__global__ __launch_bounds__(256) void k_stats_u(const void* __restrict__ u, float* __restrict__ S){
  __shared__ int sf;
  int isf = detect_u((const u16*)u, threadIdx.x, &sf);
  if (isf) stats_u_body<true>(u,S); else stats_u_body<false>(u,S);
}

// ---------------- parallel gather of u stats (256 threads) ----------------
__device__ __forceinline__ void prep_u_par(const float* __restrict__ S, float* mr,
                                           float* scr /*256 floats*/, int tid){
  {
    int col = tid & 3, isq = (tid >> 2) & 1, grp = tid >> 3;   // grp 0..31, 2 shards each
    float t = S[(grp*2+0)*SHARD + S_U + isq*4 + col]
            + S[(grp*2+1)*SHARD + S_U + isq*4 + col];
    scr[tid] = t;
  }
  __syncthreads();
  if (tid < 8){
    float t = 0.f;
#pragma unroll
    for (int g=0; g<32; ++g) t += scr[tid + 8*g];
    mr[tid] = t;                                   // raw sums: [0..3]=s, [4..7]=q
  }
  __syncthreads();
  if (tid < 4){
    float s = mr[tid], q = mr[4+tid];
    float m = s*(1.0f/ROWS);
    float var = q*(1.0f/ROWS) - m*m;
    mr[tid]   = m;
    mr[4+tid] = rsqrtf(var + EPS);
  }
  __syncthreads();
}
template<bool F32>
__device__ __forceinline__ void bn_u_l(const float* mr, const void* g, const void* b,
                                       const float* f, float* xn){
#pragma unroll
  for (int k=0;k<4;++k)
    xn[k] = (f[k]-mr[k])*(rdp<F32>(g,k)*mr[4+k]) + rdp<F32>(b,k);
}

// ---------------- fold1: u-BN folded into layer-1 weights ----------------
// o1[j] = tanh( sum_k f[k]*W1f[j*4+k] + c1[j] ), W1f = W1*sc, c1 = W1·sh
template<bool F32>
__device__ __forceinline__ void fold1_body(
    const void* pg1,const void* pb1,const void* pw1,
    const void* og1,const void* ob1,const void* ow1,
    const float* __restrict__ S, float* __restrict__ F1, float* scr, float* mr)
{
  int tid = threadIdx.x;
  prep_u_par(S, mr, scr, tid);
  if (tid < 64){
    int side = tid>>5, jj = tid&31;
    const void* W = side? ow1:pw1;
    const void* g = side? og1:pg1;
    const void* b = side? ob1:pb1;
    float c = 0.f;
#pragma unroll
    for (int k=0;k<4;++k){
      float sc = rdp<F32>(g,k)*mr[4+k];
      float sh = rdp<F32>(b,k) - mr[k]*sc;
      float wv = rdp<F32>(W, jj*4+k);
      F1[side*128 + jj*4 + k] = wv*sc;
      c += wv*sh;
    }
    F1[256 + side*32 + jj] = c;
  }
}
__global__ __launch_bounds__(256) void k_fold1(const void* __restrict__ u,
    const void* pg1,const void* pb1,const void* pw1,
    const void* og1,const void* ob1,const void* ow1,
    const float* __restrict__ S, float* __restrict__ F1){
  __shared__ float scr[256];
  __shared__ float mr[8];
  __shared__ int sf;
  int isf = detect_u((const u16*)u, threadIdx.x, &sf);
  if (isf) fold1_body<true >(pg1,pb1,pw1,og1,ob1,ow1,S,F1,scr,mr);
  else     fold1_body<false>(pg1,pb1,pw1,og1,ob1,ow1,S,F1,scr,mr);
}

// ---------------- foldw: BN(stats)+Linear folded -> global WT (f16 [64][32]) + CB ----------------
template<bool F32>
__device__ __forceinline__ void foldw_body(const float* __restrict__ S, int offA, int offB,
    const void* gA,const void* bA,const void* WA,
    const void* gB,const void* bB,const void* WB,
    u16* __restrict__ WTg, float* __restrict__ CBg, float* scr)
{
  int tid = threadIdx.x;
  {
    int pair = tid >> 2;            // 0..63 : L=pair>>5, k=pair&31
    int isq  = (tid >> 1) & 1;
    int half = tid & 1;
    int L = pair >> 5, k = pair & 31;
    int off = (L ? offB : offA) + isq*32 + k;
    float t = 0.f;
#pragma unroll
    for (int i=0;i<32;++i)
      t += S[(half*32 + i)*SHARD + off];
    scr[tid] = t;
  }
  __syncthreads();
  if (tid < 64){
    int L = tid>>5, k = tid&31;
    const void* g = L? gB:gA; const void* b = L? bB:bA;
    float s = scr[tid*4+0] + scr[tid*4+1];
    float q = scr[tid*4+2] + scr[tid*4+3];
    float m    = s*(1.0f/ROWS);
    float var  = q*(1.0f/ROWS) - m*m;
    float rstd = rsqrtf(var+EPS);
    float sc = rdp<F32>(g,k)*rstd;
    scr[256+tid] = sc;
    scr[320+tid] = rdp<F32>(b,k) - m*sc;
  }
  __syncthreads();
  if (tid < 64){
    int L = tid>>5, j = tid&31;
    const void* W = L? WB:WA;
    float c = 0.f;
#pragma unroll
    for (int k=0;k<32;++k){
      float Wv = rdp<F32>(W, j*32+k);
      WTg[(L*32+j)*32 + k] = f2h(Wv * scr[256 + ((L<<5)|k)]);
      c += Wv * scr[320 + ((L<<5)|k)];
    }
    CBg[L*32+j] = c;
  }
}
__global__ __launch_bounds__(256) void k_foldw(const void* __restrict__ u,
    const float* __restrict__ S, int offA, int offB,
    const void* gA,const void* bA,const void* WA,
    const void* gB,const void* bB,const void* WB,
    u16* __restrict__ WTg, float* __restrict__ CBg){
  __shared__ float scr[512];
  __shared__ int sf;
  int isf = detect_u((const u16*)u, threadIdx.x, &sf);
  if (isf) foldw_body<true >(S,offA,offB,gA,bA,WA,gB,bB,WB,WTg,CBg,scr);
  else     foldw_body<false>(S,offA,offB,gA,bA,WA,gB,bB,WB,WTg,CBg,scr);
}

// ---------------- chain with pre-folded f32 weights -> f16 LDS row (+ global) ----------------
template<bool STORE>
__device__ __forceinline__ void chain1f(const float* f, const float* __restrict__ Wf,
                                        const float* __restrict__ cf,
                                        u16* Xrow, u16* __restrict__ grow){
  u32 buf[16];
#pragma unroll
  for (int jp=0; jp<16; ++jp){
    int j0 = 2*jp, j1 = 2*jp+1;
    float a0 = tanh_fast(fmaf(f[0],Wf[j0*4+0], fmaf(f[1],Wf[j0*4+1],
                         fmaf(f[2],Wf[j0*4+2], fmaf(f[3],Wf[j0*4+3], cf[j0])))));
    float a1 = tanh_fast(fmaf(f[0],Wf[j1*4+0], fmaf(f[1],Wf[j1*4+1],
                         fmaf(f[2],Wf[j1*4+2], fmaf(f[3],Wf[j1*4+3], cf[j1])))));
    buf[jp] = pack2h(a0, a1);
  }
#pragma unroll
  for (int c=0;c<4;++c){
    uint4 v; v.x = buf[c*4]; v.y = buf[c*4+1]; v.z = buf[c*4+2]; v.w = buf[c*4+3];
    *(uint4*)&Xrow[c*8] = v;
    if (STORE) *(uint4*)&grow[c*8] = v;
  }
}

// ---------------- legacy chain (fallback path) ----------------
template<bool F32, bool STORE>
__device__ __forceinline__ void chain1_out(const float* xn, const void* W1, u16* Xrow,
                                           u16* __restrict__ grow){
  u32 buf[16];
#pragma unroll
  for (int jp=0; jp<16; ++jp){
    int j0 = 2*jp, j1 = 2*jp+1;
    float a0 = tanh_fast(xn[0]*rdp<F32>(W1,j0*4+0) + xn[1]*rdp<F32>(W1,j0*4+1)
                       + xn[2]*rdp<F32>(W1,j0*4+2) + xn[3]*rdp<F32>(W1,j0*4+3));
    float a1 = tanh_fast(xn[0]*rdp<F32>(W1,j1*4+0) + xn[1]*rdp<F32>(W1,j1*4+1)
                       + xn[2]*rdp<F32>(W1,j1*4+2) + xn[3]*rdp<F32>(W1,j1*4+3));
    buf[jp] = pack2h(a0, a1);
  }
#pragma unroll
  for (int c=0;c<4;++c){
    uint4 v; v.x = buf[c*4]; v.y = buf[c*4+1]; v.z = buf[c*4+2]; v.w = buf[c*4+3];
    *(uint4*)&Xrow[c*8] = v;
    if (STORE) *(uint4*)&grow[c*8] = v;
  }
}

// ---------------- in-block fold (fallback path only; LDS Wt) ----------------
template<bool F32>
__device__ __forceinline__ void fold2(const float* __restrict__ S, int offA, int offB,
    const void* gA, const void* bA, const void* WA,
    const void* gB, const void* bB, const void* WB,
    u16* Wt, float* Cb, float* scr /* 512 floats */)
{
  int tid = threadIdx.x;
  {
    int pair = tid >> 2;
    int isq  = (tid >> 1) & 1;
    int half = tid & 1;
    int L = pair >> 5, k = pair & 31;
    int off = (L ? offB : offA) + isq*32 + k;
    float t = 0.f;
#pragma unroll
    for (int i=0;i<32;++i)
      t += S[(half*32 + i)*SHARD + off];
    scr[tid] = t;
  }
  __syncthreads();
  if (tid < 64){
    int L = tid>>5, k = tid&31;
    const void* g = L? gB:gA; const void* b = L? bB:bA;
    float s = scr[tid*4+0] + scr[tid*4+1];
    float q = scr[tid*4+2] + scr[tid*4+3];
    float m    = s*(1.0f/ROWS);
    float var  = q*(1.0f/ROWS) - m*m;
    float rstd = rsqrtf(var+EPS);
    float sc = rdp<F32>(g,k)*rstd;
    scr[256+tid] = sc;
    scr[320+tid] = rdp<F32>(b,k) - m*sc;
  }
  __syncthreads();
  if (tid < 64){
    int L = tid>>5, j = tid&31;
    const void* W = L? WB:WA;
    float c = 0.f;
#pragma unroll
    for (int k=0;k<32;++k){
      float Wv = rdp<F32>(W, j*32+k);
      Wt[(L*32+j)*XSTR + k] = f2h(Wv * scr[256 + ((L<<5)|k)]);
      c += Wv * scr[320 + ((L<<5)|k)];
    }
    Cb[L*32+j] = c;
  }
  __syncthreads();
}

// ---------------- MFMA layer (LDS in/out) -- fallback pass3 ----------------
#define KIND_TANH          0
#define KIND_TANHRES       2
#define KIND_TANHRES_ATREG 3
template<int KIND>
__device__ __forceinline__ void mfma_layer(u16* X, const u16* Wt, const float* Cb,
                                           int L, int wv, int lane, const u32* at_pk)
{
  int ln15 = lane & 15, quad = lane >> 4;
  half8 w0 = *(const half8*)&Wt[(L*32 + ln15     )*XSTR + quad*8];
  half8 w1 = *(const half8*)&Wt[(L*32 + ln15 + 16)*XSTR + quad*8];
  float bias0[4], bias1[4];
#pragma unroll
  for (int reg=0;reg<4;++reg){
    bias0[reg] = Cb[L*32 +      quad*4 + reg];
    bias1[reg] = Cb[L*32 + 16 + quad*4 + reg];
  }
  int rowbase = wv*64;
#pragma unroll
  for (int Mt=0; Mt<4; ++Mt){
    int s = rowbase + Mt*16 + ln15;
    half8 bfr = *(const half8*)&X[s*XSTR + quad*8];
    f32x4 c0 = {0.f,0.f,0.f,0.f}, c1 = {0.f,0.f,0.f,0.f};
    c0 = __builtin_amdgcn_mfma_f32_16x16x32_f16(w0, bfr, c0, 0,0,0);
    c1 = __builtin_amdgcn_mfma_f32_16x16x32_f16(w1, bfr, c1, 0,0,0);
    float o0[4], o1v[4];
    if (KIND == KIND_TANHRES || KIND == KIND_TANHRES_ATREG){
      unpk4(*(const uint2*)&X[s*XSTR +      quad*4], o0);
      unpk4(*(const uint2*)&X[s*XSTR + 16 + quad*4], o1v);
    }
    float a0v[4], a1v[4];
    if (KIND == KIND_TANHRES_ATREG){
      a0v[0]=lo16(at_pk[Mt*4+0]); a0v[1]=hi16(at_pk[Mt*4+0]);
      a0v[2]=lo16(at_pk[Mt*4+1]); a0v[3]=hi16(at_pk[Mt*4+1]);
      a1v[0]=lo16(at_pk[Mt*4+2]); a1v[1]=hi16(at_pk[Mt*4+2]);
      a1v[2]=lo16(at_pk[Mt*4+3]); a1v[3]=hi16(at_pk[Mt*4+3]);
    }
    float v0[4], v1[4];
#pragma unroll
    for (int reg=0;reg<4;++reg){
      float a = c0[reg] + bias0[reg];
      float b = c1[reg] + bias1[reg];
      if (KIND == KIND_TANH){ a = tanh_fast(a); b = tanh_fast(b); }
      else if (KIND == KIND_TANHRES){ a = o0[reg] + tanh_fast(a); b = o1v[reg] + tanh_fast(b); }
      else if (KIND == KIND_TANHRES_ATREG){
        a = (o0[reg] + tanh_fast(a)) * a0v[reg];
        b = (o1v[reg] + tanh_fast(b)) * a1v[reg];
      }
      v0[reg] = a; v1[reg] = b;
    }
    uint2 w0o, w1o;
    w0o.x = pack2h(v0[0], v0[1]); w0o.y = pack2h(v0[2], v0[3]);
    w1o.x = pack2h(v1[0], v1[1]); w1o.y = pack2h(v1[2], v1[3]);
    *(uint2*)&X[s*XSTR +      quad*4] = w0o;
    *(uint2*)&X[s*XSTR + 16 + quad*4] = w1o;
  }
}

// cross-lane + cross-wave combine of per-lane col stats -> sharded atomics
__device__ __forceinline__ void emit_stats(float* s8, float* q8, int tid, int wv,
    int quad, int ln15, float* scr /*512*/, float* __restrict__ S, int offS, int shard)
{
#pragma unroll
  for (int i=0;i<8;++i){ s8[i]=red16(s8[i]); q8[i]=red16(q8[i]); }
  __syncthreads();
  if (ln15 == 0){
#pragma unroll
    for (int rg=0; rg<4; ++rg){
      int cl = quad*4+rg, ch = 16+quad*4+rg;
      scr[wv*64 + cl]       = s8[rg];
      scr[wv*64 + ch]       = s8[4+rg];
      scr[256 + wv*64 + cl] = q8[rg];
      scr[256 + wv*64 + ch] = q8[4+rg];
    }
  }
  __syncthreads();
  if (tid < 64){
    int j = tid & 31, isq = tid >> 5;
    const float* src = scr + isq*256;
    float tot = src[j] + src[64+j] + src[128+j] + src[192+j];
    atomicAdd(&S[shard*SHARD + offS + isq*32 + j], tot);
  }
}

// ---------------- column stats reducer (fallback) ----------------
__device__ __forceinline__ void reduce_f16(const u16* X, float* lds2,
                                           float* __restrict__ S, int offS, int shard)
{
  int tid = threadIdx.x;
  __syncthreads();
  {
    int j = tid & 31, seg = tid >> 5;
    float s=0.f, q=0.f;
#pragma unroll
    for (int q2=0;q2<32;++q2){
      float v = h2f(X[(seg*32+q2)*XSTR + j]);
      s += v; q = fmaf(v,v,q);
    }
    lds2[seg*32+j] = s;
    lds2[256 + seg*32+j] = q;
  }
  __syncthreads();
  if (tid < 64){
    int j = tid & 31; bool isq = tid >= 32;
    const float* src = lds2 + (isq?256:0);
    float tot=0.f;
#pragma unroll
    for (int sg=0;sg<8;++sg) tot += src[sg*32+j];
    atomicAdd(&S[shard*SHARD + offS + (isq?32:0) + j], tot);
  }
  __syncthreads();
}

__device__ __forceinline__ void reduce_f32(const float* Xs, float* lds2,
                                           float* __restrict__ S, int offS, int shard)
{
  int tid = threadIdx.x;
  __syncthreads();
  {
    int j = tid & 31, seg = tid >> 5;
    float s=0.f, q=0.f;
#pragma unroll
    for (int q2=0;q2<32;++q2){
      float v = Xs[(seg*32+q2)*33 + j];
      s += v; q = fmaf(v,v,q);
    }
    lds2[seg*32+j] = s;
    lds2[256 + seg*32+j] = q;
  }
  __syncthreads();
  if (tid < 64){
    int j = tid & 31; bool isq = tid >= 32;
    const float* src = lds2 + (isq?256:0);
    float tot=0.f;
#pragma unroll
    for (int sg=0;sg<8;++sg) tot += src[sg*32+j];
    atomicAdd(&S[shard*SHARD + offS + (isq?32:0) + j], tot);
  }
  __syncthreads();
}

// ---------------- pass1: 512 blocks x 4 groups; folded W1; reg-accum stats ----------------
template<bool F32, bool MAT>
__device__ __forceinline__ void pass1_body(const void* __restrict__ u,
    const float* __restrict__ F1, float* __restrict__ S,
    u16* __restrict__ o1g, u16* __restrict__ a1g,
    u16* X, float* lds2)
{
  int tid = threadIdx.x;
  int base = blockIdx.x*1024;
  int shard = blockIdx.x & (NSH-1);
  const float* W1p = F1;
  const float* W1o = F1 + 128;
  const float* c1p = F1 + 256;
  const float* c1o = F1 + 288;
  float f[4][4];
#pragma unroll
  for (int g=0; g<4; ++g) load_u4<F32>(u, base + g*256 + tid, f[g]);

  int j = tid & 31, seg = tid >> 5;
  float sa0=0.f, qa0=0.f, sa1=0.f, qa1=0.f;

#pragma unroll
  for (int g=0; g<4; ++g){
    int r = base + g*256 + tid;
    chain1f<MAT>(f[g], W1p, c1p, X + tid*XSTR, o1g + (size_t)r*32);
    __syncthreads();
#pragma unroll
    for (int q2=0;q2<32;++q2){
      float v = h2f(X[(seg*32+q2)*XSTR + j]);
      sa0 += v; qa0 = fmaf(v,v,qa0);
    }
    __syncthreads();
    chain1f<MAT>(f[g], W1o, c1o, X + tid*XSTR, a1g + (size_t)r*32);
    __syncthreads();
#pragma unroll
    for (int q2=0;q2<32;++q2){
      float v = h2f(X[(seg*32+q2)*XSTR + j]);
      sa1 += v; qa1 = fmaf(v,v,qa1);
    }
    __syncthreads();
  }
  // emit side 0 -> S_O1
  lds2[tid] = sa0; lds2[256+tid] = qa0;
  __syncthreads();
  if (tid < 64){
    int j2 = tid & 31; bool isq = tid >= 32;
    const float* src = lds2 + (isq?256:0);
    float tot=0.f;
#pragma unroll
    for (int sg=0;sg<8;++sg) tot += src[sg*32+j2];
    atomicAdd(&S[shard*SHARD + S_O1 + (isq?32:0) + j2], tot);
  }
  __syncthreads();
  // emit side 1 -> S_A1
  lds2[tid] = sa1; lds2[256+tid] = qa1;
  __syncthreads();
  if (tid < 64){
    int j2 = tid & 31; bool isq = tid >= 32;
    const float* src = lds2 + (isq?256:0);
    float tot=0.f;
#pragma unroll
    for (int sg=0;sg<8;++sg) tot += src[sg*32+j2];
    atomicAdd(&S[shard*SHARD + S_A1 + (isq?32:0) + j2], tot);
  }
}
template<bool MAT>
__global__ __launch_bounds__(256) void k_pass1(const void* __restrict__ u,
    const float* __restrict__ F1, float* __restrict__ S, u16* o1g, u16* a1g){
  __shared__ u16 X[256*XSTR];
  __shared__ float lds2[512];
  __shared__ int sf;
  int isf = detect_u((const u16*)u, threadIdx.x, &sf);
  if (isf) pass1_body<true ,MAT>(u,F1,S,o1g,a1g,X,lds2);
  else     pass1_body<false,MAT>(u,F1,S,o1g,a1g,X,lds2);
}

// ---------------- pass2m (MAT): pre-folded weights; 4 groups; in-place ----------------
// In-place safety: each group's loads are consumed (hw waitcnt) before that group's
// stores issue; distinct groups touch distinct rows; no cross-block aliasing.
__global__ __launch_bounds__(256, 3) void k_pass2m(
    const u16* __restrict__ WT, const float* __restrict__ CB,
    float* __restrict__ S, u16* __restrict__ o12g, u16* __restrict__ a2g)
{
  __shared__ float lds2[512];
  int tid = threadIdx.x;
  int wv = tid >> 6, lane = tid & 63;
  int ln15 = lane & 15, quad = lane >> 4;
  int gbase = blockIdx.x*1024;
  int shard = blockIdx.x & (NSH-1);
  int rowbase = wv*64;

  half8 w0o = *(const half8*)&WT[(ln15     )*32 + quad*8];
  half8 w1o = *(const half8*)&WT[(ln15 + 16)*32 + quad*8];
  half8 w0a = *(const half8*)&WT[(32 + ln15     )*32 + quad*8];
  half8 w1a = *(const half8*)&WT[(32 + ln15 + 16)*32 + quad*8];
  float b0o[4], b1o[4], b0a[4], b1a[4];
#pragma unroll
  for (int reg=0;reg<4;++reg){
    b0o[reg] = CB[     quad*4 + reg]; b1o[reg] = CB[16 + quad*4 + reg];
    b0a[reg] = CB[32 + quad*4 + reg]; b1a[reg] = CB[48 + quad*4 + reg];
  }

  float s8o[8], q8o[8], s8a[8], q8a[8];
#pragma unroll
  for (int i=0;i<8;++i){ s8o[i]=0.f; q8o[i]=0.f; s8a[i]=0.f; q8a[i]=0.f; }

#pragma unroll
  for (int g=0; g<4; ++g){
    half8 fo[4], fa[4]; uint2 r0[4], r1[4];
#pragma unroll
    for (int Mt=0; Mt<4; ++Mt){
      size_t R = (size_t)(gbase + g*256 + rowbase + Mt*16 + ln15);
      fo[Mt] = *(const half8*)&o12g[R*32 + quad*8];
      fa[Mt] = *(const half8*)&a2g [R*32 + quad*8];
      r0[Mt] = *(const uint2*)&o12g[R*32 +      quad*4];
      r1[Mt] = *(const uint2*)&o12g[R*32 + 16 + quad*4];
    }
#pragma unroll
    for (int Mt=0; Mt<4; ++Mt){
      size_t R = (size_t)(gbase + g*256 + rowbase + Mt*16 + ln15);
      {   // o-side: o12 = o1 + tanh(fold(o1))
        f32x4 c0 = {0.f,0.f,0.f,0.f}, c1 = {0.f,0.f,0.f,0.f};
        c0 = __builtin_amdgcn_mfma_f32_16x16x32_f16(w0o, fo[Mt], c0, 0,0,0);
        c1 = __builtin_amdgcn_mfma_f32_16x16x32_f16(w1o, fo[Mt], c1, 0,0,0);
        float o0[4], o1v[4];
        unpk4(r0[Mt], o0); unpk4(r1[Mt], o1v);
        float v0[4], v1[4];
#pragma unroll
        for (int reg=0;reg<4;++reg){
          float a = o0[reg]  + tanh_fast(c0[reg] + b0o[reg]);
          float b = o1v[reg] + tanh_fast(c1[reg] + b1o[reg]);
          s8o[reg]   += a; q8o[reg]   = fmaf(a,a,q8o[reg]);
          s8o[4+reg] += b; q8o[4+reg] = fmaf(b,b,q8o[4+reg]);
          v0[reg] = a; v1[reg] = b;
        }
        uint2 wA, wB;
        wA.x = pack2h(v0[0], v0[1]); wA.y = pack2h(v0[2], v0[3]);
        wB.x = pack2h(v1[0], v1[1]); wB.y = pack2h(v1[2], v1[3]);
        *(uint2*)&o12g[R*32 +      quad*4] = wA;
        *(uint2*)&o12g[R*32 + 16 + quad*4] = wB;
      }
      {   // a-side: a2 = tanh(fold(a1))
        f32x4 c0 = {0.f,0.f,0.f,0.f}, c1 = {0.f,0.f,0.f,0.f};
        c0 = __builtin_amdgcn_mfma_f32_16x16x32_f16(w0a, fa[Mt], c0, 0,0,0);
        c1 = __builtin_amdgcn_mfma_f32_16x16x32_f16(w1a, fa[Mt], c1, 0,0,0);
        float v0[4], v1[4];
#pragma unroll
        for (int reg=0;reg<4;++reg){
          float a = tanh_fast(c0[reg] + b0a[reg]);
          float b = tanh_fast(c1[reg] + b1a[reg]);
          s8a[reg]   += a; q8a[reg]   = fmaf(a,a,q8a[reg]);
          s8a[4+reg] += b; q8a[4+reg] = fmaf(b,b,q8a[4+reg]);
          v0[reg] = a; v1[reg] = b;
        }
        uint2 wA, wB;
        wA.x = pack2h(v0[0], v0[1]); wA.y = pack2h(v0[2], v0[3]);
        wB.x = pack2h(v1[0], v1[1]); wB.y = pack2h(v1[2], v1[3]);
        *(uint2*)&a2g[R*32 +      quad*4] = wA;
        *(uint2*)&a2g[R*32 + 16 + quad*4] = wB;
      }
    }
  }
  emit_stats(s8o, q8o, tid, wv, quad, ln15, lds2, S, S_O12, shard);
  emit_stats(s8a, q8a, tid, wv, quad, ln15, lds2, S, S_A2, shard);
}

// ---------------- pass3m (MAT): pre-folded weights; 4 groups ----------------
__global__ __launch_bounds__(256, 3) void k_pass3m(const int* __restrict__ mask,
    const u16* __restrict__ WT, const float* __restrict__ CB,
    const u16* __restrict__ o12g, const u16* __restrict__ a2g,
    float* __restrict__ x, float* __restrict__ S)
{
  __shared__ float lds2[512];
  int tid = threadIdx.x;
  int wv = tid >> 6, lane = tid & 63;
  int ln15 = lane & 15, quad = lane >> 4;
  int gbase = blockIdx.x*1024;
  int shard = blockIdx.x & (NSH-1);
  int rowbase = wv*64;

  // L0 = 3O (softmax, stats S_A2), L1 = 3P (pool, stats S_O12)
  half8 w0s = *(const half8*)&WT[(ln15     )*32 + quad*8];
  half8 w1s = *(const half8*)&WT[(ln15 + 16)*32 + quad*8];
  half8 w0p = *(const half8*)&WT[(32 + ln15     )*32 + quad*8];
  half8 w1p = *(const half8*)&WT[(32 + ln15 + 16)*32 + quad*8];
  float b0s[4], b1s[4], b0p[4], b1p[4];
#pragma unroll
  for (int reg=0;reg<4;++reg){
    b0s[reg] = CB[     quad*4 + reg]; b1s[reg] = CB[16 + quad*4 + reg];
    b0p[reg] = CB[32 + quad*4 + reg]; b1p[reg] = CB[48 + quad*4 + reg];
  }

#pragma unroll
  for (int g=0; g<4; ++g){
    half8 fa[4], fo[4]; uint2 r0[4], r1[4];
#pragma unroll
    for (int Mt=0; Mt<4; ++Mt){
      size_t R = (size_t)(gbase + g*256 + rowbase + Mt*16 + ln15);
      fa[Mt] = *(const half8*)&a2g [R*32 + quad*8];
      fo[Mt] = *(const half8*)&o12g[R*32 + quad*8];
      r0[Mt] = *(const uint2*)&o12g[R*32 +      quad*4];
      r1[Mt] = *(const uint2*)&o12g[R*32 + 16 + quad*4];
    }
    int maskbase = gbase + g*256 + wv*64;
    u32 at_pk[16];
#pragma unroll
    for (int Mt=0; Mt<4; ++Mt){     // logits + softmax
      f32x4 c0 = {0.f,0.f,0.f,0.f}, c1 = {0.f,0.f,0.f,0.f};
      c0 = __builtin_amdgcn_mfma_f32_16x16x32_f16(w0s, fa[Mt], c0, 0,0,0);
      c1 = __builtin_amdgcn_mfma_f32_16x16x32_f16(w1s, fa[Mt], c1, 0,0,0);
      float l0[4], l1[4];
#pragma unroll
      for (int reg=0;reg<4;++reg){ l0[reg] = c0[reg]+b0s[reg]; l1[reg] = c1[reg]+b1s[reg]; }
      float mx = l0[0];
#pragma unroll
      for (int reg=1;reg<4;++reg) mx = fmaxf(mx, l0[reg]);
#pragma unroll
      for (int reg=0;reg<4;++reg) mx = fmaxf(mx, l1[reg]);
      mx = fmaxf(mx, __shfl_xor(mx, 16));
      mx = fmaxf(mx, __shfl_xor(mx, 32));
      float sum = 0.f;
#pragma unroll
      for (int reg=0;reg<4;++reg){ l0[reg] = __expf(l0[reg]-mx); sum += l0[reg]; }
#pragma unroll
      for (int reg=0;reg<4;++reg){ l1[reg] = __expf(l1[reg]-mx); sum += l1[reg]; }
      sum += __shfl_xor(sum, 16);
      sum += __shfl_xor(sum, 32);
      float inv = __builtin_amdgcn_rcpf(sum);
      bool mz = (mask[maskbase + Mt*16 + ln15] == 0);
#pragma unroll
      for (int reg=0;reg<4;++reg){
        l0[reg] *= inv; l1[reg] *= inv;
        if (mz){ l0[reg] = -__builtin_inff(); l1[reg] = -__builtin_inff(); }
      }
      at_pk[Mt*4+0] = pack2h(l0[0], l0[1]);
      at_pk[Mt*4+1] = pack2h(l0[2], l0[3]);
      at_pk[Mt*4+2] = pack2h(l1[0], l1[1]);
      at_pk[Mt*4+3] = pack2h(l1[2], l1[3]);
    }
    float ps[8];
#pragma unroll
    for (int i=0;i<8;++i) ps[i]=0.f;
#pragma unroll
    for (int Mt=0; Mt<4; ++Mt){     // (o3 + residual) * attn, pooled
      f32x4 c0 = {0.f,0.f,0.f,0.f}, c1 = {0.f,0.f,0.f,0.f};
      c0 = __builtin_amdgcn_mfma_f32_16x16x32_f16(w0p, fo[Mt], c0, 0,0,0);
      c1 = __builtin_amdgcn_mfma_f32_16x16x32_f16(w1p, fo[Mt], c1, 0,0,0);
      float o0[4], o1v[4];
      unpk4(r0[Mt], o0); unpk4(r1[Mt], o1v);
      float a0v[4], a1v[4];
      a0v[0]=lo16(at_pk[Mt*4+0]); a0v[1]=hi16(at_pk[Mt*4+0]);
      a0v[2]=lo16(at_pk[Mt*4+1]); a0v[3]=hi16(at_pk[Mt*4+1]);
      a1v[0]=lo16(at_pk[Mt*4+2]); a1v[1]=hi16(at_pk[Mt*4+2]);
      a1v[2]=lo16(at_pk[Mt*4+3]); a1v[3]=hi16(at_pk[Mt*4+3]);
#pragma unroll
      for (int reg=0;reg<4;++reg){
        float a = (o0[reg]  + tanh_fast(c0[reg]+b0p[reg])) * a0v[reg];
        float b = (o1v[reg] + tanh_fast(c1[reg]+b1p[reg])) * a1v[reg];
        ps[reg]   += a;
        ps[4+reg] += b;
      }
    }
#pragma unroll
    for (int i=0;i<8;++i) ps[i]=red16(ps[i]);
    __syncthreads();
    if (ln15 == 0){
#pragma unroll
      for (int rg=0; rg<4; ++rg){
        lds2[wv*32 + quad*4+rg]    = ps[rg];
        lds2[wv*32 + 16+quad*4+rg] = ps[4+rg];
      }
    }
    __syncthreads();
    if (tid < 64){
      int half = tid >> 5, j = tid & 31;
      float v = lds2[half*64 + j] + lds2[half*64 + 32 + j];
      x[((size_t)blockIdx.x*8 + g*2 + half)*32 + j] = v;
      float* Sh = S + shard*SHARD;
      atomicAdd(&Sh[S_X+j], v);
      atomicAdd(&Sh[S_X+32+j], v*v);
    }
  }
}

// ---------------- pass2 (fallback, recompute, no stores; grid 2048) ----------------
template<int KIND>
__device__ __forceinline__ void mfma_stat_l(const u16* X, const u16* Wt, const float* Cb,
    int L, int wv, int lane, float* s8, float* q8)
{
  int ln15 = lane & 15, quad = lane >> 4;
  half8 w0 = *(const half8*)&Wt[(L*32 + ln15     )*XSTR + quad*8];
  half8 w1 = *(const half8*)&Wt[(L*32 + ln15 + 16)*XSTR + quad*8];
  float bias0[4], bias1[4];
#pragma unroll
  for (int reg=0;reg<4;++reg){
    bias0[reg] = Cb[L*32 +      quad*4 + reg];
    bias1[reg] = Cb[L*32 + 16 + quad*4 + reg];
  }
#pragma unroll
  for (int i=0;i<8;++i){ s8[i]=0.f; q8[i]=0.f; }
  int rowbase = wv*64;
#pragma unroll
  for (int Mt=0; Mt<4; ++Mt){
    int s = rowbase + Mt*16 + ln15;
    half8 bfr = *(const half8*)&X[s*XSTR + quad*8];
    f32x4 c0 = {0.f,0.f,0.f,0.f}, c1 = {0.f,0.f,0.f,0.f};
    c0 = __builtin_amdgcn_mfma_f32_16x16x32_f16(w0, bfr, c0, 0,0,0);
    c1 = __builtin_amdgcn_mfma_f32_16x16x32_f16(w1, bfr, c1, 0,0,0);
    float o0[4], o1v[4];
    if (KIND == KIND_TANHRES){
      unpk4(*(const uint2*)&X[s*XSTR +      quad*4], o0);
      unpk4(*(const uint2*)&X[s*XSTR + 16 + quad*4], o1v);
    }
#pragma unroll
    for (int reg=0;reg<4;++reg){
      float a = c0[reg] + bias0[reg];
      float b = c1[reg] + bias1[reg];
      if (KIND == KIND_TANH){ a = tanh_fast(a); b = tanh_fast(b); }
      else { a = o0[reg] + tanh_fast(a); b = o1v[reg] + tanh_fast(b); }
      s8[reg]   += a; q8[reg]   = fmaf(a,a,q8[reg]);
      s8[4+reg] += b; q8[4+reg] = fmaf(b,b,q8[4+reg]);
    }
  }
}
template<bool F32>
__device__ __forceinline__ void pass2_body(const void* __restrict__ u,
    const void* pg1, const void* pb1, const void* pw1,
    const void* og1, const void* ob1, const void* ow1,
    const void* pg2, const void* pb2, const void* pw2,
    const void* og2, const void* ob2, const void* ow2,
    float* __restrict__ S,
    u16* X, u16* Wt, float* Cb, float* lds2, float* mr)
{
  int tid = threadIdx.x;
  int wv = tid >> 6, lane = tid & 63;
  int ln15 = lane & 15, quad = lane >> 4;
  int r = blockIdx.x*256 + tid;
  int shard = blockIdx.x & (NSH-1);
  float f[4], xn[4];
  load_u4<F32>(u,r,f);
  prep_u_par(S, mr, lds2, tid);
  fold2<F32>(S, S_O1, S_A1, pg2,pb2,pw2, og2,ob2,ow2, Wt, Cb, lds2);

  float s8[8], q8[8];

  bn_u_l<F32>(mr, pg1, pb1, f, xn);
  chain1_out<F32,false>(xn, pw1, X + tid*XSTR, 0);
  __syncthreads();
  mfma_stat_l<KIND_TANHRES>(X, Wt, Cb, 0, wv, lane, s8, q8);
  emit_stats(s8, q8, tid, wv, quad, ln15, lds2, S, S_O12, shard);

  bn_u_l<F32>(mr, og1, ob1, f, xn);
  chain1_out<F32,false>(xn, ow1, X + tid*XSTR, 0);
  __syncthreads();
  mfma_stat_l<KIND_TANH>(X, Wt, Cb, 1, wv, lane, s8, q8);
  emit_stats(s8, q8, tid, wv, quad, ln15, lds2, S, S_A2, shard);
}
__global__ __launch_bounds__(256) void k_pass2(const void* __restrict__ u,
    const void* pg1, const void* pb1, const void* pw1,
    const void* og1, const void* ob1, const void* ow1,
    const void* pg2, const void* pb2, const void* pw2,
    const void* og2, const void* ob2, const void* ow2,
    float* __restrict__ S){
  __shared__ u16 X[256*XSTR];
  __shared__ u16 Wt[2*32*XSTR];
  __shared__ float Cb[64];
  __shared__ float lds2[512];
  __shared__ float mr[8];
  __shared__ int sf;
  int isf = detect_u((const u16*)u, threadIdx.x, &sf);
  if (isf) pass2_body<true >(u,pg1,pb1,pw1,og1,ob1,ow1,pg2,pb2,pw2,og2,ob2,ow2,S,X,Wt,Cb,lds2,mr);
  else     pass2_body<false>(u,pg1,pb1,pw1,og1,ob1,ow1,pg2,pb2,pw2,og2,ob2,ow2,S,X,Wt,Cb,lds2,mr);
}

// ---------------- pass3 (fallback, full recompute; grid 2048) ----------------
template<bool F32>
__device__ __forceinline__ void fold4(const float* __restrict__ S,
    int off0,int off1,int off2,int off3,
    const void* g0,const void* b0,const void* W0,
    const void* g1,const void* b1,const void* W1,
    const void* g2,const void* b2,const void* W2,
    const void* g3,const void* b3,const void* W3,
    u16* Wt, float* Cb, float* scr)
{
  int tid = threadIdx.x;
  __shared__ float scr2[256];
  if (tid < 128){
    int L = tid>>5, k = tid&31;
    const void* g = (L==0)?g0:(L==1)?g1:(L==2)?g2:g3;
    const void* b = (L==0)?b0:(L==1)?b1:(L==2)?b2:b3;
    int off = (L==0)?off0:(L==1)?off1:(L==2)?off2:off3;
    float s=0.f, q=0.f;
#pragma unroll
    for (int sh=0; sh<NSH; ++sh){
      s += S[sh*SHARD + off + k];
      q += S[sh*SHARD + off + 32 + k];
    }
    float m    = s*(1.0f/ROWS);
    float var  = q*(1.0f/ROWS) - m*m;
    float rstd = rsqrtf(var+EPS);
    float sc = rdp<F32>(g,k)*rstd;
    scr[tid]  = sc;
    scr2[tid] = rdp<F32>(b,k) - m*sc;
  }
  __syncthreads();
  if (tid < 128){
    int L = tid>>5, j = tid&31;
    const void* W = (L==0)?W0:(L==1)?W1:(L==2)?W2:W3;
    float c = 0.f;
#pragma unroll
    for (int k=0;k<32;++k){
      float Wv = rdp<F32>(W, j*32+k);
      Wt[(L*32+j)*XSTR + k] = f2h(Wv * scr[(L<<5)|k]);
      c += Wv * scr2[(L<<5)|k];
    }
    Cb[L*32+j] = c;
  }
  __syncthreads();
}

template<bool F32>
__device__ __forceinline__ void pass3_body(const void* __restrict__ u, const int* __restrict__ mask,
    const void* pg1, const void* pb1, const void* pw1,
    const void* og1, const void* ob1, const void* ow1,
    const void* pg2, const void* pb2, const void* pw2,
    const void* og2, const void* ob2, const void* ow2,
    const void* pg3, const void* pb3, const void* pw3,
    const void* og3, const void* ob3, const void* ow3,
    float* __restrict__ x, float* __restrict__ S,
    u16* X, u16* Wt, float* Cb, float* red2, float* mr)
{
  int tid = threadIdx.x;
  int wv = tid >> 6, lane = tid & 63;
  int r = blockIdx.x*256 + tid;
  float f[4], xn[4];
  load_u4<F32>(u,r,f);
  prep_u_par(S, mr, red2, tid);
  fold4<F32>(S, S_A1, S_A2, S_O1, S_O12,
             og2,ob2,ow2, og3,ob3,ow3, pg2,pb2,pw2, pg3,pb3,pw3,
             Wt, Cb, red2);

  u32 at_pk[16];
  int maskbase = blockIdx.x*256 + wv*64;

  bn_u_l<F32>(mr, og1, ob1, f, xn);
  chain1_out<F32,false>(xn, ow1, X + tid*XSTR, 0);
  mfma_layer<KIND_TANH>(X, Wt, Cb, 0, wv, lane, 0);
  {
    int ln15 = lane & 15, quad = lane >> 4;
    half8 w0 = *(const half8*)&Wt[(1*32 + ln15     )*XSTR + quad*8];
    half8 w1 = *(const half8*)&Wt[(1*32 + ln15 + 16)*XSTR + quad*8];
    float bias0[4], bias1[4];
#pragma unroll
    for (int reg=0;reg<4;++reg){
      bias0[reg] = Cb[32 +      quad*4 + reg];
      bias1[reg] = Cb[32 + 16 + quad*4 + reg];
    }
    int rowbase = wv*64;
#pragma unroll
    for (int Mt=0; Mt<4; ++Mt){
      int s = rowbase + Mt*16 + ln15;
      half8 bfr = *(const half8*)&X[s*XSTR + quad*8];
      f32x4 c0 = {0.f,0.f,0.f,0.f}, c1 = {0.f,0.f,0.f,0.f};
      c0 = __builtin_amdgcn_mfma_f32_16x16x32_f16(w0, bfr, c0, 0,0,0);
      c1 = __builtin_amdgcn_mfma_f32_16x16x32_f16(w1, bfr, c1, 0,0,0);
      float l0[4], l1[4];
#pragma unroll
      for (int reg=0;reg<4;++reg){ l0[reg] = c0[reg]+bias0[reg]; l1[reg] = c1[reg]+bias1[reg]; }
      float mx = l0[0];
#pragma unroll
      for (int reg=1;reg<4;++reg) mx = fmaxf(mx, l0[reg]);
#pragma unroll
      for (int reg=0;reg<4;++reg) mx = fmaxf(mx, l1[reg]);
      mx = fmaxf(mx, __shfl_xor(mx, 16));
      mx = fmaxf(mx, __shfl_xor(mx, 32));
      float sum = 0.f;
#pragma unroll
      for (int reg=0;reg<4;++reg){ l0[reg] = __expf(l0[reg]-mx); sum += l0[reg]; }
#pragma unroll
      for (int reg=0;reg<4;++reg){ l1[reg] = __expf(l1[reg]-mx); sum += l1[reg]; }
      sum += __shfl_xor(sum, 16);
      sum += __shfl_xor(sum, 32);
      float inv = __builtin_amdgcn_rcpf(sum);
      bool mz = (mask[maskbase + Mt*16 + ln15] == 0);
#pragma unroll
      for (int reg=0;reg<4;++reg){
        l0[reg] *= inv; l1[reg] *= inv;
        if (mz){ l0[reg] = -__builtin_inff(); l1[reg] = -__builtin_inff(); }
      }
      at_pk[Mt*4+0] = pack2h(l0[0], l0[1]);
      at_pk[Mt*4+1] = pack2h(l0[2], l0[3]);
      at_pk[Mt*4+2] = pack2h(l1[0], l1[1]);
      at_pk[Mt*4+3] = pack2h(l1[2], l1[3]);
    }
  }

  bn_u_l<F32>(mr, pg1, pb1, f, xn);
  chain1_out<F32,false>(xn, pw1, X + tid*XSTR, 0);
  mfma_layer<KIND_TANHRES   >(X, Wt, Cb, 2, wv, lane, 0);
  mfma_layer<KIND_TANHRES_ATREG>(X, Wt, Cb, 3, wv, lane, at_pk);

  __syncthreads();
  {
    int jj = tid & 31, cgrp = (tid >> 5) & 3, half = tid >> 7;
    float s2 = 0.f;
#pragma unroll
    for (int q2=0;q2<32;++q2) s2 += h2f(X[(half*128 + cgrp*32 + q2)*XSTR + jj]);
    red2[tid] = s2;
  }
  __syncthreads();
  if (tid < 64){
    int half = tid >> 5, j = tid & 31;
    float v = red2[half*128+j] + red2[half*128+32+j] + red2[half*128+64+j] + red2[half*128+96+j];
    x[(blockIdx.x*2 + half)*32 + j] = v;
    float* Sh = S + (blockIdx.x & (NSH-1))*SHARD;
    atomicAdd(&Sh[S_X+j], v);
    atomicAdd(&Sh[S_X+32+j], v*v);
  }
}
__global__ __launch_bounds__(256) void k_pass3(const void* __restrict__ u, const int* __restrict__ mask,
    const void* pg1, const void* pb1, const void* pw1,
    const void* og1, const void* ob1, const void* ow1,
    const void* pg2, const void* pb2, const void* pw2,
    const void* og2, const void* ob2, const void* ow2,
    const void* pg3, const void* pb3, const void* pw3,
    const void* og3, const void* ob3, const void* ow3,
    float* __restrict__ x, float* __restrict__ S){
  __shared__ u16 X [256*XSTR];
  __shared__ u16 Wt[4*32*XSTR];
  __shared__ float Cb[128];
  __shared__ float red2[256];
  __shared__ float mr[8];
  __shared__ int sf;
  int isf = detect_u((const u16*)u, threadIdx.x, &sf);
  if (isf) pass3_body<true >(u,mask,pg1,pb1,pw1,og1,ob1,ow1,pg2,pb2,pw2,og2,ob2,ow2,
                             pg3,pb3,pw3,og3,ob3,ow3,x,S,X,Wt,Cb,red2,mr);
  else     pass3_body<false>(u,mask,pg1,pb1,pw1,og1,ob1,ow1,pg2,pb2,pw2,og2,ob2,ow2,
                             pg3,pb3,pw3,og3,ob3,ow3,x,S,X,Wt,Cb,red2,mr);
}

// ---------------- theta chain: 4 small stream-ordered kernels ----------------
template<int NSH_IN>
__device__ __forceinline__ void theta_gather(const float* __restrict__ S, int off,
                                             float* scratch, float* lds2, int tid){
  int col = tid & 63, grp = tid >> 6;
  float t = 0.f;
#pragma unroll
  for (int i = 0; i < NSH_IN/4; ++i)
    t += S[(grp + i*4)*SHARD + off + col];
  scratch[tid] = t;
  __syncthreads();
  if (tid < 64)
    scratch[tid] = scratch[tid] + scratch[64+tid] + scratch[128+tid] + scratch[192+tid];
  __syncthreads();
  if (tid < 32){
    float m   = scratch[tid]*(1.0f/BROWS);
    float var = scratch[32+tid]*(1.0f/BROWS) - m*m;
    lds2[tid]    = m;
    lds2[32+tid] = rsqrtf(var + EPS);
  }
  __syncthreads();
}

template<bool F32>
__device__ __forceinline__ void theta_layer(float* v, const float* lds2,
    const void* g, const void* b, const void* W){
  float xn[32];
#pragma unroll
  for (int k=0;k<32;++k)
    xn[k] = (v[k] - lds2[k]) * (rdp<F32>(g,k)*lds2[32+k]) + rdp<F32>(b,k);
#pragma unroll
  for (int j=0;j<32;++j){
    float acc = 0.f;
#pragma unroll
    for (int k=0;k<32;++k) acc = fmaf(rdp<F32>(W, j*32+k), xn[k], acc);
    v[j] = tanh_fast(acc);
  }
}

template<bool F32, int NSH_IN>
__device__ __forceinline__ void theta_L_body(const float* __restrict__ xin,
    float* __restrict__ xout, float* __restrict__ S, int off_in, int off_out,
    const void* g, const void* b, const void* W, float* lds, float* lds2)
{
  int tid = threadIdx.x, blk = blockIdx.x;
  int r = blk*256 + tid;
  float v[32];
  {
    const float4* xr = (const float4*)&xin[(size_t)r*32];
#pragma unroll
    for (int k=0;k<8;++k){ float4 t = xr[k]; v[4*k]=t.x; v[4*k+1]=t.y; v[4*k+2]=t.z; v[4*k+3]=t.w; }
  }
  theta_gather<NSH_IN>(S, off_in, lds, lds2, tid);
  theta_layer<F32>(v, lds2, g, b, W);
  {
    float4* xw = (float4*)&xout[(size_t)r*32];
#pragma unroll
    for (int k=0;k<8;++k){ float4 t; t.x=v[4*k]; t.y=v[4*k+1]; t.z=v[4*k+2]; t.w=v[4*k+3]; xw[k]=t; }
  }
  float* Xp = lds + tid*33;
#pragma unroll
  for (int j=0;j<32;++j) Xp[j] = v[j];
  reduce_f32(lds, lds2, S, off_out, blk);   // shard = blk: zero contention
}
template<int NSH_IN>
__global__ __launch_bounds__(256) void k_theta_L(const void* __restrict__ u,
    const float* __restrict__ xin, float* __restrict__ xout,
    float* __restrict__ S, int off_in, int off_out,
    const void* g, const void* b, const void* W){
  __shared__ float lds[256*33];
  __shared__ float lds2[512];
  __shared__ int sf;
  int isf = detect_u((const u16*)u, threadIdx.x, &sf);
  if (isf) theta_L_body<true , NSH_IN>(xin, xout, S, off_in, off_out, g, b, W, lds, lds2);
  else     theta_L_body<false, NSH_IN>(xin, xout, S, off_in, off_out, g, b, W, lds, lds2);
}

template<bool F32>
__device__ __forceinline__ void theta_fin_body(const float* __restrict__ xin,
    float* __restrict__ S,
    const void* g4, const void* b4, const void* w4, const void* bb4,
    void* out, float* lds, float* lds2)
{
  int tid = threadIdx.x, blk = blockIdx.x;
  int r = blk*256 + tid;
  const float4* xr = (const float4*)&xin[(size_t)r*32];
  float4 t0 = xr[0], t1 = xr[1], t2 = xr[2], t3 = xr[3];
  float4 t4 = xr[4], t5 = xr[5], t6 = xr[6], t7 = xr[7];
  theta_gather<16>(S, S_X3, lds, lds2, tid);
  float vv[32];
  vv[0]=t0.x; vv[1]=t0.y; vv[2]=t0.z; vv[3]=t0.w;
  vv[4]=t1.x; vv[5]=t1.y; vv[6]=t1.z; vv[7]=t1.w;
  vv[8]=t2.x; vv[9]=t2.y; vv[10]=t2.z; vv[11]=t2.w;
  vv[12]=t3.x; vv[13]=t3.y; vv[14]=t3.z; vv[15]=t3.w;
  vv[16]=t4.x; vv[17]=t4.y; vv[18]=t4.z; vv[19]=t4.w;
  vv[20]=t5.x; vv[21]=t5.y; vv[22]=t5.z; vv[23]=t5.w;
  vv[24]=t6.x; vv[25]=t6.y; vv[26]=t6.z; vv[27]=t6.w;
  vv[28]=t7.x; vv[29]=t7.y; vv[30]=t7.z; vv[31]=t7.w;
  float acc = rdp<F32>(bb4, 0);
#pragma unroll
  for (int k=0;k<32;++k){
    float xnv = (vv[k] - lds2[k]) * (rdp<F32>(g4,k)*lds2[32+k]) + rdp<F32>(b4,k);
    acc = fmaf(rdp<F32>(w4,k), xnv, acc);
  }
  if (F32) ((float*)out)[r] = acc;
  else     ((u16*)out)[r]  = f2b(acc);
}
__global__ __launch_bounds__(256) void k_theta_fin(const void* __restrict__ u,
    const float* __restrict__ xin, float* __restrict__ S,
    const void* g4, const void* b4, const void* w4, const void* bb4,
    void* out){
  __shared__ float lds[256];
  __shared__ float lds2[512];
  __shared__ int sf;
  int isf = detect_u((const u16*)u, threadIdx.x, &sf);
  if (isf) theta_fin_body<true >(xin, S, g4, b4, w4, bb4, out, lds, lds2);
  else     theta_fin_body<false>(xin, S, g4, b4, w4, bb4, out, lds, lds2);
}

extern "C" void kernel_launch(void* const* d_in, const int* in_sizes, int n_in,
                              void* d_out, int out_size, void* d_ws, size_t ws_size,
                              hipStream_t stream)
{
  const void* u    = d_in[0];
  const int*  mask = (const int*)d_in[1];
  const void *pg1=d_in[2],  *pb1=d_in[3],  *pw1=d_in[4];
  const void *pg2=d_in[5],  *pb2=d_in[6],  *pw2=d_in[7];
  const void *pg3=d_in[8],  *pb3=d_in[9],  *pw3=d_in[10];
  const void *og1=d_in[11], *ob1=d_in[12], *ow1=d_in[13];
  const void *og2=d_in[14], *ob2=d_in[15], *ow2=d_in[16];
  const void *og3=d_in[17], *ob3=d_in[18], *ow3=d_in[19];
  const void *tg1=d_in[20], *tb1=d_in[21], *tw1=d_in[22];
  const void *tg2=d_in[23], *tb2=d_in[24], *tw2=d_in[25];
  const void *tg3=d_in[26], *tb3=d_in[27], *tw3=d_in[28];
  const void *tg4=d_in[29], *tb4=d_in[30], *tw4=d_in[31], *tbb4=d_in[32];

  char* ws = (char*)d_ws;
  float* S    = (float*)(ws + 4096);         // 64 shards x 1024 floats = 256 KB
  float* x    = (float*)(ws + 524288);       // 4096*32 f32 (512 KB)
  float* xb   = (float*)(ws + 1048576);      // ping-pong buffer (512 KB)
  float* F1   = (float*)(ws + 1572864);      // folded layer-1 weights (1.3 KB)
  u16*   WT2  = (u16*)  (ws + 1572864 + 4096);
  float* CB2  = (float*)(ws + 1572864 + 8192);
  u16*   WT3  = (u16*)  (ws + 1572864 + 12288);
  float* CB3  = (float*)(ws + 1572864 + 16384);

  const size_t MB = 1024*1024;
  u16* o12g = (u16*)(ws + 8*MB);             // 32 MB: o1 then (in-place) o12
  u16* a2g  = (u16*)(ws + 40*MB);            // 32 MB: a1 then (in-place) a2
  bool MAT = ws_size >= 73*MB;               // constant per process -> graph-safe

  (void)hipMemsetAsync(ws, 0, 4096 + NSH*SHARD*4, stream);  // zero sharded stats
  k_stats_u<<<1024, 256, 0, stream>>>(u, S);
  k_fold1<<<1, 256, 0, stream>>>(u, pg1,pb1,pw1, og1,ob1,ow1, S, F1);
  if (MAT){
    k_pass1<true ><<<512, 256, 0, stream>>>(u, F1, S, o12g, a2g);
    k_foldw<<<1, 256, 0, stream>>>(u, S, S_O1, S_A1, pg2,pb2,pw2, og2,ob2,ow2, WT2, CB2);
    k_pass2m<<<512, 256, 0, stream>>>(WT2, CB2, S, o12g, a2g);
    k_foldw<<<1, 256, 0, stream>>>(u, S, S_A2, S_O12, og3,ob3,ow3, pg3,pb3,pw3, WT3, CB3);
    k_pass3m<<<512, 256, 0, stream>>>(mask, WT3, CB3, o12g, a2g, x, S);
  } else {
    k_pass1<false><<<512, 256, 0, stream>>>(u, F1, S, o12g, a2g);
    k_pass2<<<2048, 256, 0, stream>>>(u, pg1,pb1,pw1, og1,ob1,ow1,
                                      pg2,pb2,pw2, og2,ob2,ow2, S);
    k_pass3<<<2048, 256, 0, stream>>>(u, mask, pg1,pb1,pw1, og1,ob1,ow1,
                                      pg2,pb2,pw2, og2,ob2,ow2,
                                      pg3,pb3,pw3, og3,ob3,ow3, x, S);
  }
  // theta chain: 4 tiny kernels; stream order supplies the global sync
  k_theta_L<64><<<16, 256, 0, stream>>>(u, x,  xb, S, S_X,  S_X1, tg1, tb1, tw1);
  k_theta_L<16><<<16, 256, 0, stream>>>(u, xb, x,  S, S_X1, S_X2, tg2, tb2, tw2);
  k_theta_L<16><<<16, 256, 0, stream>>>(u, x,  xb, S, S_X2, S_X3, tg3, tb3, tw3);
  k_theta_fin<<<16, 256, 0, stream>>>(u, xb, S, tg4, tb4, tw4, tbb4, d_out);
}

// Round 8
// 409.519 us; speedup vs baseline: 1.2112x; 1.2112x over previous
//
#include <hip/hip_runtime.h>

typedef unsigned int u32;
typedef unsigned short u16;
typedef __attribute__((ext_vector_type(8))) _Float16 half8;
typedef __attribute__((ext_vector_type(4))) float f32x4;

#define ROWS  524288   // B*N
#define BROWS 4096     // B
#define EPS   1e-5f

// ---- stats: 64 shards of 1024 floats; block-coop summing ----
#define S_U   0
#define S_O1  8
#define S_A1  72
#define S_O12 136
#define S_A2  200
#define S_X   264
#define S_X1  328
#define S_X2  392
#define S_X3  456
#define SHARD 1024
#define NSH   64

#define XSTR 40   // LDS row stride in u16 (80 B: 16B-aligned for uint4 rows)

__device__ __forceinline__ float bl(u32 u){ return __uint_as_float(u << 16); }
__device__ __forceinline__ float bh(u32 u){ return __uint_as_float(u & 0xFFFF0000u); }
__device__ __forceinline__ float b2f(u16 h){ return __uint_as_float(((u32)h) << 16); }
__device__ __forceinline__ u16 f2b(float f){
  u32 u = __float_as_uint(f);
  return (u16)((u + 0x7FFFu + ((u >> 16) & 1u)) >> 16);   // RNE (bf16, output only)
}
__device__ __forceinline__ u16 f2h(float f){ _Float16 h = (_Float16)f; return __builtin_bit_cast(u16, h); }
__device__ __forceinline__ float h2f(u16 x){ return (float)__builtin_bit_cast(_Float16, x); }
__device__ __forceinline__ u32 pack2h(float a, float b){
  auto v = __builtin_amdgcn_cvt_pkrtz(a, b);
  return __builtin_bit_cast(u32, v);
}
__device__ __forceinline__ float lo16(u32 w){ return h2f((u16)(w & 0xFFFF)); }
__device__ __forceinline__ float hi16(u32 w){ return h2f((u16)(w >> 16)); }
__device__ __forceinline__ void unpk4(uint2 v, float* d){
  d[0]=lo16(v.x); d[1]=hi16(v.x); d[2]=lo16(v.y); d[3]=hi16(v.y);
}

// Padé(5,4) tanh: no v_exp; err <= ~1e-3, clamped to [-1,1].
__device__ __forceinline__ float tanh_fast(float x){
  float x2 = x*x;
  float num = fmaf(x2 + 105.0f, x2, 945.0f) * x;
  float den = fmaf(fmaf(x2, 15.0f, 420.0f), x2, 945.0f);
  float v = num * __builtin_amdgcn_rcpf(den);
  return fminf(1.0f, fmaxf(-1.0f, v));
}

// sum over the 16-lane subgroup
__device__ __forceinline__ float red16(float v){
  v += __shfl_xor(v, 1);
  v += __shfl_xor(v, 2);
  v += __shfl_xor(v, 4);
  v += __shfl_xor(v, 8);
  return v;
}

template<bool F32>
__device__ __forceinline__ float rdp(const void* p, int i){
  if (F32) return ((const float*)p)[i];
  return b2f(((const u16*)p)[i]);
}
template<bool F32>
__device__ __forceinline__ void load_u4(const void* u, int r, float* f){
  if (F32){
    float4 v = ((const float4*)u)[r];
    f[0]=v.x; f[1]=v.y; f[2]=v.z; f[3]=v.w;
  } else {
    uint2 v = ((const uint2*)u)[r];
    f[0]=bl(v.x); f[1]=bh(v.x); f[2]=bl(v.y); f[3]=bh(v.y);
  }
}

// ---- per-block inline dtype detect ----
__device__ __forceinline__ int detect_u(const u16* __restrict__ u, int tid, int* sf){
  if (tid < 64){
    int bad = 0;
#pragma unroll
    for (int i = 0; i < 4; ++i){
      int e = (u[tid*4 + i] >> 7) & 0xFF;
      bad += (e >= 0x90) ? 1 : 0;
    }
#pragma unroll
    for (int off = 32; off >= 1; off >>= 1) bad += __shfl_down(bad, off);
    if (tid == 0) *sf = (bad >= 4) ? 1 : 0;
  }
  __syncthreads();
  return *sf;
}

// ---------------- stats of u (4 cols) ----------------
template<bool F32>
__device__ __forceinline__ void stats_u_body(const void* __restrict__ u, float* __restrict__ S){
  int tid = blockIdx.x*blockDim.x + threadIdx.x;
  int nt  = gridDim.x*blockDim.x;
  float s[4]={0,0,0,0}, q[4]={0,0,0,0};
  for (int r = tid; r < ROWS; r += nt){
    float f[4]; load_u4<F32>(u, r, f);
#pragma unroll
    for (int k=0;k<4;++k){ s[k]+=f[k]; q[k]+=f[k]*f[k]; }
  }
#pragma unroll
  for (int off=32; off>=1; off>>=1){
#pragma unroll
    for (int k=0;k<4;++k){ s[k]+=__shfl_down(s[k],off); q[k]+=__shfl_down(q[k],off); }
  }
  if ((threadIdx.x & 63) == 0){
    float* Sh = S + (blockIdx.x & (NSH-1))*SHARD;
#pragma unroll
    for (int k=0;k<4;++k){ atomicAdd(&Sh[S_U+k], s[k]); atomicAdd(&Sh[S_U+4+k], q[k]); }
  }
}
__global__ __launch_bounds__(256) void k_stats_u(const void* __restrict__ u, float* __restrict__ S){
  __shared__ int sf;
  int isf = detect_u((const u16*)u, threadIdx.x, &sf);
  if (isf) stats_u_body<true>(u,S); else stats_u_body<false>(u,S);
}

// ---------------- parallel gather of u stats (256 threads) ----------------
__device__ __forceinline__ void prep_u_par(const float* __restrict__ S, float* mr,
                                           float* scr /*256 floats*/, int tid){
  {
    int col = tid & 3, isq = (tid >> 2) & 1, grp = tid >> 3;   // grp 0..31, 2 shards each
    float t = S[(grp*2+0)*SHARD + S_U + isq*4 + col]
            + S[(grp*2+1)*SHARD + S_U + isq*4 + col];
    scr[tid] = t;
  }
  __syncthreads();
  if (tid < 8){
    float t = 0.f;
#pragma unroll
    for (int g=0; g<32; ++g) t += scr[tid + 8*g];
    mr[tid] = t;                                   // raw sums: [0..3]=s, [4..7]=q
  }
  __syncthreads();
  if (tid < 4){
    float s = mr[tid], q = mr[4+tid];
    float m = s*(1.0f/ROWS);
    float var = q*(1.0f/ROWS) - m*m;
    mr[tid]   = m;
    mr[4+tid] = rsqrtf(var + EPS);
  }
  __syncthreads();
}
template<bool F32>
__device__ __forceinline__ void bn_u_l(const float* mr, const void* g, const void* b,
                                       const float* f, float* xn){
#pragma unroll
  for (int k=0;k<4;++k)
    xn[k] = (f[k]-mr[k])*(rdp<F32>(g,k)*mr[4+k]) + rdp<F32>(b,k);
}

// ---------------- fold1: u-BN folded into layer-1 weights ----------------
template<bool F32>
__device__ __forceinline__ void fold1_body(
    const void* pg1,const void* pb1,const void* pw1,
    const void* og1,const void* ob1,const void* ow1,
    const float* __restrict__ S, float* __restrict__ F1, float* scr, float* mr)
{
  int tid = threadIdx.x;
  prep_u_par(S, mr, scr, tid);
  if (tid < 64){
    int side = tid>>5, jj = tid&31;
    const void* W = side? ow1:pw1;
    const void* g = side? og1:pg1;
    const void* b = side? ob1:pb1;
    float c = 0.f;
#pragma unroll
    for (int k=0;k<4;++k){
      float sc = rdp<F32>(g,k)*mr[4+k];
      float sh = rdp<F32>(b,k) - mr[k]*sc;
      float wv = rdp<F32>(W, jj*4+k);
      F1[side*128 + jj*4 + k] = wv*sc;
      c += wv*sh;
    }
    F1[256 + side*32 + jj] = c;
  }
}
__global__ __launch_bounds__(256) void k_fold1(const void* __restrict__ u,
    const void* pg1,const void* pb1,const void* pw1,
    const void* og1,const void* ob1,const void* ow1,
    const float* __restrict__ S, float* __restrict__ F1){
  __shared__ float scr[256];
  __shared__ float mr[8];
  __shared__ int sf;
  int isf = detect_u((const u16*)u, threadIdx.x, &sf);
  if (isf) fold1_body<true >(pg1,pb1,pw1,og1,ob1,ow1,S,F1,scr,mr);
  else     fold1_body<false>(pg1,pb1,pw1,og1,ob1,ow1,S,F1,scr,mr);
}

// ---------------- foldw: BN(stats)+Linear folded -> global WT (f16 [64][32]) + CB ----------------
template<bool F32>
__device__ __forceinline__ void foldw_body(const float* __restrict__ S, int offA, int offB,
    const void* gA,const void* bA,const void* WA,
    const void* gB,const void* bB,const void* WB,
    u16* __restrict__ WTg, float* __restrict__ CBg, float* scr)
{
  int tid = threadIdx.x;
  {
    int pair = tid >> 2;            // 0..63 : L=pair>>5, k=pair&31
    int isq  = (tid >> 1) & 1;
    int half = tid & 1;
    int L = pair >> 5, k = pair & 31;
    int off = (L ? offB : offA) + isq*32 + k;
    float t = 0.f;
#pragma unroll
    for (int i=0;i<32;++i)
      t += S[(half*32 + i)*SHARD + off];
    scr[tid] = t;
  }
  __syncthreads();
  if (tid < 64){
    int L = tid>>5, k = tid&31;
    const void* g = L? gB:gA; const void* b = L? bB:bA;
    float s = scr[tid*4+0] + scr[tid*4+1];
    float q = scr[tid*4+2] + scr[tid*4+3];
    float m    = s*(1.0f/ROWS);
    float var  = q*(1.0f/ROWS) - m*m;
    float rstd = rsqrtf(var+EPS);
    float sc = rdp<F32>(g,k)*rstd;
    scr[256+tid] = sc;
    scr[320+tid] = rdp<F32>(b,k) - m*sc;
  }
  __syncthreads();
  if (tid < 64){
    int L = tid>>5, j = tid&31;
    const void* W = L? WB:WA;
    float c = 0.f;
#pragma unroll
    for (int k=0;k<32;++k){
      float Wv = rdp<F32>(W, j*32+k);
      WTg[(L*32+j)*32 + k] = f2h(Wv * scr[256 + ((L<<5)|k)]);
      c += Wv * scr[320 + ((L<<5)|k)];
    }
    CBg[L*32+j] = c;
  }
}
__global__ __launch_bounds__(256) void k_foldw(const void* __restrict__ u,
    const float* __restrict__ S, int offA, int offB,
    const void* gA,const void* bA,const void* WA,
    const void* gB,const void* bB,const void* WB,
    u16* __restrict__ WTg, float* __restrict__ CBg){
  __shared__ float scr[512];
  __shared__ int sf;
  int isf = detect_u((const u16*)u, threadIdx.x, &sf);
  if (isf) foldw_body<true >(S,offA,offB,gA,bA,WA,gB,bB,WB,WTg,CBg,scr);
  else     foldw_body<false>(S,offA,offB,gA,bA,WA,gB,bB,WB,WTg,CBg,scr);
}

// ---------------- chain with pre-folded f32 weights -> f16 LDS row (+ global) ----------------
template<bool STORE>
__device__ __forceinline__ void chain1f(const float* f, const float* __restrict__ Wf,
                                        const float* __restrict__ cf,
                                        u16* Xrow, u16* __restrict__ grow){
  u32 buf[16];
#pragma unroll
  for (int jp=0; jp<16; ++jp){
    int j0 = 2*jp, j1 = 2*jp+1;
    float a0 = tanh_fast(fmaf(f[0],Wf[j0*4+0], fmaf(f[1],Wf[j0*4+1],
                         fmaf(f[2],Wf[j0*4+2], fmaf(f[3],Wf[j0*4+3], cf[j0])))));
    float a1 = tanh_fast(fmaf(f[0],Wf[j1*4+0], fmaf(f[1],Wf[j1*4+1],
                         fmaf(f[2],Wf[j1*4+2], fmaf(f[3],Wf[j1*4+3], cf[j1])))));
    buf[jp] = pack2h(a0, a1);
  }
#pragma unroll
  for (int c=0;c<4;++c){
    uint4 v; v.x = buf[c*4]; v.y = buf[c*4+1]; v.z = buf[c*4+2]; v.w = buf[c*4+3];
    *(uint4*)&Xrow[c*8] = v;
    if (STORE) *(uint4*)&grow[c*8] = v;
  }
}

// ---------------- legacy chain (fallback path) ----------------
template<bool F32, bool STORE>
__device__ __forceinline__ void chain1_out(const float* xn, const void* W1, u16* Xrow,
                                           u16* __restrict__ grow){
  u32 buf[16];
#pragma unroll
  for (int jp=0; jp<16; ++jp){
    int j0 = 2*jp, j1 = 2*jp+1;
    float a0 = tanh_fast(xn[0]*rdp<F32>(W1,j0*4+0) + xn[1]*rdp<F32>(W1,j0*4+1)
                       + xn[2]*rdp<F32>(W1,j0*4+2) + xn[3]*rdp<F32>(W1,j0*4+3));
    float a1 = tanh_fast(xn[0]*rdp<F32>(W1,j1*4+0) + xn[1]*rdp<F32>(W1,j1*4+1)
                       + xn[2]*rdp<F32>(W1,j1*4+2) + xn[3]*rdp<F32>(W1,j1*4+3));
    buf[jp] = pack2h(a0, a1);
  }
#pragma unroll
  for (int c=0;c<4;++c){
    uint4 v; v.x = buf[c*4]; v.y = buf[c*4+1]; v.z = buf[c*4+2]; v.w = buf[c*4+3];
    *(uint4*)&Xrow[c*8] = v;
    if (STORE) *(uint4*)&grow[c*8] = v;
  }
}

// ---------------- in-block fold (fallback path only; LDS Wt) ----------------
template<bool F32>
__device__ __forceinline__ void fold2(const float* __restrict__ S, int offA, int offB,
    const void* gA, const void* bA, const void* WA,
    const void* gB, const void* bB, const void* WB,
    u16* Wt, float* Cb, float* scr /* 512 floats */)
{
  int tid = threadIdx.x;
  {
    int pair = tid >> 2;
    int isq  = (tid >> 1) & 1;
    int half = tid & 1;
    int L = pair >> 5, k = pair & 31;
    int off = (L ? offB : offA) + isq*32 + k;
    float t = 0.f;
#pragma unroll
    for (int i=0;i<32;++i)
      t += S[(half*32 + i)*SHARD + off];
    scr[tid] = t;
  }
  __syncthreads();
  if (tid < 64){
    int L = tid>>5, k = tid&31;
    const void* g = L? gB:gA; const void* b = L? bB:bA;
    float s = scr[tid*4+0] + scr[tid*4+1];
    float q = scr[tid*4+2] + scr[tid*4+3];
    float m    = s*(1.0f/ROWS);
    float var  = q*(1.0f/ROWS) - m*m;
    float rstd = rsqrtf(var+EPS);
    float sc = rdp<F32>(g,k)*rstd;
    scr[256+tid] = sc;
    scr[320+tid] = rdp<F32>(b,k) - m*sc;
  }
  __syncthreads();
  if (tid < 64){
    int L = tid>>5, j = tid&31;
    const void* W = L? WB:WA;
    float c = 0.f;
#pragma unroll
    for (int k=0;k<32;++k){
      float Wv = rdp<F32>(W, j*32+k);
      Wt[(L*32+j)*XSTR + k] = f2h(Wv * scr[256 + ((L<<5)|k)]);
      c += Wv * scr[320 + ((L<<5)|k)];
    }
    Cb[L*32+j] = c;
  }
  __syncthreads();
}

// ---------------- MFMA layer (LDS in/out) -- fallback pass3 ----------------
#define KIND_TANH          0
#define KIND_TANHRES       2
#define KIND_TANHRES_ATREG 3
template<int KIND>
__device__ __forceinline__ void mfma_layer(u16* X, const u16* Wt, const float* Cb,
                                           int L, int wv, int lane, const u32* at_pk)
{
  int ln15 = lane & 15, quad = lane >> 4;
  half8 w0 = *(const half8*)&Wt[(L*32 + ln15     )*XSTR + quad*8];
  half8 w1 = *(const half8*)&Wt[(L*32 + ln15 + 16)*XSTR + quad*8];
  float bias0[4], bias1[4];
#pragma unroll
  for (int reg=0;reg<4;++reg){
    bias0[reg] = Cb[L*32 +      quad*4 + reg];
    bias1[reg] = Cb[L*32 + 16 + quad*4 + reg];
  }
  int rowbase = wv*64;
#pragma unroll
  for (int Mt=0; Mt<4; ++Mt){
    int s = rowbase + Mt*16 + ln15;
    half8 bfr = *(const half8*)&X[s*XSTR + quad*8];
    f32x4 c0 = {0.f,0.f,0.f,0.f}, c1 = {0.f,0.f,0.f,0.f};
    c0 = __builtin_amdgcn_mfma_f32_16x16x32_f16(w0, bfr, c0, 0,0,0);
    c1 = __builtin_amdgcn_mfma_f32_16x16x32_f16(w1, bfr, c1, 0,0,0);
    float o0[4], o1v[4];
    if (KIND == KIND_TANHRES || KIND == KIND_TANHRES_ATREG){
      unpk4(*(const uint2*)&X[s*XSTR +      quad*4], o0);
      unpk4(*(const uint2*)&X[s*XSTR + 16 + quad*4], o1v);
    }
    float a0v[4], a1v[4];
    if (KIND == KIND_TANHRES_ATREG){
      a0v[0]=lo16(at_pk[Mt*4+0]); a0v[1]=hi16(at_pk[Mt*4+0]);
      a0v[2]=lo16(at_pk[Mt*4+1]); a0v[3]=hi16(at_pk[Mt*4+1]);
      a1v[0]=lo16(at_pk[Mt*4+2]); a1v[1]=hi16(at_pk[Mt*4+2]);
      a1v[2]=lo16(at_pk[Mt*4+3]); a1v[3]=hi16(at_pk[Mt*4+3]);
    }
    float v0[4], v1[4];
#pragma unroll
    for (int reg=0;reg<4;++reg){
      float a = c0[reg] + bias0[reg];
      float b = c1[reg] + bias1[reg];
      if (KIND == KIND_TANH){ a = tanh_fast(a); b = tanh_fast(b); }
      else if (KIND == KIND_TANHRES){ a = o0[reg] + tanh_fast(a); b = o1v[reg] + tanh_fast(b); }
      else if (KIND == KIND_TANHRES_ATREG){
        a = (o0[reg] + tanh_fast(a)) * a0v[reg];
        b = (o1v[reg] + tanh_fast(b)) * a1v[reg];
      }
      v0[reg] = a; v1[reg] = b;
    }
    uint2 w0o, w1o;
    w0o.x = pack2h(v0[0], v0[1]); w0o.y = pack2h(v0[2], v0[3]);
    w1o.x = pack2h(v1[0], v1[1]); w1o.y = pack2h(v1[2], v1[3]);
    *(uint2*)&X[s*XSTR +      quad*4] = w0o;
    *(uint2*)&X[s*XSTR + 16 + quad*4] = w1o;
  }
}

// cross-lane + cross-wave combine of per-lane col stats -> sharded atomics
__device__ __forceinline__ void emit_stats(float* s8, float* q8, int tid, int wv,
    int quad, int ln15, float* scr /*512*/, float* __restrict__ S, int offS, int shard)
{
#pragma unroll
  for (int i=0;i<8;++i){ s8[i]=red16(s8[i]); q8[i]=red16(q8[i]); }
  __syncthreads();
  if (ln15 == 0){
#pragma unroll
    for (int rg=0; rg<4; ++rg){
      int cl = quad*4+rg, ch = 16+quad*4+rg;
      scr[wv*64 + cl]       = s8[rg];
      scr[wv*64 + ch]       = s8[4+rg];
      scr[256 + wv*64 + cl] = q8[rg];
      scr[256 + wv*64 + ch] = q8[4+rg];
    }
  }
  __syncthreads();
  if (tid < 64){
    int j = tid & 31, isq = tid >> 5;
    const float* src = scr + isq*256;
    float tot = src[j] + src[64+j] + src[128+j] + src[192+j];
    atomicAdd(&S[shard*SHARD + offS + isq*32 + j], tot);
  }
}

// ---------------- column stats reducers ----------------
__device__ __forceinline__ void reduce_f16(const u16* X, float* lds2,
                                           float* __restrict__ S, int offS, int shard)
{
  int tid = threadIdx.x;
  __syncthreads();
  {
    int j = tid & 31, seg = tid >> 5;
    float s=0.f, q=0.f;
#pragma unroll
    for (int q2=0;q2<32;++q2){
      float v = h2f(X[(seg*32+q2)*XSTR + j]);
      s += v; q = fmaf(v,v,q);
    }
    lds2[seg*32+j] = s;
    lds2[256 + seg*32+j] = q;
  }
  __syncthreads();
  if (tid < 64){
    int j = tid & 31; bool isq = tid >= 32;
    const float* src = lds2 + (isq?256:0);
    float tot=0.f;
#pragma unroll
    for (int sg=0;sg<8;++sg) tot += src[sg*32+j];
    atomicAdd(&S[shard*SHARD + offS + (isq?32:0) + j], tot);
  }
  __syncthreads();
}

__device__ __forceinline__ void reduce_f32(const float* Xs, float* lds2,
                                           float* __restrict__ S, int offS, int shard)
{
  int tid = threadIdx.x;
  __syncthreads();
  {
    int j = tid & 31, seg = tid >> 5;
    float s=0.f, q=0.f;
#pragma unroll
    for (int q2=0;q2<32;++q2){
      float v = Xs[(seg*32+q2)*33 + j];
      s += v; q = fmaf(v,v,q);
    }
    lds2[seg*32+j] = s;
    lds2[256 + seg*32+j] = q;
  }
  __syncthreads();
  if (tid < 64){
    int j = tid & 31; bool isq = tid >= 32;
    const float* src = lds2 + (isq?256:0);
    float tot=0.f;
#pragma unroll
    for (int sg=0;sg<8;++sg) tot += src[sg*32+j];
    atomicAdd(&S[shard*SHARD + offS + (isq?32:0) + j], tot);
  }
  __syncthreads();
}

// ---------------- pass1: 512 blocks x 4 groups; folded W1; reg-accum stats ----------------
template<bool F32, bool MAT>
__device__ __forceinline__ void pass1_body(const void* __restrict__ u,
    const float* __restrict__ F1, float* __restrict__ S,
    u16* __restrict__ o1g, u16* __restrict__ a1g,
    u16* X, float* lds2)
{
  int tid = threadIdx.x;
  int base = blockIdx.x*1024;
  int shard = blockIdx.x & (NSH-1);
  const float* W1p = F1;
  const float* W1o = F1 + 128;
  const float* c1p = F1 + 256;
  const float* c1o = F1 + 288;
  float f[4][4];
#pragma unroll
  for (int g=0; g<4; ++g) load_u4<F32>(u, base + g*256 + tid, f[g]);

  int j = tid & 31, seg = tid >> 5;
  float sa0=0.f, qa0=0.f, sa1=0.f, qa1=0.f;

#pragma unroll
  for (int g=0; g<4; ++g){
    int r = base + g*256 + tid;
    chain1f<MAT>(f[g], W1p, c1p, X + tid*XSTR, o1g + (size_t)r*32);
    __syncthreads();
#pragma unroll
    for (int q2=0;q2<32;++q2){
      float v = h2f(X[(seg*32+q2)*XSTR + j]);
      sa0 += v; qa0 = fmaf(v,v,qa0);
    }
    __syncthreads();
    chain1f<MAT>(f[g], W1o, c1o, X + tid*XSTR, a1g + (size_t)r*32);
    __syncthreads();
#pragma unroll
    for (int q2=0;q2<32;++q2){
      float v = h2f(X[(seg*32+q2)*XSTR + j]);
      sa1 += v; qa1 = fmaf(v,v,qa1);
    }
    __syncthreads();
  }
  // emit side 0 -> S_O1
  lds2[tid] = sa0; lds2[256+tid] = qa0;
  __syncthreads();
  if (tid < 64){
    int j2 = tid & 31; bool isq = tid >= 32;
    const float* src = lds2 + (isq?256:0);
    float tot=0.f;
#pragma unroll
    for (int sg=0;sg<8;++sg) tot += src[sg*32+j2];
    atomicAdd(&S[shard*SHARD + S_O1 + (isq?32:0) + j2], tot);
  }
  __syncthreads();
  // emit side 1 -> S_A1
  lds2[tid] = sa1; lds2[256+tid] = qa1;
  __syncthreads();
  if (tid < 64){
    int j2 = tid & 31; bool isq = tid >= 32;
    const float* src = lds2 + (isq?256:0);
    float tot=0.f;
#pragma unroll
    for (int sg=0;sg<8;++sg) tot += src[sg*32+j2];
    atomicAdd(&S[shard*SHARD + S_A1 + (isq?32:0) + j2], tot);
  }
}
template<bool MAT>
__global__ __launch_bounds__(256) void k_pass1(const void* __restrict__ u,
    const float* __restrict__ F1, float* __restrict__ S, u16* o1g, u16* a1g){
  __shared__ u16 X[256*XSTR];
  __shared__ float lds2[512];
  __shared__ int sf;
  int isf = detect_u((const u16*)u, threadIdx.x, &sf);
  if (isf) pass1_body<true ,MAT>(u,F1,S,o1g,a1g,X,lds2);
  else     pass1_body<false,MAT>(u,F1,S,o1g,a1g,X,lds2);
}

// ---------------- pass2m (MAT): round-6 dbuf structure + pre-folded global weights ----------------
// The __syncthreads() after the prefetch+weight loads is ESSENTIAL: it (a) drains
// vmcnt so the in-place stores can't pass the loads, and (b) phase-locks the 4 waves
// so stores to adjacent rows land in a tight window and merge to full lines in L2
// (round-7 removal of this barrier doubled FETCH+WRITE traffic).
#define P2_LOADM(BUF, G, MT) { \
  size_t R = (size_t)(gbase + (G)*256 + rowbase + (MT)*16 + ln15); \
  fo[BUF][MT] = *(const half8*)&o12g[R*32 + quad*8]; \
  fa[BUF][MT] = *(const half8*)&a2g [R*32 + quad*8]; }
#define P2_LOAD(BUF, G) P2_LOADM(BUF,G,0) P2_LOADM(BUF,G,1) P2_LOADM(BUF,G,2) P2_LOADM(BUF,G,3)

__global__ __launch_bounds__(256) void k_pass2m(
    const u16* __restrict__ WT, const float* __restrict__ CB,
    float* __restrict__ S, u16* __restrict__ o12g, u16* __restrict__ a2g)
{
  __shared__ float lds2[512];
  int tid = threadIdx.x;
  int wv = tid >> 6, lane = tid & 63;
  int ln15 = lane & 15, quad = lane >> 4;
  int gbase = blockIdx.x*1024;
  int shard = blockIdx.x & (NSH-1);
  int rowbase = wv*64;

  half8 fo[2][4], fa[2][4];
  P2_LOAD(0, 0)                       // group-0 operands prefetched

  half8 w0o = *(const half8*)&WT[(ln15     )*32 + quad*8];
  half8 w1o = *(const half8*)&WT[(ln15 + 16)*32 + quad*8];
  half8 w0a = *(const half8*)&WT[(32 + ln15     )*32 + quad*8];
  half8 w1a = *(const half8*)&WT[(32 + ln15 + 16)*32 + quad*8];
  float b0o[4], b1o[4], b0a[4], b1a[4];
#pragma unroll
  for (int reg=0;reg<4;++reg){
    b0o[reg] = CB[     quad*4 + reg]; b1o[reg] = CB[16 + quad*4 + reg];
    b0a[reg] = CB[32 + quad*4 + reg]; b1a[reg] = CB[48 + quad*4 + reg];
  }

  __syncthreads();   // vmcnt drain + wave phase-lock (see comment above)

  float s8o[8], q8o[8], s8a[8], q8a[8];
#pragma unroll
  for (int i=0;i<8;++i){ s8o[i]=0.f; q8o[i]=0.f; s8a[i]=0.f; q8a[i]=0.f; }

#pragma unroll
  for (int g=0; g<4; ++g){
    const int buf = g & 1;
    if (g < 3){ P2_LOAD(buf^1, g+1) }          // prefetch next group's operands
    uint2 r0[4], r1[4];                        // residuals for this group
#pragma unroll
    for (int Mt=0; Mt<4; ++Mt){
      size_t R = (size_t)(gbase + g*256 + rowbase + Mt*16 + ln15);
      r0[Mt] = *(const uint2*)&o12g[R*32 +      quad*4];
      r1[Mt] = *(const uint2*)&o12g[R*32 + 16 + quad*4];
    }
#pragma unroll
    for (int Mt=0; Mt<4; ++Mt){
      size_t R = (size_t)(gbase + g*256 + rowbase + Mt*16 + ln15);
      {   // o-side: o12 = o1 + tanh(fold(o1))
        f32x4 c0 = {0.f,0.f,0.f,0.f}, c1 = {0.f,0.f,0.f,0.f};
        c0 = __builtin_amdgcn_mfma_f32_16x16x32_f16(w0o, fo[buf][Mt], c0, 0,0,0);
        c1 = __builtin_amdgcn_mfma_f32_16x16x32_f16(w1o, fo[buf][Mt], c1, 0,0,0);
        float o0[4], o1v[4];
        unpk4(r0[Mt], o0); unpk4(r1[Mt], o1v);
        float v0[4], v1[4];
#pragma unroll
        for (int reg=0;reg<4;++reg){
          float a = o0[reg]  + tanh_fast(c0[reg] + b0o[reg]);
          float b = o1v[reg] + tanh_fast(c1[reg] + b1o[reg]);
          s8o[reg]   += a; q8o[reg]   = fmaf(a,a,q8o[reg]);
          s8o[4+reg] += b; q8o[4+reg] = fmaf(b,b,q8o[4+reg]);
          v0[reg] = a; v1[reg] = b;
        }
        uint2 wA, wB;
        wA.x = pack2h(v0[0], v0[1]); wA.y = pack2h(v0[2], v0[3]);
        wB.x = pack2h(v1[0], v1[1]); wB.y = pack2h(v1[2], v1[3]);
        *(uint2*)&o12g[R*32 +      quad*4] = wA;
        *(uint2*)&o12g[R*32 + 16 + quad*4] = wB;
      }
      {   // a-side: a2 = tanh(fold(a1))
        f32x4 c0 = {0.f,0.f,0.f,0.f}, c1 = {0.f,0.f,0.f,0.f};
        c0 = __builtin_amdgcn_mfma_f32_16x16x32_f16(w0a, fa[buf][Mt], c0, 0,0,0);
        c1 = __builtin_amdgcn_mfma_f32_16x16x32_f16(w1a, fa[buf][Mt], c1, 0,0,0);
        float v0[4], v1[4];
#pragma unroll
        for (int reg=0;reg<4;++reg){
          float a = tanh_fast(c0[reg] + b0a[reg]);
          float b = tanh_fast(c1[reg] + b1a[reg]);
          s8a[reg]   += a; q8a[reg]   = fmaf(a,a,q8a[reg]);
          s8a[4+reg] += b; q8a[4+reg] = fmaf(b,b,q8a[4+reg]);
          v0[reg] = a; v1[reg] = b;
        }
        uint2 wA, wB;
        wA.x = pack2h(v0[0], v0[1]); wA.y = pack2h(v0[2], v0[3]);
        wB.x = pack2h(v1[0], v1[1]); wB.y = pack2h(v1[2], v1[3]);
        *(uint2*)&a2g[R*32 +      quad*4] = wA;
        *(uint2*)&a2g[R*32 + 16 + quad*4] = wB;
      }
    }
  }
  emit_stats(s8o, q8o, tid, wv, quad, ln15, lds2, S, S_O12, shard);
  emit_stats(s8a, q8a, tid, wv, quad, ln15, lds2, S, S_A2, shard);
}

// ---------------- pass3m (MAT): round-6 dbuf structure + pre-folded global weights ----------------
#define P3_LOADM(BUF, G, MT) { \
  size_t R = (size_t)(gbase + (G)*256 + rowbase + (MT)*16 + ln15); \
  fa[BUF][MT] = *(const half8*)&a2g [R*32 + quad*8]; \
  fo[BUF][MT] = *(const half8*)&o12g[R*32 + quad*8]; }
#define P3_LOAD(BUF, G) P3_LOADM(BUF,G,0) P3_LOADM(BUF,G,1) P3_LOADM(BUF,G,2) P3_LOADM(BUF,G,3)

__global__ __launch_bounds__(256) void k_pass3m(const int* __restrict__ mask,
    const u16* __restrict__ WT, const float* __restrict__ CB,
    const u16* __restrict__ o12g, const u16* __restrict__ a2g,
    float* __restrict__ x, float* __restrict__ S)
{
  __shared__ float lds2[512];
  int tid = threadIdx.x;
  int wv = tid >> 6, lane = tid & 63;
  int ln15 = lane & 15, quad = lane >> 4;
  int gbase = blockIdx.x*1024;
  int shard = blockIdx.x & (NSH-1);
  int rowbase = wv*64;

  half8 fa[2][4], fo[2][4];
  P3_LOAD(0, 0)

  // L0 = 3O (softmax, stats from S_A2), L1 = 3P (pool, stats from S_O12)
  half8 w0s = *(const half8*)&WT[(ln15     )*32 + quad*8];
  half8 w1s = *(const half8*)&WT[(ln15 + 16)*32 + quad*8];
  half8 w0p = *(const half8*)&WT[(32 + ln15     )*32 + quad*8];
  half8 w1p = *(const half8*)&WT[(32 + ln15 + 16)*32 + quad*8];
  float b0s[4], b1s[4], b0p[4], b1p[4];
#pragma unroll
  for (int reg=0;reg<4;++reg){
    b0s[reg] = CB[     quad*4 + reg]; b1s[reg] = CB[16 + quad*4 + reg];
    b0p[reg] = CB[32 + quad*4 + reg]; b1p[reg] = CB[48 + quad*4 + reg];
  }

  __syncthreads();   // vmcnt drain + wave phase-lock

#pragma unroll
  for (int g=0; g<4; ++g){
    const int buf = g & 1;
    if (g < 3){ P3_LOAD(buf^1, g+1) }
    uint2 r0[4], r1[4];
#pragma unroll
    for (int Mt=0; Mt<4; ++Mt){
      size_t R = (size_t)(gbase + g*256 + rowbase + Mt*16 + ln15);
      r0[Mt] = *(const uint2*)&o12g[R*32 +      quad*4];
      r1[Mt] = *(const uint2*)&o12g[R*32 + 16 + quad*4];
    }
    int maskbase = gbase + g*256 + wv*64;
    u32 at_pk[16];
#pragma unroll
    for (int Mt=0; Mt<4; ++Mt){     // logits + softmax
      f32x4 c0 = {0.f,0.f,0.f,0.f}, c1 = {0.f,0.f,0.f,0.f};
      c0 = __builtin_amdgcn_mfma_f32_16x16x32_f16(w0s, fa[buf][Mt], c0, 0,0,0);
      c1 = __builtin_amdgcn_mfma_f32_16x16x32_f16(w1s, fa[buf][Mt], c1, 0,0,0);
      float l0[4], l1[4];
#pragma unroll
      for (int reg=0;reg<4;++reg){ l0[reg] = c0[reg]+b0s[reg]; l1[reg] = c1[reg]+b1s[reg]; }
      float mx = l0[0];
#pragma unroll
      for (int reg=1;reg<4;++reg) mx = fmaxf(mx, l0[reg]);
#pragma unroll
      for (int reg=0;reg<4;++reg) mx = fmaxf(mx, l1[reg]);
      mx = fmaxf(mx, __shfl_xor(mx, 16));
      mx = fmaxf(mx, __shfl_xor(mx, 32));
      float sum = 0.f;
#pragma unroll
      for (int reg=0;reg<4;++reg){ l0[reg] = __expf(l0[reg]-mx); sum += l0[reg]; }
#pragma unroll
      for (int reg=0;reg<4;++reg){ l1[reg] = __expf(l1[reg]-mx); sum += l1[reg]; }
      sum += __shfl_xor(sum, 16);
      sum += __shfl_xor(sum, 32);
      float inv = __builtin_amdgcn_rcpf(sum);
      bool mz = (mask[maskbase + Mt*16 + ln15] == 0);
#pragma unroll
      for (int reg=0;reg<4;++reg){
        l0[reg] *= inv; l1[reg] *= inv;
        if (mz){ l0[reg] = -__builtin_inff(); l1[reg] = -__builtin_inff(); }
      }
      at_pk[Mt*4+0] = pack2h(l0[0], l0[1]);
      at_pk[Mt*4+1] = pack2h(l0[2], l0[3]);
      at_pk[Mt*4+2] = pack2h(l1[0], l1[1]);
      at_pk[Mt*4+3] = pack2h(l1[2], l1[3]);
    }
    float ps[8];
#pragma unroll
    for (int i=0;i<8;++i) ps[i]=0.f;
#pragma unroll
    for (int Mt=0; Mt<4; ++Mt){     // (o3 + residual) * attn, pooled
      f32x4 c0 = {0.f,0.f,0.f,0.f}, c1 = {0.f,0.f,0.f,0.f};
      c0 = __builtin_amdgcn_mfma_f32_16x16x32_f16(w0p, fo[buf][Mt], c0, 0,0,0);
      c1 = __builtin_amdgcn_mfma_f32_16x16x32_f16(w1p, fo[buf][Mt], c1, 0,0,0);
      float o0[4], o1v[4];
      unpk4(r0[Mt], o0); unpk4(r1[Mt], o1v);
      float a0v[4], a1v[4];
      a0v[0]=lo16(at_pk[Mt*4+0]); a0v[1]=hi16(at_pk[Mt*4+0]);
      a0v[2]=lo16(at_pk[Mt*4+1]); a0v[3]=hi16(at_pk[Mt*4+1]);
      a1v[0]=lo16(at_pk[Mt*4+2]); a1v[1]=hi16(at_pk[Mt*4+2]);
      a1v[2]=lo16(at_pk[Mt*4+3]); a1v[3]=hi16(at_pk[Mt*4+3]);
#pragma unroll
      for (int reg=0;reg<4;++reg){
        float a = (o0[reg]  + tanh_fast(c0[reg]+b0p[reg])) * a0v[reg];
        float b = (o1v[reg] + tanh_fast(c1[reg]+b1p[reg])) * a1v[reg];
        ps[reg]   += a;
        ps[4+reg] += b;
      }
    }
#pragma unroll
    for (int i=0;i<8;++i) ps[i]=red16(ps[i]);
    __syncthreads();
    if (ln15 == 0){
#pragma unroll
      for (int rg=0; rg<4; ++rg){
        lds2[wv*32 + quad*4+rg]    = ps[rg];
        lds2[wv*32 + 16+quad*4+rg] = ps[4+rg];
      }
    }
    __syncthreads();
    if (tid < 64){
      int half = tid >> 5, j = tid & 31;
      float v = lds2[half*64 + j] + lds2[half*64 + 32 + j];
      x[((size_t)blockIdx.x*8 + g*2 + half)*32 + j] = v;
      float* Sh = S + shard*SHARD;
      atomicAdd(&Sh[S_X+j], v);
      atomicAdd(&Sh[S_X+32+j], v*v);
    }
  }
}

// ---------------- pass2 (fallback, recompute, no stores; grid 2048) ----------------
template<int KIND>
__device__ __forceinline__ void mfma_stat_l(const u16* X, const u16* Wt, const float* Cb,
    int L, int wv, int lane, float* s8, float* q8)
{
  int ln15 = lane & 15, quad = lane >> 4;
  half8 w0 = *(const half8*)&Wt[(L*32 + ln15     )*XSTR + quad*8];
  half8 w1 = *(const half8*)&Wt[(L*32 + ln15 + 16)*XSTR + quad*8];
  float bias0[4], bias1[4];
#pragma unroll
  for (int reg=0;reg<4;++reg){
    bias0[reg] = Cb[L*32 +      quad*4 + reg];
    bias1[reg] = Cb[L*32 + 16 + quad*4 + reg];
  }
#pragma unroll
  for (int i=0;i<8;++i){ s8[i]=0.f; q8[i]=0.f; }
  int rowbase = wv*64;
#pragma unroll
  for (int Mt=0; Mt<4; ++Mt){
    int s = rowbase + Mt*16 + ln15;
    half8 bfr = *(const half8*)&X[s*XSTR + quad*8];
    f32x4 c0 = {0.f,0.f,0.f,0.f}, c1 = {0.f,0.f,0.f,0.f};
    c0 = __builtin_amdgcn_mfma_f32_16x16x32_f16(w0, bfr, c0, 0,0,0);
    c1 = __builtin_amdgcn_mfma_f32_16x16x32_f16(w1, bfr, c1, 0,0,0);
    float o0[4], o1v[4];
    if (KIND == KIND_TANHRES){
      unpk4(*(const uint2*)&X[s*XSTR +      quad*4], o0);
      unpk4(*(const uint2*)&X[s*XSTR + 16 + quad*4], o1v);
    }
#pragma unroll
    for (int reg=0;reg<4;++reg){
      float a = c0[reg] + bias0[reg];
      float b = c1[reg] + bias1[reg];
      if (KIND == KIND_TANH){ a = tanh_fast(a); b = tanh_fast(b); }
      else { a = o0[reg] + tanh_fast(a); b = o1v[reg] + tanh_fast(b); }
      s8[reg]   += a; q8[reg]   = fmaf(a,a,q8[reg]);
      s8[4+reg] += b; q8[4+reg] = fmaf(b,b,q8[4+reg]);
    }
  }
}
template<bool F32>
__device__ __forceinline__ void pass2_body(const void* __restrict__ u,
    const void* pg1, const void* pb1, const void* pw1,
    const void* og1, const void* ob1, const void* ow1,
    const void* pg2, const void* pb2, const void* pw2,
    const void* og2, const void* ob2, const void* ow2,
    float* __restrict__ S,
    u16* X, u16* Wt, float* Cb, float* lds2, float* mr)
{
  int tid = threadIdx.x;
  int wv = tid >> 6, lane = tid & 63;
  int ln15 = lane & 15, quad = lane >> 4;
  int r = blockIdx.x*256 + tid;
  int shard = blockIdx.x & (NSH-1);
  float f[4], xn[4];
  load_u4<F32>(u,r,f);
  prep_u_par(S, mr, lds2, tid);
  fold2<F32>(S, S_O1, S_A1, pg2,pb2,pw2, og2,ob2,ow2, Wt, Cb, lds2);

  float s8[8], q8[8];

  bn_u_l<F32>(mr, pg1, pb1, f, xn);
  chain1_out<F32,false>(xn, pw1, X + tid*XSTR, 0);
  __syncthreads();
  mfma_stat_l<KIND_TANHRES>(X, Wt, Cb, 0, wv, lane, s8, q8);
  emit_stats(s8, q8, tid, wv, quad, ln15, lds2, S, S_O12, shard);

  bn_u_l<F32>(mr, og1, ob1, f, xn);
  chain1_out<F32,false>(xn, ow1, X + tid*XSTR, 0);
  __syncthreads();
  mfma_stat_l<KIND_TANH>(X, Wt, Cb, 1, wv, lane, s8, q8);
  emit_stats(s8, q8, tid, wv, quad, ln15, lds2, S, S_A2, shard);
}
__global__ __launch_bounds__(256) void k_pass2(const void* __restrict__ u,
    const void* pg1, const void* pb1, const void* pw1,
    const void* og1, const void* ob1, const void* ow1,
    const void* pg2, const void* pb2, const void* pw2,
    const void* og2, const void* ob2, const void* ow2,
    float* __restrict__ S){
  __shared__ u16 X[256*XSTR];
  __shared__ u16 Wt[2*32*XSTR];
  __shared__ float Cb[64];
  __shared__ float lds2[512];
  __shared__ float mr[8];
  __shared__ int sf;
  int isf = detect_u((const u16*)u, threadIdx.x, &sf);
  if (isf) pass2_body<true >(u,pg1,pb1,pw1,og1,ob1,ow1,pg2,pb2,pw2,og2,ob2,ow2,S,X,Wt,Cb,lds2,mr);
  else     pass2_body<false>(u,pg1,pb1,pw1,og1,ob1,ow1,pg2,pb2,pw2,og2,ob2,ow2,S,X,Wt,Cb,lds2,mr);
}

// ---------------- pass3 (fallback, full recompute; grid 2048) ----------------
template<bool F32>
__device__ __forceinline__ void fold4(const float* __restrict__ S,
    int off0,int off1,int off2,int off3,
    const void* g0,const void* b0,const void* W0,
    const void* g1,const void* b1,const void* W1,
    const void* g2,const void* b2,const void* W2,
    const void* g3,const void* b3,const void* W3,
    u16* Wt, float* Cb, float* scr)
{
  int tid = threadIdx.x;
  __shared__ float scr2[256];
  if (tid < 128){
    int L = tid>>5, k = tid&31;
    const void* g = (L==0)?g0:(L==1)?g1:(L==2)?g2:g3;
    const void* b = (L==0)?b0:(L==1)?b1:(L==2)?b2:b3;
    int off = (L==0)?off0:(L==1)?off1:(L==2)?off2:off3;
    float s=0.f, q=0.f;
#pragma unroll
    for (int sh=0; sh<NSH; ++sh){
      s += S[sh*SHARD + off + k];
      q += S[sh*SHARD + off + 32 + k];
    }
    float m    = s*(1.0f/ROWS);
    float var  = q*(1.0f/ROWS) - m*m;
    float rstd = rsqrtf(var+EPS);
    float sc = rdp<F32>(g,k)*rstd;
    scr[tid]  = sc;
    scr2[tid] = rdp<F32>(b,k) - m*sc;
  }
  __syncthreads();
  if (tid < 128){
    int L = tid>>5, j = tid&31;
    const void* W = (L==0)?W0:(L==1)?W1:(L==2)?W2:W3;
    float c = 0.f;
#pragma unroll
    for (int k=0;k<32;++k){
      float Wv = rdp<F32>(W, j*32+k);
      Wt[(L*32+j)*XSTR + k] = f2h(Wv * scr[(L<<5)|k]);
      c += Wv * scr2[(L<<5)|k];
    }
    Cb[L*32+j] = c;
  }
  __syncthreads();
}

template<bool F32>
__device__ __forceinline__ void pass3_body(const void* __restrict__ u, const int* __restrict__ mask,
    const void* pg1, const void* pb1, const void* pw1,
    const void* og1, const void* ob1, const void* ow1,
    const void* pg2, const void* pb2, const void* pw2,
    const void* og2, const void* ob2, const void* ow2,
    const void* pg3, const void* pb3, const void* pw3,
    const void* og3, const void* ob3, const void* ow3,
    float* __restrict__ x, float* __restrict__ S,
    u16* X, u16* Wt, float* Cb, float* red2, float* mr)
{
  int tid = threadIdx.x;
  int wv = tid >> 6, lane = tid & 63;
  int r = blockIdx.x*256 + tid;
  float f[4], xn[4];
  load_u4<F32>(u,r,f);
  prep_u_par(S, mr, red2, tid);
  fold4<F32>(S, S_A1, S_A2, S_O1, S_O12,
             og2,ob2,ow2, og3,ob3,ow3, pg2,pb2,pw2, pg3,pb3,pw3,
             Wt, Cb, red2);

  u32 at_pk[16];
  int maskbase = blockIdx.x*256 + wv*64;

  bn_u_l<F32>(mr, og1, ob1, f, xn);
  chain1_out<F32,false>(xn, ow1, X + tid*XSTR, 0);
  mfma_layer<KIND_TANH>(X, Wt, Cb, 0, wv, lane, 0);
  {
    int ln15 = lane & 15, quad = lane >> 4;
    half8 w0 = *(const half8*)&Wt[(1*32 + ln15     )*XSTR + quad*8];
    half8 w1 = *(const half8*)&Wt[(1*32 + ln15 + 16)*XSTR + quad*8];
    float bias0[4], bias1[4];
#pragma unroll
    for (int reg=0;reg<4;++reg){
      bias0[reg] = Cb[32 +      quad*4 + reg];
      bias1[reg] = Cb[32 + 16 + quad*4 + reg];
    }
    int rowbase = wv*64;
#pragma unroll
    for (int Mt=0; Mt<4; ++Mt){
      int s = rowbase + Mt*16 + ln15;
      half8 bfr = *(const half8*)&X[s*XSTR + quad*8];
      f32x4 c0 = {0.f,0.f,0.f,0.f}, c1 = {0.f,0.f,0.f,0.f};
      c0 = __builtin_amdgcn_mfma_f32_16x16x32_f16(w0, bfr, c0, 0,0,0);
      c1 = __builtin_amdgcn_mfma_f32_16x16x32_f16(w1, bfr, c1, 0,0,0);
      float l0[4], l1[4];
#pragma unroll
      for (int reg=0;reg<4;++reg){ l0[reg] = c0[reg]+bias0[reg]; l1[reg] = c1[reg]+bias1[reg]; }
      float mx = l0[0];
#pragma unroll
      for (int reg=1;reg<4;++reg) mx = fmaxf(mx, l0[reg]);
#pragma unroll
      for (int reg=0;reg<4;++reg) mx = fmaxf(mx, l1[reg]);
      mx = fmaxf(mx, __shfl_xor(mx, 16));
      mx = fmaxf(mx, __shfl_xor(mx, 32));
      float sum = 0.f;
#pragma unroll
      for (int reg=0;reg<4;++reg){ l0[reg] = __expf(l0[reg]-mx); sum += l0[reg]; }
#pragma unroll
      for (int reg=0;reg<4;++reg){ l1[reg] = __expf(l1[reg]-mx); sum += l1[reg]; }
      sum += __shfl_xor(sum, 16);
      sum += __shfl_xor(sum, 32);
      float inv = __builtin_amdgcn_rcpf(sum);
      bool mz = (mask[maskbase + Mt*16 + ln15] == 0);
#pragma unroll
      for (int reg=0;reg<4;++reg){
        l0[reg] *= inv; l1[reg] *= inv;
        if (mz){ l0[reg] = -__builtin_inff(); l1[reg] = -__builtin_inff(); }
      }
      at_pk[Mt*4+0] = pack2h(l0[0], l0[1]);
      at_pk[Mt*4+1] = pack2h(l0[2], l0[3]);
      at_pk[Mt*4+2] = pack2h(l1[0], l1[1]);
      at_pk[Mt*4+3] = pack2h(l1[2], l1[3]);
    }
  }

  bn_u_l<F32>(mr, pg1, pb1, f, xn);
  chain1_out<F32,false>(xn, pw1, X + tid*XSTR, 0);
  mfma_layer<KIND_TANHRES   >(X, Wt, Cb, 2, wv, lane, 0);
  mfma_layer<KIND_TANHRES_ATREG>(X, Wt, Cb, 3, wv, lane, at_pk);

  __syncthreads();
  {
    int jj = tid & 31, cgrp = (tid >> 5) & 3, half = tid >> 7;
    float s2 = 0.f;
#pragma unroll
    for (int q2=0;q2<32;++q2) s2 += h2f(X[(half*128 + cgrp*32 + q2)*XSTR + jj]);
    red2[tid] = s2;
  }
  __syncthreads();
  if (tid < 64){
    int half = tid >> 5, j = tid & 31;
    float v = red2[half*128+j] + red2[half*128+32+j] + red2[half*128+64+j] + red2[half*128+96+j];
    x[(blockIdx.x*2 + half)*32 + j] = v;
    float* Sh = S + (blockIdx.x & (NSH-1))*SHARD;
    atomicAdd(&Sh[S_X+j], v);
    atomicAdd(&Sh[S_X+32+j], v*v);
  }
}
__global__ __launch_bounds__(256) void k_pass3(const void* __restrict__ u, const int* __restrict__ mask,
    const void* pg1, const void* pb1, const void* pw1,
    const void* og1, const void* ob1, const void* ow1,
    const void* pg2, const void* pb2, const void* pw2,
    const void* og2, const void* ob2, const void* ow2,
    const void* pg3, const void* pb3, const void* pw3,
    const void* og3, const void* ob3, const void* ow3,
    float* __restrict__ x, float* __restrict__ S){
  __shared__ u16 X [256*XSTR];
  __shared__ u16 Wt[4*32*XSTR];
  __shared__ float Cb[128];
  __shared__ float red2[256];
  __shared__ float mr[8];
  __shared__ int sf;
  int isf = detect_u((const u16*)u, threadIdx.x, &sf);
  if (isf) pass3_body<true >(u,mask,pg1,pb1,pw1,og1,ob1,ow1,pg2,pb2,pw2,og2,ob2,ow2,
                             pg3,pb3,pw3,og3,ob3,ow3,x,S,X,Wt,Cb,red2,mr);
  else     pass3_body<false>(u,mask,pg1,pb1,pw1,og1,ob1,ow1,pg2,pb2,pw2,og2,ob2,ow2,
                             pg3,pb3,pw3,og3,ob3,ow3,x,S,X,Wt,Cb,red2,mr);
}

// ---------------- theta chain: 4 small stream-ordered kernels ----------------
template<int NSH_IN>
__device__ __forceinline__ void theta_gather(const float* __restrict__ S, int off,
                                             float* scratch, float* lds2, int tid){
  int col = tid & 63, grp = tid >> 6;
  float t = 0.f;
#pragma unroll
  for (int i = 0; i < NSH_IN/4; ++i)
    t += S[(grp + i*4)*SHARD + off + col];
  scratch[tid] = t;
  __syncthreads();
  if (tid < 64)
    scratch[tid] = scratch[tid] + scratch[64+tid] + scratch[128+tid] + scratch[192+tid];
  __syncthreads();
  if (tid < 32){
    float m   = scratch[tid]*(1.0f/BROWS);
    float var = scratch[32+tid]*(1.0f/BROWS) - m*m;
    lds2[tid]    = m;
    lds2[32+tid] = rsqrtf(var + EPS);
  }
  __syncthreads();
}

template<bool F32>
__device__ __forceinline__ void theta_layer(float* v, const float* lds2,
    const void* g, const void* b, const void* W){
  float xn[32];
#pragma unroll
  for (int k=0;k<32;++k)
    xn[k] = (v[k] - lds2[k]) * (rdp<F32>(g,k)*lds2[32+k]) + rdp<F32>(b,k);
#pragma unroll
  for (int j=0;j<32;++j){
    float acc = 0.f;
#pragma unroll
    for (int k=0;k<32;++k) acc = fmaf(rdp<F32>(W, j*32+k), xn[k], acc);
    v[j] = tanh_fast(acc);
  }
}

template<bool F32, int NSH_IN>
__device__ __forceinline__ void theta_L_body(const float* __restrict__ xin,
    float* __restrict__ xout, float* __restrict__ S, int off_in, int off_out,
    const void* g, const void* b, const void* W, float* lds, float* lds2)
{
  int tid = threadIdx.x, blk = blockIdx.x;
  int r = blk*256 + tid;
  float v[32];
  {
    const float4* xr = (const float4*)&xin[(size_t)r*32];
#pragma unroll
    for (int k=0;k<8;++k){ float4 t = xr[k]; v[4*k]=t.x; v[4*k+1]=t.y; v[4*k+2]=t.z; v[4*k+3]=t.w; }
  }
  theta_gather<NSH_IN>(S, off_in, lds, lds2, tid);
  theta_layer<F32>(v, lds2, g, b, W);
  {
    float4* xw = (float4*)&xout[(size_t)r*32];
#pragma unroll
    for (int k=0;k<8;++k){ float4 t; t.x=v[4*k]; t.y=v[4*k+1]; t.z=v[4*k+2]; t.w=v[4*k+3]; xw[k]=t; }
  }
  float* Xp = lds + tid*33;
#pragma unroll
  for (int j=0;j<32;++j) Xp[j] = v[j];
  reduce_f32(lds, lds2, S, off_out, blk);   // shard = blk: zero contention
}
template<int NSH_IN>
__global__ __launch_bounds__(256) void k_theta_L(const void* __restrict__ u,
    const float* __restrict__ xin, float* __restrict__ xout,
    float* __restrict__ S, int off_in, int off_out,
    const void* g, const void* b, const void* W){
  __shared__ float lds[256*33];
  __shared__ float lds2[512];
  __shared__ int sf;
  int isf = detect_u((const u16*)u, threadIdx.x, &sf);
  if (isf) theta_L_body<true , NSH_IN>(xin, xout, S, off_in, off_out, g, b, W, lds, lds2);
  else     theta_L_body<false, NSH_IN>(xin, xout, S, off_in, off_out, g, b, W, lds, lds2);
}

template<bool F32>
__device__ __forceinline__ void theta_fin_body(const float* __restrict__ xin,
    float* __restrict__ S,
    const void* g4, const void* b4, const void* w4, const void* bb4,
    void* out, float* lds, float* lds2)
{
  int tid = threadIdx.x, blk = blockIdx.x;
  int r = blk*256 + tid;
  const float4* xr = (const float4*)&xin[(size_t)r*32];
  float4 t0 = xr[0], t1 = xr[1], t2 = xr[2], t3 = xr[3];
  float4 t4 = xr[4], t5 = xr[5], t6 = xr[6], t7 = xr[7];
  theta_gather<16>(S, S_X3, lds, lds2, tid);
  float vv[32];
  vv[0]=t0.x; vv[1]=t0.y; vv[2]=t0.z; vv[3]=t0.w;
  vv[4]=t1.x; vv[5]=t1.y; vv[6]=t1.z; vv[7]=t1.w;
  vv[8]=t2.x; vv[9]=t2.y; vv[10]=t2.z; vv[11]=t2.w;
  vv[12]=t3.x; vv[13]=t3.y; vv[14]=t3.z; vv[15]=t3.w;
  vv[16]=t4.x; vv[17]=t4.y; vv[18]=t4.z; vv[19]=t4.w;
  vv[20]=t5.x; vv[21]=t5.y; vv[22]=t5.z; vv[23]=t5.w;
  vv[24]=t6.x; vv[25]=t6.y; vv[26]=t6.z; vv[27]=t6.w;
  vv[28]=t7.x; vv[29]=t7.y; vv[30]=t7.z; vv[31]=t7.w;
  float acc = rdp<F32>(bb4, 0);
#pragma unroll
  for (int k=0;k<32;++k){
    float xnv = (vv[k] - lds2[k]) * (rdp<F32>(g4,k)*lds2[32+k]) + rdp<F32>(b4,k);
    acc = fmaf(rdp<F32>(w4,k), xnv, acc);
  }
  if (F32) ((float*)out)[r] = acc;
  else     ((u16*)out)[r]  = f2b(acc);
}
__global__ __launch_bounds__(256) void k_theta_fin(const void* __restrict__ u,
    const float* __restrict__ xin, float* __restrict__ S,
    const void* g4, const void* b4, const void* w4, const void* bb4,
    void* out){
  __shared__ float lds[256];
  __shared__ float lds2[512];
  __shared__ int sf;
  int isf = detect_u((const u16*)u, threadIdx.x, &sf);
  if (isf) theta_fin_body<true >(xin, S, g4, b4, w4, bb4, out, lds, lds2);
  else     theta_fin_body<false>(xin, S, g4, b4, w4, bb4, out, lds, lds2);
}

extern "C" void kernel_launch(void* const* d_in, const int* in_sizes, int n_in,
                              void* d_out, int out_size, void* d_ws, size_t ws_size,
                              hipStream_t stream)
{
  const void* u    = d_in[0];
  const int*  mask = (const int*)d_in[1];
  const void *pg1=d_in[2],  *pb1=d_in[3],  *pw1=d_in[4];
  const void *pg2=d_in[5],  *pb2=d_in[6],  *pw2=d_in[7];
  const void *pg3=d_in[8],  *pb3=d_in[9],  *pw3=d_in[10];
  const void *og1=d_in[11], *ob1=d_in[12], *ow1=d_in[13];
  const void *og2=d_in[14], *ob2=d_in[15], *ow2=d_in[16];
  const void *og3=d_in[17], *ob3=d_in[18], *ow3=d_in[19];
  const void *tg1=d_in[20], *tb1=d_in[21], *tw1=d_in[22];
  const void *tg2=d_in[23], *tb2=d_in[24], *tw2=d_in[25];
  const void *tg3=d_in[26], *tb3=d_in[27], *tw3=d_in[28];
  const void *tg4=d_in[29], *tb4=d_in[30], *tw4=d_in[31], *tbb4=d_in[32];

  char* ws = (char*)d_ws;
  float* S    = (float*)(ws + 4096);         // 64 shards x 1024 floats = 256 KB
  float* x    = (float*)(ws + 524288);       // 4096*32 f32 (512 KB)
  float* xb   = (float*)(ws + 1048576);      // ping-pong buffer (512 KB)
  float* F1   = (float*)(ws + 1572864);      // folded layer-1 weights (1.3 KB)
  u16*   WT2  = (u16*)  (ws + 1572864 + 4096);
  float* CB2  = (float*)(ws + 1572864 + 8192);
  u16*   WT3  = (u16*)  (ws + 1572864 + 12288);
  float* CB3  = (float*)(ws + 1572864 + 16384);

  const size_t MB = 1024*1024;
  u16* o12g = (u16*)(ws + 8*MB);             // 32 MB: o1 then (in-place) o12
  u16* a2g  = (u16*)(ws + 40*MB);            // 32 MB: a1 then (in-place) a2
  bool MAT = ws_size >= 73*MB;               // constant per process -> graph-safe

  (void)hipMemsetAsync(ws, 0, 4096 + NSH*SHARD*4, stream);  // zero sharded stats
  k_stats_u<<<1024, 256, 0, stream>>>(u, S);
  k_fold1<<<1, 256, 0, stream>>>(u, pg1,pb1,pw1, og1,ob1,ow1, S, F1);
  if (MAT){
    k_pass1<true ><<<512, 256, 0, stream>>>(u, F1, S, o12g, a2g);
    k_foldw<<<1, 256, 0, stream>>>(u, S, S_O1, S_A1, pg2,pb2,pw2, og2,ob2,ow2, WT2, CB2);
    k_pass2m<<<512, 256, 0, stream>>>(WT2, CB2, S, o12g, a2g);
    k_foldw<<<1, 256, 0, stream>>>(u, S, S_A2, S_O12, og3,ob3,ow3, pg3,pb3,pw3, WT3, CB3);
    k_pass3m<<<512, 256, 0, stream>>>(mask, WT3, CB3, o12g, a2g, x, S);
  } else {
    k_pass1<false><<<512, 256, 0, stream>>>(u, F1, S, o12g, a2g);
    k_pass2<<<2048, 256, 0, stream>>>(u, pg1,pb1,pw1, og1,ob1,ow1,
                                      pg2,pb2,pw2, og2,ob2,ow2, S);
    k_pass3<<<2048, 256, 0, stream>>>(u, mask, pg1,pb1,pw1, og1,ob1,ow1,
                                      pg2,pb2,pw2, og2,ob2,ow2,
                                      pg3,pb3,pw3, og3,ob3,ow3, x, S);
  }
  // theta chain: 4 tiny kernels; stream order supplies the global sync
  k_theta_L<64><<<16, 256, 0, stream>>>(u, x,  xb, S, S_X,  S_X1, tg1, tb1, tw1);
  k_theta_L<16><<<16, 256, 0, stream>>>(u, xb, x,  S, S_X1, S_X2, tg2, tb2, tw2);
  k_theta_L<16><<<16, 256, 0, stream>>>(u, x,  xb, S, S_X2, S_X3, tg3, tb3, tw3);
  k_theta_fin<<<16, 256, 0, stream>>>(u, xb, S, tg4, tb4, tw4, tbb4, d_out);
}

// Round 9
// 403.479 us; speedup vs baseline: 1.2294x; 1.0150x over previous
//
#include <hip/hip_runtime.h>

typedef unsigned int u32;
typedef unsigned short u16;
typedef __attribute__((ext_vector_type(8))) _Float16 half8;
typedef __attribute__((ext_vector_type(4))) float f32x4;

#define ROWS  524288   // B*N
#define BROWS 4096     // B
#define EPS   1e-5f

// ---- stats: 64 shards of 1024 floats; block-coop summing ----
#define S_U   0
#define S_O1  8
#define S_A1  72
#define S_O12 136
#define S_A2  200
#define S_X   264
#define S_X1  328
#define S_X2  392
#define S_X3  456
#define SHARD 1024
#define NSH   64

#define XSTR 40   // LDS row stride in u16 (80 B: 16B-aligned for uint4 rows)

__device__ __forceinline__ float bl(u32 u){ return __uint_as_float(u << 16); }
__device__ __forceinline__ float bh(u32 u){ return __uint_as_float(u & 0xFFFF0000u); }
__device__ __forceinline__ float b2f(u16 h){ return __uint_as_float(((u32)h) << 16); }
__device__ __forceinline__ u16 f2b(float f){
  u32 u = __float_as_uint(f);
  return (u16)((u + 0x7FFFu + ((u >> 16) & 1u)) >> 16);   // RNE (bf16, output only)
}
__device__ __forceinline__ u16 f2h(float f){ _Float16 h = (_Float16)f; return __builtin_bit_cast(u16, h); }
__device__ __forceinline__ float h2f(u16 x){ return (float)__builtin_bit_cast(_Float16, x); }
__device__ __forceinline__ u32 pack2h(float a, float b){
  auto v = __builtin_amdgcn_cvt_pkrtz(a, b);
  return __builtin_bit_cast(u32, v);
}
__device__ __forceinline__ float lo16(u32 w){ return h2f((u16)(w & 0xFFFF)); }
__device__ __forceinline__ float hi16(u32 w){ return h2f((u16)(w >> 16)); }
__device__ __forceinline__ void unpk4(uint2 v, float* d){
  d[0]=lo16(v.x); d[1]=hi16(v.x); d[2]=lo16(v.y); d[3]=hi16(v.y);
}

// Padé(5,4) tanh: no v_exp; err <= ~1e-3, clamped to [-1,1].
__device__ __forceinline__ float tanh_fast(float x){
  float x2 = x*x;
  float num = fmaf(x2 + 105.0f, x2, 945.0f) * x;
  float den = fmaf(fmaf(x2, 15.0f, 420.0f), x2, 945.0f);
  float v = num * __builtin_amdgcn_rcpf(den);
  return fminf(1.0f, fmaxf(-1.0f, v));
}

// sum over the 16-lane subgroup (xor masks 1,2,4,8 -> DPP-friendly)
__device__ __forceinline__ float red16(float v){
  v += __shfl_xor(v, 1);
  v += __shfl_xor(v, 2);
  v += __shfl_xor(v, 4);
  v += __shfl_xor(v, 8);
  return v;
}

template<bool F32>
__device__ __forceinline__ float rdp(const void* p, int i){
  if (F32) return ((const float*)p)[i];
  return b2f(((const u16*)p)[i]);
}
template<bool F32>
__device__ __forceinline__ void load_u4(const void* u, int r, float* f){
  if (F32){
    float4 v = ((const float4*)u)[r];
    f[0]=v.x; f[1]=v.y; f[2]=v.z; f[3]=v.w;
  } else {
    uint2 v = ((const uint2*)u)[r];
    f[0]=bl(v.x); f[1]=bh(v.x); f[2]=bl(v.y); f[3]=bh(v.y);
  }
}

// ---- per-block inline dtype detect ----
__device__ __forceinline__ int detect_u(const u16* __restrict__ u, int tid, int* sf){
  if (tid < 64){
    int bad = 0;
#pragma unroll
    for (int i = 0; i < 4; ++i){
      int e = (u[tid*4 + i] >> 7) & 0xFF;
      bad += (e >= 0x90) ? 1 : 0;
    }
#pragma unroll
    for (int off = 32; off >= 1; off >>= 1) bad += __shfl_down(bad, off);
    if (tid == 0) *sf = (bad >= 4) ? 1 : 0;
  }
  __syncthreads();
  return *sf;
}

// ---------------- stats of u (4 cols) ----------------
template<bool F32>
__device__ __forceinline__ void stats_u_body(const void* __restrict__ u, float* __restrict__ S){
  int tid = blockIdx.x*blockDim.x + threadIdx.x;
  int nt  = gridDim.x*blockDim.x;
  float s[4]={0,0,0,0}, q[4]={0,0,0,0};
  for (int r = tid; r < ROWS; r += nt){
    float f[4]; load_u4<F32>(u, r, f);
#pragma unroll
    for (int k=0;k<4;++k){ s[k]+=f[k]; q[k]+=f[k]*f[k]; }
  }
#pragma unroll
  for (int off=32; off>=1; off>>=1){
#pragma unroll
    for (int k=0;k<4;++k){ s[k]+=__shfl_down(s[k],off); q[k]+=__shfl_down(q[k],off); }
  }
  if ((threadIdx.x & 63) == 0){
    float* Sh = S + (blockIdx.x & (NSH-1))*SHARD;
#pragma unroll
    for (int k=0;k<4;++k){ atomicAdd(&Sh[S_U+k], s[k]); atomicAdd(&Sh[S_U+4+k], q[k]); }
  }
}
__global__ __launch_bounds__(256) void k_stats_u(const void* __restrict__ u, float* __restrict__ S){
  __shared__ int sf;
  int isf = detect_u((const u16*)u, threadIdx.x, &sf);
  if (isf) stats_u_body<true>(u,S); else stats_u_body<false>(u,S);
}

// ---------------- block preamble: m/rstd of u (parallel gather, 256 threads) ----------------
__device__ __forceinline__ void prep_u_par(const float* __restrict__ S, float* mr,
                                           float* scr /*256 floats*/, int tid){
  {
    int col = tid & 3, isq = (tid >> 2) & 1, grp = tid >> 3;   // grp 0..31, 2 shards each
    float t = S[(grp*2+0)*SHARD + S_U + isq*4 + col]
            + S[(grp*2+1)*SHARD + S_U + isq*4 + col];
    scr[tid] = t;
  }
  __syncthreads();
  if (tid < 8){
    float t = 0.f;
#pragma unroll
    for (int g=0; g<32; ++g) t += scr[tid + 8*g];
    mr[tid] = t;                                   // raw sums: [0..3]=s, [4..7]=q
  }
  __syncthreads();
  if (tid < 4){
    float s = mr[tid], q = mr[4+tid];
    float m = s*(1.0f/ROWS);
    float var = q*(1.0f/ROWS) - m*m;
    mr[tid]   = m;
    mr[4+tid] = rsqrtf(var + EPS);
  }
  __syncthreads();
}
template<bool F32>
__device__ __forceinline__ void bn_u_l(const float* mr, const void* g, const void* b,
                                       const float* f, float* xn){
#pragma unroll
  for (int k=0;k<4;++k)
    xn[k] = (f[k]-mr[k])*(rdp<F32>(g,k)*mr[4+k]) + rdp<F32>(b,k);
}

// ---------------- L1 chain -> f16 LDS row (+ optional global row) ----------------
template<bool F32, bool STORE>
__device__ __forceinline__ void chain1_out(const float* xn, const void* W1, u16* Xrow,
                                           u16* __restrict__ grow){
  u32 buf[16];
#pragma unroll
  for (int jp=0; jp<16; ++jp){
    int j0 = 2*jp, j1 = 2*jp+1;
    float a0 = tanh_fast(xn[0]*rdp<F32>(W1,j0*4+0) + xn[1]*rdp<F32>(W1,j0*4+1)
                       + xn[2]*rdp<F32>(W1,j0*4+2) + xn[3]*rdp<F32>(W1,j0*4+3));
    float a1 = tanh_fast(xn[0]*rdp<F32>(W1,j1*4+0) + xn[1]*rdp<F32>(W1,j1*4+1)
                       + xn[2]*rdp<F32>(W1,j1*4+2) + xn[3]*rdp<F32>(W1,j1*4+3));
    buf[jp] = pack2h(a0, a1);
  }
#pragma unroll
  for (int c=0;c<4;++c){
    uint4 v; v.x = buf[c*4]; v.y = buf[c*4+1]; v.z = buf[c*4+2]; v.w = buf[c*4+3];
    *(uint4*)&Xrow[c*8] = v;
    if (STORE) *(uint4*)&grow[c*8] = v;
  }
}

// ---------------- in-block BN+Linear folds (parallel 256-thread gather) ----------------
template<bool F32>
__device__ __forceinline__ void fold2(const float* __restrict__ S, int offA, int offB,
    const void* gA, const void* bA, const void* WA,
    const void* gB, const void* bB, const void* WB,
    u16* Wt, float* Cb, float* scr /* 512 floats */)
{
  int tid = threadIdx.x;
  {
    int pair = tid >> 2;            // 0..63 : L=pair>>5, k=pair&31
    int isq  = (tid >> 1) & 1;      // 0=sum, 1=sumsq
    int half = tid & 1;             // shard half
    int L = pair >> 5, k = pair & 31;
    int off = (L ? offB : offA) + isq*32 + k;
    float t = 0.f;
#pragma unroll
    for (int i=0;i<32;++i)
      t += S[(half*32 + i)*SHARD + off];
    scr[tid] = t;                   // tid = pair*4 + isq*2 + half
  }
  __syncthreads();
  if (tid < 64){
    int L = tid>>5, k = tid&31;
    const void* g = L? gB:gA; const void* b = L? bB:bA;
    float s = scr[tid*4+0] + scr[tid*4+1];
    float q = scr[tid*4+2] + scr[tid*4+3];
    float m    = s*(1.0f/ROWS);
    float var  = q*(1.0f/ROWS) - m*m;
    float rstd = rsqrtf(var+EPS);
    float sc = rdp<F32>(g,k)*rstd;
    scr[256+tid] = sc;
    scr[320+tid] = rdp<F32>(b,k) - m*sc;
  }
  __syncthreads();
  if (tid < 64){
    int L = tid>>5, j = tid&31;
    const void* W = L? WB:WA;
    float c = 0.f;
#pragma unroll
    for (int k=0;k<32;++k){
      float Wv = rdp<F32>(W, j*32+k);
      Wt[(L*32+j)*XSTR + k] = f2h(Wv * scr[256 + ((L<<5)|k)]);
      c += Wv * scr[320 + ((L<<5)|k)];
    }
    Cb[L*32+j] = c;
  }
  __syncthreads();
}

// ---------------- MFMA layer (LDS in/out) -- used by fallback pass3 ----------------
#define KIND_TANH          0
#define KIND_TANHRES       2
#define KIND_TANHRES_ATREG 3
template<int KIND>
__device__ __forceinline__ void mfma_layer(u16* X, const u16* Wt, const float* Cb,
                                           int L, int wv, int lane, const u32* at_pk)
{
  int ln15 = lane & 15, quad = lane >> 4;
  half8 w0 = *(const half8*)&Wt[(L*32 + ln15     )*XSTR + quad*8];
  half8 w1 = *(const half8*)&Wt[(L*32 + ln15 + 16)*XSTR + quad*8];
  float bias0[4], bias1[4];
#pragma unroll
  for (int reg=0;reg<4;++reg){
    bias0[reg] = Cb[L*32 +      quad*4 + reg];
    bias1[reg] = Cb[L*32 + 16 + quad*4 + reg];
  }
  int rowbase = wv*64;
#pragma unroll
  for (int Mt=0; Mt<4; ++Mt){
    int s = rowbase + Mt*16 + ln15;
    half8 bfr = *(const half8*)&X[s*XSTR + quad*8];
    f32x4 c0 = {0.f,0.f,0.f,0.f}, c1 = {0.f,0.f,0.f,0.f};
    c0 = __builtin_amdgcn_mfma_f32_16x16x32_f16(w0, bfr, c0, 0,0,0);
    c1 = __builtin_amdgcn_mfma_f32_16x16x32_f16(w1, bfr, c1, 0,0,0);
    float o0[4], o1v[4];
    if (KIND == KIND_TANHRES || KIND == KIND_TANHRES_ATREG){
      unpk4(*(const uint2*)&X[s*XSTR +      quad*4], o0);
      unpk4(*(const uint2*)&X[s*XSTR + 16 + quad*4], o1v);
    }
    float a0v[4], a1v[4];
    if (KIND == KIND_TANHRES_ATREG){
      a0v[0]=lo16(at_pk[Mt*4+0]); a0v[1]=hi16(at_pk[Mt*4+0]);
      a0v[2]=lo16(at_pk[Mt*4+1]); a0v[3]=hi16(at_pk[Mt*4+1]);
      a1v[0]=lo16(at_pk[Mt*4+2]); a1v[1]=hi16(at_pk[Mt*4+2]);
      a1v[2]=lo16(at_pk[Mt*4+3]); a1v[3]=hi16(at_pk[Mt*4+3]);
    }
    float v0[4], v1[4];
#pragma unroll
    for (int reg=0;reg<4;++reg){
      float a = c0[reg] + bias0[reg];
      float b = c1[reg] + bias1[reg];
      if (KIND == KIND_TANH){ a = tanh_fast(a); b = tanh_fast(b); }
      else if (KIND == KIND_TANHRES){ a = o0[reg] + tanh_fast(a); b = o1v[reg] + tanh_fast(b); }
      else if (KIND == KIND_TANHRES_ATREG){
        a = (o0[reg] + tanh_fast(a)) * a0v[reg];
        b = (o1v[reg] + tanh_fast(b)) * a1v[reg];
      }
      v0[reg] = a; v1[reg] = b;
    }
    uint2 w0o, w1o;
    w0o.x = pack2h(v0[0], v0[1]); w0o.y = pack2h(v0[2], v0[3]);
    w1o.x = pack2h(v1[0], v1[1]); w1o.y = pack2h(v1[2], v1[3]);
    *(uint2*)&X[s*XSTR +      quad*4] = w0o;
    *(uint2*)&X[s*XSTR + 16 + quad*4] = w1o;
  }
}

// cross-lane (16 rows) + cross-wave combine of per-lane col stats -> sharded atomics
__device__ __forceinline__ void emit_stats(float* s8, float* q8, int tid, int wv,
    int quad, int ln15, float* scr /*512*/, float* __restrict__ S, int offS, int shard)
{
#pragma unroll
  for (int i=0;i<8;++i){ s8[i]=red16(s8[i]); q8[i]=red16(q8[i]); }
  __syncthreads();                 // protect scr reuse
  if (ln15 == 0){
#pragma unroll
    for (int rg=0; rg<4; ++rg){
      int cl = quad*4+rg, ch = 16+quad*4+rg;
      scr[wv*64 + cl]       = s8[rg];
      scr[wv*64 + ch]       = s8[4+rg];
      scr[256 + wv*64 + cl] = q8[rg];
      scr[256 + wv*64 + ch] = q8[4+rg];
    }
  }
  __syncthreads();
  if (tid < 64){
    int j = tid & 31, isq = tid >> 5;
    const float* src = scr + isq*256;
    float tot = src[j] + src[64+j] + src[128+j] + src[192+j];
    atomicAdd(&S[shard*SHARD + offS + isq*32 + j], tot);
  }
}

// ---------------- column stats reducers ----------------
__device__ __forceinline__ void reduce_f16(const u16* X, float* lds2,
                                           float* __restrict__ S, int offS, int shard)
{
  int tid = threadIdx.x;
  __syncthreads();
  {
    int j = tid & 31, seg = tid >> 5;
    float s=0.f, q=0.f;
#pragma unroll
    for (int q2=0;q2<32;++q2){
      float v = h2f(X[(seg*32+q2)*XSTR + j]);
      s += v; q = fmaf(v,v,q);
    }
    lds2[seg*32+j] = s;
    lds2[256 + seg*32+j] = q;
  }
  __syncthreads();
  if (tid < 64){
    int j = tid & 31; bool isq = tid >= 32;
    const float* src = lds2 + (isq?256:0);
    float tot=0.f;
#pragma unroll
    for (int sg=0;sg<8;++sg) tot += src[sg*32+j];
    atomicAdd(&S[shard*SHARD + offS + (isq?32:0) + j], tot);
  }
  __syncthreads();
}

__device__ __forceinline__ void reduce_f32(const float* Xs, float* lds2,
                                           float* __restrict__ S, int offS, int shard)
{
  int tid = threadIdx.x;
  __syncthreads();
  {
    int j = tid & 31, seg = tid >> 5;
    float s=0.f, q=0.f;
#pragma unroll
    for (int q2=0;q2<32;++q2){
      float v = Xs[(seg*32+q2)*33 + j];
      s += v; q = fmaf(v,v,q);
    }
    lds2[seg*32+j] = s;
    lds2[256 + seg*32+j] = q;
  }
  __syncthreads();
  if (tid < 64){
    int j = tid & 31; bool isq = tid >= 32;
    const float* src = lds2 + (isq?256:0);
    float tot=0.f;
#pragma unroll
    for (int sg=0;sg<8;++sg) tot += src[sg*32+j];
    atomicAdd(&S[shard*SHARD + offS + (isq?32:0) + j], tot);
  }
  __syncthreads();
}

// ---------------- pass1: 512 blocks x 4 row-groups; chains o1/a1; stats ----------------
template<bool F32, bool MAT>
__device__ __forceinline__ void pass1_body(const void* __restrict__ u,
    const void* pg1, const void* pb1, const void* pw1,
    const void* og1, const void* ob1, const void* ow1,
    float* __restrict__ S, u16* __restrict__ o1g, u16* __restrict__ a1g,
    u16* X, float* lds2, float* mr)
{
  int tid = threadIdx.x;
  int base = blockIdx.x*1024;
  int shard = blockIdx.x & (NSH-1);
  float f[4][4];
#pragma unroll
  for (int g=0; g<4; ++g) load_u4<F32>(u, base + g*256 + tid, f[g]);  // issued before gather
  prep_u_par(S, mr, lds2, tid);

#pragma unroll
  for (int g=0; g<4; ++g){
    int r = base + g*256 + tid;
    float xn[4];
    bn_u_l<F32>(mr, pg1, pb1, f[g], xn);
    chain1_out<F32,MAT>(xn, pw1, X + tid*XSTR, o1g + (size_t)r*32);
    reduce_f16(X, lds2, S, S_O1, shard);

    bn_u_l<F32>(mr, og1, ob1, f[g], xn);
    chain1_out<F32,MAT>(xn, ow1, X + tid*XSTR, a1g + (size_t)r*32);
    reduce_f16(X, lds2, S, S_A1, shard);
  }
}
template<bool MAT>
__global__ __launch_bounds__(256) void k_pass1(const void* __restrict__ u,
    const void* pg1, const void* pb1, const void* pw1,
    const void* og1, const void* ob1, const void* ow1,
    float* __restrict__ S, u16* o1g, u16* a1g){
  __shared__ u16 X[256*XSTR];
  __shared__ float lds2[512];
  __shared__ float mr[8];
  __shared__ int sf;
  int isf = detect_u((const u16*)u, threadIdx.x, &sf);
  if (isf) pass1_body<true ,MAT>(u,pg1,pb1,pw1,og1,ob1,ow1,S,o1g,a1g,X,lds2,mr);
  else     pass1_body<false,MAT>(u,pg1,pb1,pw1,og1,ob1,ow1,S,o1g,a1g,X,lds2,mr);
}

// ---------------- pass2m (MAT): 512 blocks x 4 groups, dbuf prefetch (incl. residuals) ----------------
// In-place safety is by dataflow: each group's loads are consumed (hw waitcnt before the
// consuming MFMA/unpk) before that group's stores issue; prefetched loads for group g+1
// read rows disjoint from group g's stores; distinct blocks touch distinct rows.
// Round-9 delta vs round 6: r0/r1 residual loads moved into the prefetch macro (one
// group ahead) -- removes 8 L2-latency loads from each group's critical path (+8 VGPR).
#define P2_LOADM(BUF, G, MT) { \
  size_t R = (size_t)(gbase + (G)*256 + rowbase + (MT)*16 + ln15); \
  fo[BUF][MT] = *(const half8*)&o12g[R*32 + quad*8]; \
  fa[BUF][MT] = *(const half8*)&a2g [R*32 + quad*8]; \
  r0[BUF][MT] = *(const uint2*)&o12g[R*32 +      quad*4]; \
  r1[BUF][MT] = *(const uint2*)&o12g[R*32 + 16 + quad*4]; }
#define P2_LOAD(BUF, G) P2_LOADM(BUF,G,0) P2_LOADM(BUF,G,1) P2_LOADM(BUF,G,2) P2_LOADM(BUF,G,3)

template<bool F32>
__device__ __forceinline__ void pass2m_body(
    const void* pg2, const void* pb2, const void* pw2,
    const void* og2, const void* ob2, const void* ow2,
    float* __restrict__ S, u16* __restrict__ o12g, u16* __restrict__ a2g,
    u16* Wt, float* Cb, float* lds2)
{
  int tid = threadIdx.x;
  int wv = tid >> 6, lane = tid & 63;
  int ln15 = lane & 15, quad = lane >> 4;
  int gbase = blockIdx.x*1024;
  int shard = blockIdx.x & (NSH-1);
  int rowbase = wv*64;

  half8 fo[2][4], fa[2][4];
  uint2 r0[2][4], r1[2][4];
  P2_LOAD(0, 0)                       // group-0 operands: latency hides under fold2

  fold2<F32>(S, S_O1, S_A1, pg2,pb2,pw2, og2,ob2,ow2, Wt, Cb, lds2);

  half8 w0o = *(const half8*)&Wt[(ln15     )*XSTR + quad*8];
  half8 w1o = *(const half8*)&Wt[(ln15 + 16)*XSTR + quad*8];
  half8 w0a = *(const half8*)&Wt[(32 + ln15     )*XSTR + quad*8];
  half8 w1a = *(const half8*)&Wt[(32 + ln15 + 16)*XSTR + quad*8];
  float b0o[4], b1o[4], b0a[4], b1a[4];
#pragma unroll
  for (int reg=0;reg<4;++reg){
    b0o[reg] = Cb[     quad*4 + reg]; b1o[reg] = Cb[16 + quad*4 + reg];
    b0a[reg] = Cb[32 + quad*4 + reg]; b1a[reg] = Cb[48 + quad*4 + reg];
  }

  float s8o[8], q8o[8], s8a[8], q8a[8];
#pragma unroll
  for (int i=0;i<8;++i){ s8o[i]=0.f; q8o[i]=0.f; s8a[i]=0.f; q8a[i]=0.f; }

#pragma unroll
  for (int g=0; g<4; ++g){
    const int buf = g & 1;
    if (g < 3){ P2_LOAD(buf^1, g+1) }          // prefetch next group's operands+residuals
#pragma unroll
    for (int Mt=0; Mt<4; ++Mt){
      size_t R = (size_t)(gbase + g*256 + rowbase + Mt*16 + ln15);
      {   // o-side: o12 = o1 + tanh(fold(o1))
        f32x4 c0 = {0.f,0.f,0.f,0.f}, c1 = {0.f,0.f,0.f,0.f};
        c0 = __builtin_amdgcn_mfma_f32_16x16x32_f16(w0o, fo[buf][Mt], c0, 0,0,0);
        c1 = __builtin_amdgcn_mfma_f32_16x16x32_f16(w1o, fo[buf][Mt], c1, 0,0,0);
        float o0[4], o1v[4];
        unpk4(r0[buf][Mt], o0); unpk4(r1[buf][Mt], o1v);
        float v0[4], v1[4];
#pragma unroll
        for (int reg=0;reg<4;++reg){
          float a = o0[reg]  + tanh_fast(c0[reg] + b0o[reg]);
          float b = o1v[reg] + tanh_fast(c1[reg] + b1o[reg]);
          s8o[reg]   += a; q8o[reg]   = fmaf(a,a,q8o[reg]);
          s8o[4+reg] += b; q8o[4+reg] = fmaf(b,b,q8o[4+reg]);
          v0[reg] = a; v1[reg] = b;
        }
        uint2 wA, wB;
        wA.x = pack2h(v0[0], v0[1]); wA.y = pack2h(v0[2], v0[3]);
        wB.x = pack2h(v1[0], v1[1]); wB.y = pack2h(v1[2], v1[3]);
        *(uint2*)&o12g[R*32 +      quad*4] = wA;
        *(uint2*)&o12g[R*32 + 16 + quad*4] = wB;
      }
      {   // a-side: a2 = tanh(fold(a1))
        f32x4 c0 = {0.f,0.f,0.f,0.f}, c1 = {0.f,0.f,0.f,0.f};
        c0 = __builtin_amdgcn_mfma_f32_16x16x32_f16(w0a, fa[buf][Mt], c0, 0,0,0);
        c1 = __builtin_amdgcn_mfma_f32_16x16x32_f16(w1a, fa[buf][Mt], c1, 0,0,0);
        float v0[4], v1[4];
#pragma unroll
        for (int reg=0;reg<4;++reg){
          float a = tanh_fast(c0[reg] + b0a[reg]);
          float b = tanh_fast(c1[reg] + b1a[reg]);
          s8a[reg]   += a; q8a[reg]   = fmaf(a,a,q8a[reg]);
          s8a[4+reg] += b; q8a[4+reg] = fmaf(b,b,q8a[4+reg]);
          v0[reg] = a; v1[reg] = b;
        }
        uint2 wA, wB;
        wA.x = pack2h(v0[0], v0[1]); wA.y = pack2h(v0[2], v0[3]);
        wB.x = pack2h(v1[0], v1[1]); wB.y = pack2h(v1[2], v1[3]);
        *(uint2*)&a2g[R*32 +      quad*4] = wA;
        *(uint2*)&a2g[R*32 + 16 + quad*4] = wB;
      }
    }
  }
  emit_stats(s8o, q8o, tid, wv, quad, ln15, lds2, S, S_O12, shard);
  emit_stats(s8a, q8a, tid, wv, quad, ln15, lds2, S, S_A2, shard);
}
__global__ __launch_bounds__(256) void k_pass2m(const void* __restrict__ u,
    const void* pg2, const void* pb2, const void* pw2,
    const void* og2, const void* ob2, const void* ow2,
    float* __restrict__ S, u16* o12g, u16* a2g){
  __shared__ u16 Wt[2*32*XSTR];
  __shared__ float Cb[64];
  __shared__ float lds2[512];
  __shared__ int sf;
  int isf = detect_u((const u16*)u, threadIdx.x, &sf);
  if (isf) pass2m_body<true >(pg2,pb2,pw2,og2,ob2,ow2,S,o12g,a2g,Wt,Cb,lds2);
  else     pass2m_body<false>(pg2,pb2,pw2,og2,ob2,ow2,S,o12g,a2g,Wt,Cb,lds2);
}

// ---------------- pass2 (fallback, recompute, no stores; grid 2048) ----------------
template<int KIND>
__device__ __forceinline__ void mfma_stat_l(const u16* X, const u16* Wt, const float* Cb,
    int L, int wv, int lane, float* s8, float* q8)
{
  int ln15 = lane & 15, quad = lane >> 4;
  half8 w0 = *(const half8*)&Wt[(L*32 + ln15     )*XSTR + quad*8];
  half8 w1 = *(const half8*)&Wt[(L*32 + ln15 + 16)*XSTR + quad*8];
  float bias0[4], bias1[4];
#pragma unroll
  for (int reg=0;reg<4;++reg){
    bias0[reg] = Cb[L*32 +      quad*4 + reg];
    bias1[reg] = Cb[L*32 + 16 + quad*4 + reg];
  }
#pragma unroll
  for (int i=0;i<8;++i){ s8[i]=0.f; q8[i]=0.f; }
  int rowbase = wv*64;
#pragma unroll
  for (int Mt=0; Mt<4; ++Mt){
    int s = rowbase + Mt*16 + ln15;
    half8 bfr = *(const half8*)&X[s*XSTR + quad*8];
    f32x4 c0 = {0.f,0.f,0.f,0.f}, c1 = {0.f,0.f,0.f,0.f};
    c0 = __builtin_amdgcn_mfma_f32_16x16x32_f16(w0, bfr, c0, 0,0,0);
    c1 = __builtin_amdgcn_mfma_f32_16x16x32_f16(w1, bfr, c1, 0,0,0);
    float o0[4], o1v[4];
    if (KIND == KIND_TANHRES){
      unpk4(*(const uint2*)&X[s*XSTR +      quad*4], o0);
      unpk4(*(const uint2*)&X[s*XSTR + 16 + quad*4], o1v);
    }
#pragma unroll
    for (int reg=0;reg<4;++reg){
      float a = c0[reg] + bias0[reg];
      float b = c1[reg] + bias1[reg];
      if (KIND == KIND_TANH){ a = tanh_fast(a); b = tanh_fast(b); }
      else { a = o0[reg] + tanh_fast(a); b = o1v[reg] + tanh_fast(b); }
      s8[reg]   += a; q8[reg]   = fmaf(a,a,q8[reg]);
      s8[4+reg] += b; q8[4+reg] = fmaf(b,b,q8[4+reg]);
    }
  }
}
template<bool F32>
__device__ __forceinline__ void pass2_body(const void* __restrict__ u,
    const void* pg1, const void* pb1, const void* pw1,
    const void* og1, const void* ob1, const void* ow1,
    const void* pg2, const void* pb2, const void* pw2,
    const void* og2, const void* ob2, const void* ow2,
    float* __restrict__ S,
    u16* X, u16* Wt, float* Cb, float* lds2, float* mr)
{
  int tid = threadIdx.x;
  int wv = tid >> 6, lane = tid & 63;
  int ln15 = lane & 15, quad = lane >> 4;
  int r = blockIdx.x*256 + tid;
  int shard = blockIdx.x & (NSH-1);
  float f[4], xn[4];
  load_u4<F32>(u,r,f);
  prep_u_par(S, mr, lds2, tid);
  fold2<F32>(S, S_O1, S_A1, pg2,pb2,pw2, og2,ob2,ow2, Wt, Cb, lds2);

  float s8[8], q8[8];

  bn_u_l<F32>(mr, pg1, pb1, f, xn);
  chain1_out<F32,false>(xn, pw1, X + tid*XSTR, 0);
  __syncthreads();
  mfma_stat_l<KIND_TANHRES>(X, Wt, Cb, 0, wv, lane, s8, q8);
  emit_stats(s8, q8, tid, wv, quad, ln15, lds2, S, S_O12, shard);

  bn_u_l<F32>(mr, og1, ob1, f, xn);
  chain1_out<F32,false>(xn, ow1, X + tid*XSTR, 0);
  __syncthreads();
  mfma_stat_l<KIND_TANH>(X, Wt, Cb, 1, wv, lane, s8, q8);
  emit_stats(s8, q8, tid, wv, quad, ln15, lds2, S, S_A2, shard);
}
__global__ __launch_bounds__(256) void k_pass2(const void* __restrict__ u,
    const void* pg1, const void* pb1, const void* pw1,
    const void* og1, const void* ob1, const void* ow1,
    const void* pg2, const void* pb2, const void* pw2,
    const void* og2, const void* ob2, const void* ow2,
    float* __restrict__ S){
  __shared__ u16 X[256*XSTR];
  __shared__ u16 Wt[2*32*XSTR];
  __shared__ float Cb[64];
  __shared__ float lds2[512];
  __shared__ float mr[8];
  __shared__ int sf;
  int isf = detect_u((const u16*)u, threadIdx.x, &sf);
  if (isf) pass2_body<true >(u,pg1,pb1,pw1,og1,ob1,ow1,pg2,pb2,pw2,og2,ob2,ow2,S,X,Wt,Cb,lds2,mr);
  else     pass2_body<false>(u,pg1,pb1,pw1,og1,ob1,ow1,pg2,pb2,pw2,og2,ob2,ow2,S,X,Wt,Cb,lds2,mr);
}

// ---------------- pass3m (MAT): 512 blocks x 4 groups, dbuf prefetch (incl. residuals) ----------------
#define P3_LOADM(BUF, G, MT) { \
  size_t R = (size_t)(gbase + (G)*256 + rowbase + (MT)*16 + ln15); \
  fa[BUF][MT] = *(const half8*)&a2g [R*32 + quad*8]; \
  fo[BUF][MT] = *(const half8*)&o12g[R*32 + quad*8]; \
  r0[BUF][MT] = *(const uint2*)&o12g[R*32 +      quad*4]; \
  r1[BUF][MT] = *(const uint2*)&o12g[R*32 + 16 + quad*4]; }
#define P3_LOAD(BUF, G) P3_LOADM(BUF,G,0) P3_LOADM(BUF,G,1) P3_LOADM(BUF,G,2) P3_LOADM(BUF,G,3)

template<bool F32>
__device__ __forceinline__ void pass3m_body(const int* __restrict__ mask,
    const void* pg3, const void* pb3, const void* pw3,
    const void* og3, const void* ob3, const void* ow3,
    const u16* __restrict__ o12g, const u16* __restrict__ a2g,
    float* __restrict__ x, float* __restrict__ S,
    u16* Wt, float* Cb, float* lds2)
{
  int tid = threadIdx.x;
  int wv = tid >> 6, lane = tid & 63;
  int ln15 = lane & 15, quad = lane >> 4;
  int gbase = blockIdx.x*1024;
  int shard = blockIdx.x & (NSH-1);
  int rowbase = wv*64;

  half8 fa[2][4], fo[2][4];
  uint2 r0[2][4], r1[2][4];
  P3_LOAD(0, 0)

  // L0 = 3O (stats S_A2), L1 = 3P (stats S_O12)
  fold2<F32>(S, S_A2, S_O12, og3,ob3,ow3, pg3,pb3,pw3, Wt, Cb, lds2);

  half8 w0s = *(const half8*)&Wt[(ln15     )*XSTR + quad*8];
  half8 w1s = *(const half8*)&Wt[(ln15 + 16)*XSTR + quad*8];
  half8 w0p = *(const half8*)&Wt[(32 + ln15     )*XSTR + quad*8];
  half8 w1p = *(const half8*)&Wt[(32 + ln15 + 16)*XSTR + quad*8];
  float b0s[4], b1s[4], b0p[4], b1p[4];
#pragma unroll
  for (int reg=0;reg<4;++reg){
    b0s[reg] = Cb[     quad*4 + reg]; b1s[reg] = Cb[16 + quad*4 + reg];
    b0p[reg] = Cb[32 + quad*4 + reg]; b1p[reg] = Cb[48 + quad*4 + reg];
  }

#pragma unroll
  for (int g=0; g<4; ++g){
    const int buf = g & 1;
    if (g < 3){ P3_LOAD(buf^1, g+1) }
    int maskbase = gbase + g*256 + wv*64;
    u32 at_pk[16];
#pragma unroll
    for (int Mt=0; Mt<4; ++Mt){     // logits + softmax
      f32x4 c0 = {0.f,0.f,0.f,0.f}, c1 = {0.f,0.f,0.f,0.f};
      c0 = __builtin_amdgcn_mfma_f32_16x16x32_f16(w0s, fa[buf][Mt], c0, 0,0,0);
      c1 = __builtin_amdgcn_mfma_f32_16x16x32_f16(w1s, fa[buf][Mt], c1, 0,0,0);
      float l0[4], l1[4];
#pragma unroll
      for (int reg=0;reg<4;++reg){ l0[reg] = c0[reg]+b0s[reg]; l1[reg] = c1[reg]+b1s[reg]; }
      float mx = l0[0];
#pragma unroll
      for (int reg=1;reg<4;++reg) mx = fmaxf(mx, l0[reg]);
#pragma unroll
      for (int reg=0;reg<4;++reg) mx = fmaxf(mx, l1[reg]);
      mx = fmaxf(mx, __shfl_xor(mx, 16));
      mx = fmaxf(mx, __shfl_xor(mx, 32));
      float sum = 0.f;
#pragma unroll
      for (int reg=0;reg<4;++reg){ l0[reg] = __expf(l0[reg]-mx); sum += l0[reg]; }
#pragma unroll
      for (int reg=0;reg<4;++reg){ l1[reg] = __expf(l1[reg]-mx); sum += l1[reg]; }
      sum += __shfl_xor(sum, 16);
      sum += __shfl_xor(sum, 32);
      float inv = __builtin_amdgcn_rcpf(sum);
      bool mz = (mask[maskbase + Mt*16 + ln15] == 0);
#pragma unroll
      for (int reg=0;reg<4;++reg){
        l0[reg] *= inv; l1[reg] *= inv;
        if (mz){ l0[reg] = -__builtin_inff(); l1[reg] = -__builtin_inff(); }
      }
      at_pk[Mt*4+0] = pack2h(l0[0], l0[1]);
      at_pk[Mt*4+1] = pack2h(l0[2], l0[3]);
      at_pk[Mt*4+2] = pack2h(l1[0], l1[1]);
      at_pk[Mt*4+3] = pack2h(l1[2], l1[3]);
    }
    float ps[8];
#pragma unroll
    for (int i=0;i<8;++i) ps[i]=0.f;
#pragma unroll
    for (int Mt=0; Mt<4; ++Mt){     // (o3 + residual) * attn, pooled
      f32x4 c0 = {0.f,0.f,0.f,0.f}, c1 = {0.f,0.f,0.f,0.f};
      c0 = __builtin_amdgcn_mfma_f32_16x16x32_f16(w0p, fo[buf][Mt], c0, 0,0,0);
      c1 = __builtin_amdgcn_mfma_f32_16x16x32_f16(w1p, fo[buf][Mt], c1, 0,0,0);
      float o0[4], o1v[4];
      unpk4(r0[buf][Mt], o0); unpk4(r1[buf][Mt], o1v);
      float a0v[4], a1v[4];
      a0v[0]=lo16(at_pk[Mt*4+0]); a0v[1]=hi16(at_pk[Mt*4+0]);
      a0v[2]=lo16(at_pk[Mt*4+1]); a0v[3]=hi16(at_pk[Mt*4+1]);
      a1v[0]=lo16(at_pk[Mt*4+2]); a1v[1]=hi16(at_pk[Mt*4+2]);
      a1v[2]=lo16(at_pk[Mt*4+3]); a1v[3]=hi16(at_pk[Mt*4+3]);
#pragma unroll
      for (int reg=0;reg<4;++reg){
        float a = (o0[reg]  + tanh_fast(c0[reg]+b0p[reg])) * a0v[reg];
        float b = (o1v[reg] + tanh_fast(c1[reg]+b1p[reg])) * a1v[reg];
        ps[reg]   += a;
        ps[4+reg] += b;
      }
    }
#pragma unroll
    for (int i=0;i<8;++i) ps[i]=red16(ps[i]);
    __syncthreads();
    if (ln15 == 0){
#pragma unroll
      for (int rg=0; rg<4; ++rg){
        lds2[wv*32 + quad*4+rg]    = ps[rg];
        lds2[wv*32 + 16+quad*4+rg] = ps[4+rg];
      }
    }
    __syncthreads();
    if (tid < 64){
      int half = tid >> 5, j = tid & 31;
      float v = lds2[half*64 + j] + lds2[half*64 + 32 + j];
      x[((size_t)blockIdx.x*8 + g*2 + half)*32 + j] = v;
      float* Sh = S + shard*SHARD;
      atomicAdd(&Sh[S_X+j], v);
      atomicAdd(&Sh[S_X+32+j], v*v);
    }
  }
}
__global__ __launch_bounds__(256) void k_pass3m(const void* __restrict__ u, const int* __restrict__ mask,
    const void* pg3, const void* pb3, const void* pw3,
    const void* og3, const void* ob3, const void* ow3,
    const u16* o12g, const u16* a2g,
    float* __restrict__ x, float* __restrict__ S){
  __shared__ u16 Wt[2*32*XSTR];
  __shared__ float Cb[64];
  __shared__ float lds2[512];
  __shared__ int sf;
  int isf = detect_u((const u16*)u, threadIdx.x, &sf);
  if (isf) pass3m_body<true >(mask,pg3,pb3,pw3,og3,ob3,ow3,o12g,a2g,x,S,Wt,Cb,lds2);
  else     pass3m_body<false>(mask,pg3,pb3,pw3,og3,ob3,ow3,o12g,a2g,x,S,Wt,Cb,lds2);
}

// ---------------- pass3 (fallback, full recompute; grid 2048) ----------------
template<bool F32>
__device__ __forceinline__ void fold4(const float* __restrict__ S,
    int off0,int off1,int off2,int off3,
    const void* g0,const void* b0,const void* W0,
    const void* g1,const void* b1,const void* W1,
    const void* g2,const void* b2,const void* W2,
    const void* g3,const void* b3,const void* W3,
    u16* Wt, float* Cb, float* scr)
{
  int tid = threadIdx.x;
  __shared__ float scr2[256];
  if (tid < 128){
    int L = tid>>5, k = tid&31;
    const void* g = (L==0)?g0:(L==1)?g1:(L==2)?g2:g3;
    const void* b = (L==0)?b0:(L==1)?b1:(L==2)?b2:b3;
    int off = (L==0)?off0:(L==1)?off1:(L==2)?off2:off3;
    float s=0.f, q=0.f;
#pragma unroll
    for (int sh=0; sh<NSH; ++sh){
      s += S[sh*SHARD + off + k];
      q += S[sh*SHARD + off + 32 + k];
    }
    float m    = s*(1.0f/ROWS);
    float var  = q*(1.0f/ROWS) - m*m;
    float rstd = rsqrtf(var+EPS);
    float sc = rdp<F32>(g,k)*rstd;
    scr[tid]  = sc;
    scr2[tid] = rdp<F32>(b,k) - m*sc;
  }
  __syncthreads();
  if (tid < 128){
    int L = tid>>5, j = tid&31;
    const void* W = (L==0)?W0:(L==1)?W1:(L==2)?W2:W3;
    float c = 0.f;
#pragma unroll
    for (int k=0;k<32;++k){
      float Wv = rdp<F32>(W, j*32+k);
      Wt[(L*32+j)*XSTR + k] = f2h(Wv * scr[(L<<5)|k]);
      c += Wv * scr2[(L<<5)|k];
    }
    Cb[L*32+j] = c;
  }
  __syncthreads();
}

template<bool F32>
__device__ __forceinline__ void pass3_body(const void* __restrict__ u, const int* __restrict__ mask,
    const void* pg1, const void* pb1, const void* pw1,
    const void* og1, const void* ob1, const void* ow1,
    const void* pg2, const void* pb2, const void* pw2,
    const void* og2, const void* ob2, const void* ow2,
    const void* pg3, const void* pb3, const void* pw3,
    const void* og3, const void* ob3, const void* ow3,
    float* __restrict__ x, float* __restrict__ S,
    u16* X, u16* Wt, float* Cb, float* red2, float* mr)
{
  int tid = threadIdx.x;
  int wv = tid >> 6, lane = tid & 63;
  int r = blockIdx.x*256 + tid;
  float f[4], xn[4];
  load_u4<F32>(u,r,f);
  prep_u_par(S, mr, red2, tid);
  fold4<F32>(S, S_A1, S_A2, S_O1, S_O12,
             og2,ob2,ow2, og3,ob3,ow3, pg2,pb2,pw2, pg3,pb3,pw3,
             Wt, Cb, red2);

  u32 at_pk[16];
  int maskbase = blockIdx.x*256 + wv*64;

  bn_u_l<F32>(mr, og1, ob1, f, xn);
  chain1_out<F32,false>(xn, ow1, X + tid*XSTR, 0);
  mfma_layer<KIND_TANH>(X, Wt, Cb, 0, wv, lane, 0);
  {
    int ln15 = lane & 15, quad = lane >> 4;
    half8 w0 = *(const half8*)&Wt[(1*32 + ln15     )*XSTR + quad*8];
    half8 w1 = *(const half8*)&Wt[(1*32 + ln15 + 16)*XSTR + quad*8];
    float bias0[4], bias1[4];
#pragma unroll
    for (int reg=0;reg<4;++reg){
      bias0[reg] = Cb[32 +      quad*4 + reg];
      bias1[reg] = Cb[32 + 16 + quad*4 + reg];
    }
    int rowbase = wv*64;
#pragma unroll
    for (int Mt=0; Mt<4; ++Mt){
      int s = rowbase + Mt*16 + ln15;
      half8 bfr = *(const half8*)&X[s*XSTR + quad*8];
      f32x4 c0 = {0.f,0.f,0.f,0.f}, c1 = {0.f,0.f,0.f,0.f};
      c0 = __builtin_amdgcn_mfma_f32_16x16x32_f16(w0, bfr, c0, 0,0,0);
      c1 = __builtin_amdgcn_mfma_f32_16x16x32_f16(w1, bfr, c1, 0,0,0);
      float l0[4], l1[4];
#pragma unroll
      for (int reg=0;reg<4;++reg){ l0[reg] = c0[reg]+bias0[reg]; l1[reg] = c1[reg]+bias1[reg]; }
      float mx = l0[0];
#pragma unroll
      for (int reg=1;reg<4;++reg) mx = fmaxf(mx, l0[reg]);
#pragma unroll
      for (int reg=0;reg<4;++reg) mx = fmaxf(mx, l1[reg]);
      mx = fmaxf(mx, __shfl_xor(mx, 16));
      mx = fmaxf(mx, __shfl_xor(mx, 32));
      float sum = 0.f;
#pragma unroll
      for (int reg=0;reg<4;++reg){ l0[reg] = __expf(l0[reg]-mx); sum += l0[reg]; }
#pragma unroll
      for (int reg=0;reg<4;++reg){ l1[reg] = __expf(l1[reg]-mx); sum += l1[reg]; }
      sum += __shfl_xor(sum, 16);
      sum += __shfl_xor(sum, 32);
      float inv = __builtin_amdgcn_rcpf(sum);
      bool mz = (mask[maskbase + Mt*16 + ln15] == 0);
#pragma unroll
      for (int reg=0;reg<4;++reg){
        l0[reg] *= inv; l1[reg] *= inv;
        if (mz){ l0[reg] = -__builtin_inff(); l1[reg] = -__builtin_inff(); }
      }
      at_pk[Mt*4+0] = pack2h(l0[0], l0[1]);
      at_pk[Mt*4+1] = pack2h(l0[2], l0[3]);
      at_pk[Mt*4+2] = pack2h(l1[0], l1[1]);
      at_pk[Mt*4+3] = pack2h(l1[2], l1[3]);
    }
  }

  bn_u_l<F32>(mr, pg1, pb1, f, xn);
  chain1_out<F32,false>(xn, pw1, X + tid*XSTR, 0);
  mfma_layer<KIND_TANHRES   >(X, Wt, Cb, 2, wv, lane, 0);
  mfma_layer<KIND_TANHRES_ATREG>(X, Wt, Cb, 3, wv, lane, at_pk);

  __syncthreads();
  {
    int jj = tid & 31, cgrp = (tid >> 5) & 3, half = tid >> 7;
    float s2 = 0.f;
#pragma unroll
    for (int q2=0;q2<32;++q2) s2 += h2f(X[(half*128 + cgrp*32 + q2)*XSTR + jj]);
    red2[tid] = s2;
  }
  __syncthreads();
  if (tid < 64){
    int half = tid >> 5, j = tid & 31;
    float v = red2[half*128+j] + red2[half*128+32+j] + red2[half*128+64+j] + red2[half*128+96+j];
    x[(blockIdx.x*2 + half)*32 + j] = v;
    float* Sh = S + (blockIdx.x & (NSH-1))*SHARD;
    atomicAdd(&Sh[S_X+j], v);
    atomicAdd(&Sh[S_X+32+j], v*v);
  }
}
__global__ __launch_bounds__(256) void k_pass3(const void* __restrict__ u, const int* __restrict__ mask,
    const void* pg1, const void* pb1, const void* pw1,
    const void* og1, const void* ob1, const void* ow1,
    const void* pg2, const void* pb2, const void* pw2,
    const void* og2, const void* ob2, const void* ow2,
    const void* pg3, const void* pb3, const void* pw3,
    const void* og3, const void* ob3, const void* ow3,
    float* __restrict__ x, float* __restrict__ S){
  __shared__ u16 X [256*XSTR];
  __shared__ u16 Wt[4*32*XSTR];
  __shared__ float Cb[128];
  __shared__ float red2[256];
  __shared__ float mr[8];
  __shared__ int sf;
  int isf = detect_u((const u16*)u, threadIdx.x, &sf);
  if (isf) pass3_body<true >(u,mask,pg1,pb1,pw1,og1,ob1,ow1,pg2,pb2,pw2,og2,ob2,ow2,
                             pg3,pb3,pw3,og3,ob3,ow3,x,S,X,Wt,Cb,red2,mr);
  else     pass3_body<false>(u,mask,pg1,pb1,pw1,og1,ob1,ow1,pg2,pb2,pw2,og2,ob2,ow2,
                             pg3,pb3,pw3,og3,ob3,ow3,x,S,X,Wt,Cb,red2,mr);
}

// ---------------- theta chain: 4 small stream-ordered kernels ----------------
template<int NSH_IN>
__device__ __forceinline__ void theta_gather(const float* __restrict__ S, int off,
                                             float* scratch, float* lds2, int tid){
  int col = tid & 63, grp = tid >> 6;
  float t = 0.f;
#pragma unroll
  for (int i = 0; i < NSH_IN/4; ++i)
    t += S[(grp + i*4)*SHARD + off + col];
  scratch[tid] = t;
  __syncthreads();
  if (tid < 64)
    scratch[tid] = scratch[tid] + scratch[64+tid] + scratch[128+tid] + scratch[192+tid];
  __syncthreads();
  if (tid < 32){
    float m   = scratch[tid]*(1.0f/BROWS);
    float var = scratch[32+tid]*(1.0f/BROWS) - m*m;
    lds2[tid]    = m;
    lds2[32+tid] = rsqrtf(var + EPS);
  }
  __syncthreads();
}

template<bool F32>
__device__ __forceinline__ void theta_layer(float* v, const float* lds2,
    const void* g, const void* b, const void* W){
  float xn[32];
#pragma unroll
  for (int k=0;k<32;++k)
    xn[k] = (v[k] - lds2[k]) * (rdp<F32>(g,k)*lds2[32+k]) + rdp<F32>(b,k);
#pragma unroll
  for (int j=0;j<32;++j){
    float acc = 0.f;
#pragma unroll
    for (int k=0;k<32;++k) acc = fmaf(rdp<F32>(W, j*32+k), xn[k], acc);
    v[j] = tanh_fast(acc);
  }
}

template<bool F32, int NSH_IN>
__device__ __forceinline__ void theta_L_body(const float* __restrict__ xin,
    float* __restrict__ xout, float* __restrict__ S, int off_in, int off_out,
    const void* g, const void* b, const void* W, float* lds, float* lds2)
{
  int tid = threadIdx.x, blk = blockIdx.x;
  int r = blk*256 + tid;
  float v[32];
  {
    const float4* xr = (const float4*)&xin[(size_t)r*32];
#pragma unroll
    for (int k=0;k<8;++k){ float4 t = xr[k]; v[4*k]=t.x; v[4*k+1]=t.y; v[4*k+2]=t.z; v[4*k+3]=t.w; }
  }
  theta_gather<NSH_IN>(S, off_in, lds, lds2, tid);
  theta_layer<F32>(v, lds2, g, b, W);
  {
    float4* xw = (float4*)&xout[(size_t)r*32];
#pragma unroll
    for (int k=0;k<8;++k){ float4 t; t.x=v[4*k]; t.y=v[4*k+1]; t.z=v[4*k+2]; t.w=v[4*k+3]; xw[k]=t; }
  }
  float* Xp = lds + tid*33;
#pragma unroll
  for (int j=0;j<32;++j) Xp[j] = v[j];
  reduce_f32(lds, lds2, S, off_out, blk);   // shard = blk: zero contention
}
template<int NSH_IN>
__global__ __launch_bounds__(256) void k_theta_L(const void* __restrict__ u,
    const float* __restrict__ xin, float* __restrict__ xout,
    float* __restrict__ S, int off_in, int off_out,
    const void* g, const void* b, const void* W){
  __shared__ float lds[256*33];
  __shared__ float lds2[512];
  __shared__ int sf;
  int isf = detect_u((const u16*)u, threadIdx.x, &sf);
  if (isf) theta_L_body<true , NSH_IN>(xin, xout, S, off_in, off_out, g, b, W, lds, lds2);
  else     theta_L_body<false, NSH_IN>(xin, xout, S, off_in, off_out, g, b, W, lds, lds2);
}

template<bool F32>
__device__ __forceinline__ void theta_fin_body(const float* __restrict__ xin,
    float* __restrict__ S,
    const void* g4, const void* b4, const void* w4, const void* bb4,
    void* out, float* lds, float* lds2)
{
  int tid = threadIdx.x, blk = blockIdx.x;
  int r = blk*256 + tid;
  const float4* xr = (const float4*)&xin[(size_t)r*32];
  float4 t0 = xr[0], t1 = xr[1], t2 = xr[2], t3 = xr[3];
  float4 t4 = xr[4], t5 = xr[5], t6 = xr[6], t7 = xr[7];
  theta_gather<16>(S, S_X3, lds, lds2, tid);
  float vv[32];
  vv[0]=t0.x; vv[1]=t0.y; vv[2]=t0.z; vv[3]=t0.w;
  vv[4]=t1.x; vv[5]=t1.y; vv[6]=t1.z; vv[7]=t1.w;
  vv[8]=t2.x; vv[9]=t2.y; vv[10]=t2.z; vv[11]=t2.w;
  vv[12]=t3.x; vv[13]=t3.y; vv[14]=t3.z; vv[15]=t3.w;
  vv[16]=t4.x; vv[17]=t4.y; vv[18]=t4.z; vv[19]=t4.w;
  vv[20]=t5.x; vv[21]=t5.y; vv[22]=t5.z; vv[23]=t5.w;
  vv[24]=t6.x; vv[25]=t6.y; vv[26]=t6.z; vv[27]=t6.w;
  vv[28]=t7.x; vv[29]=t7.y; vv[30]=t7.z; vv[31]=t7.w;
  float acc = rdp<F32>(bb4, 0);
#pragma unroll
  for (int k=0;k<32;++k){
    float xnv = (vv[k] - lds2[k]) * (rdp<F32>(g4,k)*lds2[32+k]) + rdp<F32>(b4,k);
    acc = fmaf(rdp<F32>(w4,k), xnv, acc);
  }
  if (F32) ((float*)out)[r] = acc;
  else     ((u16*)out)[r]  = f2b(acc);
}
__global__ __launch_bounds__(256) void k_theta_fin(const void* __restrict__ u,
    const float* __restrict__ xin, float* __restrict__ S,
    const void* g4, const void* b4, const void* w4, const void* bb4,
    void* out){
  __shared__ float lds[256];
  __shared__ float lds2[512];
  __shared__ int sf;
  int isf = detect_u((const u16*)u, threadIdx.x, &sf);
  if (isf) theta_fin_body<true >(xin, S, g4, b4, w4, bb4, out, lds, lds2);
  else     theta_fin_body<false>(xin, S, g4, b4, w4, bb4, out, lds, lds2);
}

extern "C" void kernel_launch(void* const* d_in, const int* in_sizes, int n_in,
                              void* d_out, int out_size, void* d_ws, size_t ws_size,
                              hipStream_t stream)
{
  const void* u    = d_in[0];
  const int*  mask = (const int*)d_in[1];
  const void *pg1=d_in[2],  *pb1=d_in[3],  *pw1=d_in[4];
  const void *pg2=d_in[5],  *pb2=d_in[6],  *pw2=d_in[7];
  const void *pg3=d_in[8],  *pb3=d_in[9],  *pw3=d_in[10];
  const void *og1=d_in[11], *ob1=d_in[12], *ow1=d_in[13];
  const void *og2=d_in[14], *ob2=d_in[15], *ow2=d_in[16];
  const void *og3=d_in[17], *ob3=d_in[18], *ow3=d_in[19];
  const void *tg1=d_in[20], *tb1=d_in[21], *tw1=d_in[22];
  const void *tg2=d_in[23], *tb2=d_in[24], *tw2=d_in[25];
  const void *tg3=d_in[26], *tb3=d_in[27], *tw3=d_in[28];
  const void *tg4=d_in[29], *tb4=d_in[30], *tw4=d_in[31], *tbb4=d_in[32];

  char* ws = (char*)d_ws;
  float* S    = (float*)(ws + 4096);         // 64 shards x 1024 floats = 256 KB
  float* x    = (float*)(ws + 524288);       // 4096*32 f32 (512 KB)
  float* xb   = (float*)(ws + 1048576);      // ping-pong buffer (512 KB)

  const size_t MB = 1024*1024;
  u16* o12g = (u16*)(ws + 8*MB);             // 32 MB: o1 then (in-place) o12
  u16* a2g  = (u16*)(ws + 40*MB);            // 32 MB: a1 then (in-place) a2
  bool MAT = ws_size >= 73*MB;               // constant per process -> graph-safe

  (void)hipMemsetAsync(ws, 0, 4096 + NSH*SHARD*4, stream);  // zero sharded stats
  k_stats_u<<<1024, 256, 0, stream>>>(u, S);
  if (MAT){
    k_pass1<true ><<<512, 256, 0, stream>>>(u, pg1,pb1,pw1, og1,ob1,ow1, S, o12g, a2g);
    k_pass2m<<<512, 256, 0, stream>>>(u, pg2,pb2,pw2, og2,ob2,ow2, S, o12g, a2g);
    k_pass3m<<<512, 256, 0, stream>>>(u, mask, pg3,pb3,pw3, og3,ob3,ow3, o12g, a2g, x, S);
  } else {
    k_pass1<false><<<512, 256, 0, stream>>>(u, pg1,pb1,pw1, og1,ob1,ow1, S, o12g, a2g);
    k_pass2<<<2048, 256, 0, stream>>>(u, pg1,pb1,pw1, og1,ob1,ow1,
                                      pg2,pb2,pw2, og2,ob2,ow2, S);
    k_pass3<<<2048, 256, 0, stream>>>(u, mask, pg1,pb1,pw1, og1,ob1,ow1,
                                      pg2,pb2,pw2, og2,ob2,ow2,
                                      pg3,pb3,pw3, og3,ob3,ow3, x, S);
  }
  // theta chain: 4 tiny kernels; stream order supplies the global sync
  k_theta_L<64><<<16, 256, 0, stream>>>(u, x,  xb, S, S_X,  S_X1, tg1, tb1, tw1);
  k_theta_L<16><<<16, 256, 0, stream>>>(u, xb, x,  S, S_X1, S_X2, tg2, tb2, tw2);
  k_theta_L<16><<<16, 256, 0, stream>>>(u, x,  xb, S, S_X2, S_X3, tg3, tb3, tw3);
  k_theta_fin<<<16, 256, 0, stream>>>(u, xb, S, tg4, tb4, tw4, tbb4, d_out);
}

// Round 10
// 306.628 us; speedup vs baseline: 1.6177x; 1.3159x over previous
//
#include <hip/hip_runtime.h>

typedef unsigned int u32;
typedef unsigned short u16;
typedef __attribute__((ext_vector_type(8))) _Float16 half8;
typedef __attribute__((ext_vector_type(4))) float f32x4;

#define ROWS  524288   // B*N
#define BROWS 4096     // B
#define EPS   1e-5f

// ---- stats: 64 shards of 1024 floats; block-coop summing ----
#define S_U   0
#define S_O1  8
#define S_A1  72
#define S_O12 136
#define S_A2  200
#define S_X   264
#define S_X1  328
#define S_X2  392
#define S_X3  456
#define SHARD 1024
#define NSH   64

#define XSTR 40   // LDS row stride in u16 (80 B: 16B-aligned for uint4 rows)

__device__ __forceinline__ float bl(u32 u){ return __uint_as_float(u << 16); }
__device__ __forceinline__ float bh(u32 u){ return __uint_as_float(u & 0xFFFF0000u); }
__device__ __forceinline__ float b2f(u16 h){ return __uint_as_float(((u32)h) << 16); }
__device__ __forceinline__ u16 f2b(float f){
  u32 u = __float_as_uint(f);
  return (u16)((u + 0x7FFFu + ((u >> 16) & 1u)) >> 16);   // RNE (bf16, output only)
}
__device__ __forceinline__ u16 f2h(float f){ _Float16 h = (_Float16)f; return __builtin_bit_cast(u16, h); }
__device__ __forceinline__ float h2f(u16 x){ return (float)__builtin_bit_cast(_Float16, x); }
__device__ __forceinline__ u32 pack2h(float a, float b){
  auto v = __builtin_amdgcn_cvt_pkrtz(a, b);
  return __builtin_bit_cast(u32, v);
}
__device__ __forceinline__ float lo16(u32 w){ return h2f((u16)(w & 0xFFFF)); }
__device__ __forceinline__ float hi16(u32 w){ return h2f((u16)(w >> 16)); }
__device__ __forceinline__ void unpk4(uint2 v, float* d){
  d[0]=lo16(v.x); d[1]=hi16(v.x); d[2]=lo16(v.y); d[3]=hi16(v.y);
}

// Padé(5,4) tanh: no v_exp; err <= ~1e-3, clamped to [-1,1].
__device__ __forceinline__ float tanh_fast(float x){
  float x2 = x*x;
  float num = fmaf(x2 + 105.0f, x2, 945.0f) * x;
  float den = fmaf(fmaf(x2, 15.0f, 420.0f), x2, 945.0f);
  float v = num * __builtin_amdgcn_rcpf(den);
  return fminf(1.0f, fmaxf(-1.0f, v));
}

// sum over the 16-lane subgroup (xor masks 1,2,4,8 -> DPP-friendly)
__device__ __forceinline__ float red16(float v){
  v += __shfl_xor(v, 1);
  v += __shfl_xor(v, 2);
  v += __shfl_xor(v, 4);
  v += __shfl_xor(v, 8);
  return v;
}

template<bool F32>
__device__ __forceinline__ float rdp(const void* p, int i){
  if (F32) return ((const float*)p)[i];
  return b2f(((const u16*)p)[i]);
}
template<bool F32>
__device__ __forceinline__ void load_u4(const void* u, int r, float* f){
  if (F32){
    float4 v = ((const float4*)u)[r];
    f[0]=v.x; f[1]=v.y; f[2]=v.z; f[3]=v.w;
  } else {
    uint2 v = ((const uint2*)u)[r];
    f[0]=bl(v.x); f[1]=bh(v.x); f[2]=bl(v.y); f[3]=bh(v.y);
  }
}

// ---- per-block inline dtype detect ----
__device__ __forceinline__ int detect_u(const u16* __restrict__ u, int tid, int* sf){
  if (tid < 64){
    int bad = 0;
#pragma unroll
    for (int i = 0; i < 4; ++i){
      int e = (u[tid*4 + i] >> 7) & 0xFF;
      bad += (e >= 0x90) ? 1 : 0;
    }
#pragma unroll
    for (int off = 32; off >= 1; off >>= 1) bad += __shfl_down(bad, off);
    if (tid == 0) *sf = (bad >= 4) ? 1 : 0;
  }
  __syncthreads();
  return *sf;
}

// ---------------- stats of u (4 cols) ----------------
template<bool F32>
__device__ __forceinline__ void stats_u_body(const void* __restrict__ u, float* __restrict__ S){
  int tid = blockIdx.x*blockDim.x + threadIdx.x;
  int nt  = gridDim.x*blockDim.x;
  float s[4]={0,0,0,0}, q[4]={0,0,0,0};
  for (int r = tid; r < ROWS; r += nt){
    float f[4]; load_u4<F32>(u, r, f);
#pragma unroll
    for (int k=0;k<4;++k){ s[k]+=f[k]; q[k]+=f[k]*f[k]; }
  }
#pragma unroll
  for (int off=32; off>=1; off>>=1){
#pragma unroll
    for (int k=0;k<4;++k){ s[k]+=__shfl_down(s[k],off); q[k]+=__shfl_down(q[k],off); }
  }
  if ((threadIdx.x & 63) == 0){
    float* Sh = S + (blockIdx.x & (NSH-1))*SHARD;
#pragma unroll
    for (int k=0;k<4;++k){ atomicAdd(&Sh[S_U+k], s[k]); atomicAdd(&Sh[S_U+4+k], q[k]); }
  }
}
__global__ __launch_bounds__(256) void k_stats_u(const void* __restrict__ u, float* __restrict__ S){
  __shared__ int sf;
  int isf = detect_u((const u16*)u, threadIdx.x, &sf);
  if (isf) stats_u_body<true>(u,S); else stats_u_body<false>(u,S);
}

// ---------------- block preamble: m/rstd of u (parallel gather, 256 threads) ----------------
__device__ __forceinline__ void prep_u_par(const float* __restrict__ S, float* mr,
                                           float* scr /*256 floats*/, int tid){
  {
    int col = tid & 3, isq = (tid >> 2) & 1, grp = tid >> 3;   // grp 0..31, 2 shards each
    float t = S[(grp*2+0)*SHARD + S_U + isq*4 + col]
            + S[(grp*2+1)*SHARD + S_U + isq*4 + col];
    scr[tid] = t;
  }
  __syncthreads();
  if (tid < 8){
    float t = 0.f;
#pragma unroll
    for (int g=0; g<32; ++g) t += scr[tid + 8*g];
    mr[tid] = t;                                   // raw sums: [0..3]=s, [4..7]=q
  }
  __syncthreads();
  if (tid < 4){
    float s = mr[tid], q = mr[4+tid];
    float m = s*(1.0f/ROWS);
    float var = q*(1.0f/ROWS) - m*m;
    mr[tid]   = m;
    mr[4+tid] = rsqrtf(var + EPS);
  }
  __syncthreads();
}
template<bool F32>
__device__ __forceinline__ void bn_u_l(const float* mr, const void* g, const void* b,
                                       const float* f, float* xn){
#pragma unroll
  for (int k=0;k<4;++k)
    xn[k] = (f[k]-mr[k])*(rdp<F32>(g,k)*mr[4+k]) + rdp<F32>(b,k);
}

// ---------------- L1 chain -> f16 LDS row (+ optional global row) ----------------
template<bool F32, bool STORE>
__device__ __forceinline__ void chain1_out(const float* xn, const void* W1, u16* Xrow,
                                           u16* __restrict__ grow){
  u32 buf[16];
#pragma unroll
  for (int jp=0; jp<16; ++jp){
    int j0 = 2*jp, j1 = 2*jp+1;
    float a0 = tanh_fast(xn[0]*rdp<F32>(W1,j0*4+0) + xn[1]*rdp<F32>(W1,j0*4+1)
                       + xn[2]*rdp<F32>(W1,j0*4+2) + xn[3]*rdp<F32>(W1,j0*4+3));
    float a1 = tanh_fast(xn[0]*rdp<F32>(W1,j1*4+0) + xn[1]*rdp<F32>(W1,j1*4+1)
                       + xn[2]*rdp<F32>(W1,j1*4+2) + xn[3]*rdp<F32>(W1,j1*4+3));
    buf[jp] = pack2h(a0, a1);
  }
#pragma unroll
  for (int c=0;c<4;++c){
    uint4 v; v.x = buf[c*4]; v.y = buf[c*4+1]; v.z = buf[c*4+2]; v.w = buf[c*4+3];
    *(uint4*)&Xrow[c*8] = v;
    if (STORE) *(uint4*)&grow[c*8] = v;
  }
}

// ---------------- in-block BN+Linear folds (parallel 256-thread gather) ----------------
template<bool F32>
__device__ __forceinline__ void fold2(const float* __restrict__ S, int offA, int offB,
    const void* gA, const void* bA, const void* WA,
    const void* gB, const void* bB, const void* WB,
    u16* Wt, float* Cb, float* scr /* 512 floats */)
{
  int tid = threadIdx.x;
  {
    int pair = tid >> 2;            // 0..63 : L=pair>>5, k=pair&31
    int isq  = (tid >> 1) & 1;      // 0=sum, 1=sumsq
    int half = tid & 1;             // shard half
    int L = pair >> 5, k = pair & 31;
    int off = (L ? offB : offA) + isq*32 + k;
    float t = 0.f;
#pragma unroll
    for (int i=0;i<32;++i)
      t += S[(half*32 + i)*SHARD + off];
    scr[tid] = t;                   // tid = pair*4 + isq*2 + half
  }
  __syncthreads();
  if (tid < 64){
    int L = tid>>5, k = tid&31;
    const void* g = L? gB:gA; const void* b = L? bB:bA;
    float s = scr[tid*4+0] + scr[tid*4+1];
    float q = scr[tid*4+2] + scr[tid*4+3];
    float m    = s*(1.0f/ROWS);
    float var  = q*(1.0f/ROWS) - m*m;
    float rstd = rsqrtf(var+EPS);
    float sc = rdp<F32>(g,k)*rstd;
    scr[256+tid] = sc;
    scr[320+tid] = rdp<F32>(b,k) - m*sc;
  }
  __syncthreads();
  if (tid < 64){
    int L = tid>>5, j = tid&31;
    const void* W = L? WB:WA;
    float c = 0.f;
#pragma unroll
    for (int k=0;k<32;++k){
      float Wv = rdp<F32>(W, j*32+k);
      Wt[(L*32+j)*XSTR + k] = f2h(Wv * scr[256 + ((L<<5)|k)]);
      c += Wv * scr[320 + ((L<<5)|k)];
    }
    Cb[L*32+j] = c;
  }
  __syncthreads();
}

// ---------------- MFMA layer (LDS in/out) -- used by fallback pass3 ----------------
#define KIND_TANH          0
#define KIND_TANHRES       2
#define KIND_TANHRES_ATREG 3
template<int KIND>
__device__ __forceinline__ void mfma_layer(u16* X, const u16* Wt, const float* Cb,
                                           int L, int wv, int lane, const u32* at_pk)
{
  int ln15 = lane & 15, quad = lane >> 4;
  half8 w0 = *(const half8*)&Wt[(L*32 + ln15     )*XSTR + quad*8];
  half8 w1 = *(const half8*)&Wt[(L*32 + ln15 + 16)*XSTR + quad*8];
  float bias0[4], bias1[4];
#pragma unroll
  for (int reg=0;reg<4;++reg){
    bias0[reg] = Cb[L*32 +      quad*4 + reg];
    bias1[reg] = Cb[L*32 + 16 + quad*4 + reg];
  }
  int rowbase = wv*64;
#pragma unroll
  for (int Mt=0; Mt<4; ++Mt){
    int s = rowbase + Mt*16 + ln15;
    half8 bfr = *(const half8*)&X[s*XSTR + quad*8];
    f32x4 c0 = {0.f,0.f,0.f,0.f}, c1 = {0.f,0.f,0.f,0.f};
    c0 = __builtin_amdgcn_mfma_f32_16x16x32_f16(w0, bfr, c0, 0,0,0);
    c1 = __builtin_amdgcn_mfma_f32_16x16x32_f16(w1, bfr, c1, 0,0,0);
    float o0[4], o1v[4];
    if (KIND == KIND_TANHRES || KIND == KIND_TANHRES_ATREG){
      unpk4(*(const uint2*)&X[s*XSTR +      quad*4], o0);
      unpk4(*(const uint2*)&X[s*XSTR + 16 + quad*4], o1v);
    }
    float a0v[4], a1v[4];
    if (KIND == KIND_TANHRES_ATREG){
      a0v[0]=lo16(at_pk[Mt*4+0]); a0v[1]=hi16(at_pk[Mt*4+0]);
      a0v[2]=lo16(at_pk[Mt*4+1]); a0v[3]=hi16(at_pk[Mt*4+1]);
      a1v[0]=lo16(at_pk[Mt*4+2]); a1v[1]=hi16(at_pk[Mt*4+2]);
      a1v[2]=lo16(at_pk[Mt*4+3]); a1v[3]=hi16(at_pk[Mt*4+3]);
    }
    float v0[4], v1[4];
#pragma unroll
    for (int reg=0;reg<4;++reg){
      float a = c0[reg] + bias0[reg];
      float b = c1[reg] + bias1[reg];
      if (KIND == KIND_TANH){ a = tanh_fast(a); b = tanh_fast(b); }
      else if (KIND == KIND_TANHRES){ a = o0[reg] + tanh_fast(a); b = o1v[reg] + tanh_fast(b); }
      else if (KIND == KIND_TANHRES_ATREG){
        a = (o0[reg] + tanh_fast(a)) * a0v[reg];
        b = (o1v[reg] + tanh_fast(b)) * a1v[reg];
      }
      v0[reg] = a; v1[reg] = b;
    }
    uint2 w0o, w1o;
    w0o.x = pack2h(v0[0], v0[1]); w0o.y = pack2h(v0[2], v0[3]);
    w1o.x = pack2h(v1[0], v1[1]); w1o.y = pack2h(v1[2], v1[3]);
    *(uint2*)&X[s*XSTR +      quad*4] = w0o;
    *(uint2*)&X[s*XSTR + 16 + quad*4] = w1o;
  }
}

// cross-lane (16 rows) + cross-wave combine of per-lane col stats -> sharded atomics
__device__ __forceinline__ void emit_stats(float* s8, float* q8, int tid, int wv,
    int quad, int ln15, float* scr /*512*/, float* __restrict__ S, int offS, int shard)
{
#pragma unroll
  for (int i=0;i<8;++i){ s8[i]=red16(s8[i]); q8[i]=red16(q8[i]); }
  __syncthreads();                 // protect scr reuse
  if (ln15 == 0){
#pragma unroll
    for (int rg=0; rg<4; ++rg){
      int cl = quad*4+rg, ch = 16+quad*4+rg;
      scr[wv*64 + cl]       = s8[rg];
      scr[wv*64 + ch]       = s8[4+rg];
      scr[256 + wv*64 + cl] = q8[rg];
      scr[256 + wv*64 + ch] = q8[4+rg];
    }
  }
  __syncthreads();
  if (tid < 64){
    int j = tid & 31, isq = tid >> 5;
    const float* src = scr + isq*256;
    float tot = src[j] + src[64+j] + src[128+j] + src[192+j];
    atomicAdd(&S[shard*SHARD + offS + isq*32 + j], tot);
  }
}

// ---------------- column stats reducers ----------------
__device__ __forceinline__ void reduce_f16(const u16* X, float* lds2,
                                           float* __restrict__ S, int offS, int shard)
{
  int tid = threadIdx.x;
  __syncthreads();
  {
    int j = tid & 31, seg = tid >> 5;
    float s=0.f, q=0.f;
#pragma unroll
    for (int q2=0;q2<32;++q2){
      float v = h2f(X[(seg*32+q2)*XSTR + j]);
      s += v; q = fmaf(v,v,q);
    }
    lds2[seg*32+j] = s;
    lds2[256 + seg*32+j] = q;
  }
  __syncthreads();
  if (tid < 64){
    int j = tid & 31; bool isq = tid >= 32;
    const float* src = lds2 + (isq?256:0);
    float tot=0.f;
#pragma unroll
    for (int sg=0;sg<8;++sg) tot += src[sg*32+j];
    atomicAdd(&S[shard*SHARD + offS + (isq?32:0) + j], tot);
  }
  __syncthreads();
}

__device__ __forceinline__ void reduce_f32(const float* Xs, float* lds2,
                                           float* __restrict__ S, int offS, int shard)
{
  int tid = threadIdx.x;
  __syncthreads();
  {
    int j = tid & 31, seg = tid >> 5;
    float s=0.f, q=0.f;
#pragma unroll
    for (int q2=0;q2<32;++q2){
      float v = Xs[(seg*32+q2)*33 + j];
      s += v; q = fmaf(v,v,q);
    }
    lds2[seg*32+j] = s;
    lds2[256 + seg*32+j] = q;
  }
  __syncthreads();
  if (tid < 64){
    int j = tid & 31; bool isq = tid >= 32;
    const float* src = lds2 + (isq?256:0);
    float tot=0.f;
#pragma unroll
    for (int sg=0;sg<8;++sg) tot += src[sg*32+j];
    atomicAdd(&S[shard*SHARD + offS + (isq?32:0) + j], tot);
  }
  __syncthreads();
}

// ---------------- pass1: 512 blocks x 4 row-groups; chains o1/a1; stats ----------------
template<bool F32, bool MAT>
__device__ __forceinline__ void pass1_body(const void* __restrict__ u,
    const void* pg1, const void* pb1, const void* pw1,
    const void* og1, const void* ob1, const void* ow1,
    float* __restrict__ S, u16* __restrict__ o1g, u16* __restrict__ a1g,
    u16* X, float* lds2, float* mr)
{
  int tid = threadIdx.x;
  int base = blockIdx.x*1024;
  int shard = blockIdx.x & (NSH-1);
  float f[4][4];
#pragma unroll
  for (int g=0; g<4; ++g) load_u4<F32>(u, base + g*256 + tid, f[g]);  // issued before gather
  prep_u_par(S, mr, lds2, tid);

#pragma unroll
  for (int g=0; g<4; ++g){
    int r = base + g*256 + tid;
    float xn[4];
    bn_u_l<F32>(mr, pg1, pb1, f[g], xn);
    chain1_out<F32,MAT>(xn, pw1, X + tid*XSTR, o1g + (size_t)r*32);
    reduce_f16(X, lds2, S, S_O1, shard);

    bn_u_l<F32>(mr, og1, ob1, f[g], xn);
    chain1_out<F32,MAT>(xn, ow1, X + tid*XSTR, a1g + (size_t)r*32);
    reduce_f16(X, lds2, S, S_A1, shard);
  }
}
template<bool MAT>
__global__ __launch_bounds__(256) void k_pass1(const void* __restrict__ u,
    const void* pg1, const void* pb1, const void* pw1,
    const void* og1, const void* ob1, const void* ow1,
    float* __restrict__ S, u16* o1g, u16* a1g){
  __shared__ u16 X[256*XSTR];
  __shared__ float lds2[512];
  __shared__ float mr[8];
  __shared__ int sf;
  int isf = detect_u((const u16*)u, threadIdx.x, &sf);
  if (isf) pass1_body<true ,MAT>(u,pg1,pb1,pw1,og1,ob1,ow1,S,o1g,a1g,X,lds2,mr);
  else     pass1_body<false,MAT>(u,pg1,pb1,pw1,og1,ob1,ow1,S,o1g,a1g,X,lds2,mr);
}

// ---------------- pass2m (MAT): 512 blocks x 4 groups, dbuf prefetch, in-place ----------------
// In-place safety is by dataflow: each group's loads are consumed (hw waitcnt before the
// consuming MFMA/unpk) before that group's stores issue; distinct groups touch distinct rows.
// NOTE (r7/r9 lessons): the in-block fold2 is load-bearing (latency hider + wave phase-lock
// for L2 write-merge), and the r0/r1 residual loads are per-group L1 hits (same lines as
// the fo prefetch) -- do NOT hoist either.
#define P2_LOADM(BUF, G, MT) { \
  size_t R = (size_t)(gbase + (G)*256 + rowbase + (MT)*16 + ln15); \
  fo[BUF][MT] = *(const half8*)&o12g[R*32 + quad*8]; \
  fa[BUF][MT] = *(const half8*)&a2g [R*32 + quad*8]; }
#define P2_LOAD(BUF, G) P2_LOADM(BUF,G,0) P2_LOADM(BUF,G,1) P2_LOADM(BUF,G,2) P2_LOADM(BUF,G,3)

template<bool F32>
__device__ __forceinline__ void pass2m_body(
    const void* pg2, const void* pb2, const void* pw2,
    const void* og2, const void* ob2, const void* ow2,
    float* __restrict__ S, u16* __restrict__ o12g, u16* __restrict__ a2g,
    u16* Wt, float* Cb, float* lds2)
{
  int tid = threadIdx.x;
  int wv = tid >> 6, lane = tid & 63;
  int ln15 = lane & 15, quad = lane >> 4;
  int gbase = blockIdx.x*1024;
  int shard = blockIdx.x & (NSH-1);
  int rowbase = wv*64;

  half8 fo[2][4], fa[2][4];
  P2_LOAD(0, 0)                       // group-0 operands: latency hides under fold2

  fold2<F32>(S, S_O1, S_A1, pg2,pb2,pw2, og2,ob2,ow2, Wt, Cb, lds2);

  half8 w0o = *(const half8*)&Wt[(ln15     )*XSTR + quad*8];
  half8 w1o = *(const half8*)&Wt[(ln15 + 16)*XSTR + quad*8];
  half8 w0a = *(const half8*)&Wt[(32 + ln15     )*XSTR + quad*8];
  half8 w1a = *(const half8*)&Wt[(32 + ln15 + 16)*XSTR + quad*8];
  float b0o[4], b1o[4], b0a[4], b1a[4];
#pragma unroll
  for (int reg=0;reg<4;++reg){
    b0o[reg] = Cb[     quad*4 + reg]; b1o[reg] = Cb[16 + quad*4 + reg];
    b0a[reg] = Cb[32 + quad*4 + reg]; b1a[reg] = Cb[48 + quad*4 + reg];
  }

  float s8o[8], q8o[8], s8a[8], q8a[8];
#pragma unroll
  for (int i=0;i<8;++i){ s8o[i]=0.f; q8o[i]=0.f; s8a[i]=0.f; q8a[i]=0.f; }

#pragma unroll
  for (int g=0; g<4; ++g){
    const int buf = g & 1;
    if (g < 3){ P2_LOAD(buf^1, g+1) }          // prefetch next group's operands
    uint2 r0[4], r1[4];                        // residuals for this group (L1 hits)
#pragma unroll
    for (int Mt=0; Mt<4; ++Mt){
      size_t R = (size_t)(gbase + g*256 + rowbase + Mt*16 + ln15);
      r0[Mt] = *(const uint2*)&o12g[R*32 +      quad*4];
      r1[Mt] = *(const uint2*)&o12g[R*32 + 16 + quad*4];
    }
#pragma unroll
    for (int Mt=0; Mt<4; ++Mt){
      size_t R = (size_t)(gbase + g*256 + rowbase + Mt*16 + ln15);
      {   // o-side: o12 = o1 + tanh(fold(o1))
        f32x4 c0 = {0.f,0.f,0.f,0.f}, c1 = {0.f,0.f,0.f,0.f};
        c0 = __builtin_amdgcn_mfma_f32_16x16x32_f16(w0o, fo[buf][Mt], c0, 0,0,0);
        c1 = __builtin_amdgcn_mfma_f32_16x16x32_f16(w1o, fo[buf][Mt], c1, 0,0,0);
        float o0[4], o1v[4];
        unpk4(r0[Mt], o0); unpk4(r1[Mt], o1v);
        float v0[4], v1[4];
#pragma unroll
        for (int reg=0;reg<4;++reg){
          float a = o0[reg]  + tanh_fast(c0[reg] + b0o[reg]);
          float b = o1v[reg] + tanh_fast(c1[reg] + b1o[reg]);
          s8o[reg]   += a; q8o[reg]   = fmaf(a,a,q8o[reg]);
          s8o[4+reg] += b; q8o[4+reg] = fmaf(b,b,q8o[4+reg]);
          v0[reg] = a; v1[reg] = b;
        }
        uint2 wA, wB;
        wA.x = pack2h(v0[0], v0[1]); wA.y = pack2h(v0[2], v0[3]);
        wB.x = pack2h(v1[0], v1[1]); wB.y = pack2h(v1[2], v1[3]);
        *(uint2*)&o12g[R*32 +      quad*4] = wA;
        *(uint2*)&o12g[R*32 + 16 + quad*4] = wB;
      }
      {   // a-side: a2 = tanh(fold(a1))
        f32x4 c0 = {0.f,0.f,0.f,0.f}, c1 = {0.f,0.f,0.f,0.f};
        c0 = __builtin_amdgcn_mfma_f32_16x16x32_f16(w0a, fa[buf][Mt], c0, 0,0,0);
        c1 = __builtin_amdgcn_mfma_f32_16x16x32_f16(w1a, fa[buf][Mt], c1, 0,0,0);
        float v0[4], v1[4];
#pragma unroll
        for (int reg=0;reg<4;++reg){
          float a = tanh_fast(c0[reg] + b0a[reg]);
          float b = tanh_fast(c1[reg] + b1a[reg]);
          s8a[reg]   += a; q8a[reg]   = fmaf(a,a,q8a[reg]);
          s8a[4+reg] += b; q8a[4+reg] = fmaf(b,b,q8a[4+reg]);
          v0[reg] = a; v1[reg] = b;
        }
        uint2 wA, wB;
        wA.x = pack2h(v0[0], v0[1]); wA.y = pack2h(v0[2], v0[3]);
        wB.x = pack2h(v1[0], v1[1]); wB.y = pack2h(v1[2], v1[3]);
        *(uint2*)&a2g[R*32 +      quad*4] = wA;
        *(uint2*)&a2g[R*32 + 16 + quad*4] = wB;
      }
    }
  }
  emit_stats(s8o, q8o, tid, wv, quad, ln15, lds2, S, S_O12, shard);
  emit_stats(s8a, q8a, tid, wv, quad, ln15, lds2, S, S_A2, shard);
}
__global__ __launch_bounds__(256) void k_pass2m(const void* __restrict__ u,
    const void* pg2, const void* pb2, const void* pw2,
    const void* og2, const void* ob2, const void* ow2,
    float* __restrict__ S, u16* o12g, u16* a2g){
  __shared__ u16 Wt[2*32*XSTR];
  __shared__ float Cb[64];
  __shared__ float lds2[512];
  __shared__ int sf;
  int isf = detect_u((const u16*)u, threadIdx.x, &sf);
  if (isf) pass2m_body<true >(pg2,pb2,pw2,og2,ob2,ow2,S,o12g,a2g,Wt,Cb,lds2);
  else     pass2m_body<false>(pg2,pb2,pw2,og2,ob2,ow2,S,o12g,a2g,Wt,Cb,lds2);
}

// ---------------- pass2 (fallback, recompute, no stores; grid 2048) ----------------
template<int KIND>
__device__ __forceinline__ void mfma_stat_l(const u16* X, const u16* Wt, const float* Cb,
    int L, int wv, int lane, float* s8, float* q8)
{
  int ln15 = lane & 15, quad = lane >> 4;
  half8 w0 = *(const half8*)&Wt[(L*32 + ln15     )*XSTR + quad*8];
  half8 w1 = *(const half8*)&Wt[(L*32 + ln15 + 16)*XSTR + quad*8];
  float bias0[4], bias1[4];
#pragma unroll
  for (int reg=0;reg<4;++reg){
    bias0[reg] = Cb[L*32 +      quad*4 + reg];
    bias1[reg] = Cb[L*32 + 16 + quad*4 + reg];
  }
#pragma unroll
  for (int i=0;i<8;++i){ s8[i]=0.f; q8[i]=0.f; }
  int rowbase = wv*64;
#pragma unroll
  for (int Mt=0; Mt<4; ++Mt){
    int s = rowbase + Mt*16 + ln15;
    half8 bfr = *(const half8*)&X[s*XSTR + quad*8];
    f32x4 c0 = {0.f,0.f,0.f,0.f}, c1 = {0.f,0.f,0.f,0.f};
    c0 = __builtin_amdgcn_mfma_f32_16x16x32_f16(w0, bfr, c0, 0,0,0);
    c1 = __builtin_amdgcn_mfma_f32_16x16x32_f16(w1, bfr, c1, 0,0,0);
    float o0[4], o1v[4];
    if (KIND == KIND_TANHRES){
      unpk4(*(const uint2*)&X[s*XSTR +      quad*4], o0);
      unpk4(*(const uint2*)&X[s*XSTR + 16 + quad*4], o1v);
    }
#pragma unroll
    for (int reg=0;reg<4;++reg){
      float a = c0[reg] + bias0[reg];
      float b = c1[reg] + bias1[reg];
      if (KIND == KIND_TANH){ a = tanh_fast(a); b = tanh_fast(b); }
      else { a = o0[reg] + tanh_fast(a); b = o1v[reg] + tanh_fast(b); }
      s8[reg]   += a; q8[reg]   = fmaf(a,a,q8[reg]);
      s8[4+reg] += b; q8[4+reg] = fmaf(b,b,q8[4+reg]);
    }
  }
}
template<bool F32>
__device__ __forceinline__ void pass2_body(const void* __restrict__ u,
    const void* pg1, const void* pb1, const void* pw1,
    const void* og1, const void* ob1, const void* ow1,
    const void* pg2, const void* pb2, const void* pw2,
    const void* og2, const void* ob2, const void* ow2,
    float* __restrict__ S,
    u16* X, u16* Wt, float* Cb, float* lds2, float* mr)
{
  int tid = threadIdx.x;
  int wv = tid >> 6, lane = tid & 63;
  int ln15 = lane & 15, quad = lane >> 4;
  int r = blockIdx.x*256 + tid;
  int shard = blockIdx.x & (NSH-1);
  float f[4], xn[4];
  load_u4<F32>(u,r,f);
  prep_u_par(S, mr, lds2, tid);
  fold2<F32>(S, S_O1, S_A1, pg2,pb2,pw2, og2,ob2,ow2, Wt, Cb, lds2);

  float s8[8], q8[8];

  bn_u_l<F32>(mr, pg1, pb1, f, xn);
  chain1_out<F32,false>(xn, pw1, X + tid*XSTR, 0);
  __syncthreads();
  mfma_stat_l<KIND_TANHRES>(X, Wt, Cb, 0, wv, lane, s8, q8);
  emit_stats(s8, q8, tid, wv, quad, ln15, lds2, S, S_O12, shard);

  bn_u_l<F32>(mr, og1, ob1, f, xn);
  chain1_out<F32,false>(xn, ow1, X + tid*XSTR, 0);
  __syncthreads();
  mfma_stat_l<KIND_TANH>(X, Wt, Cb, 1, wv, lane, s8, q8);
  emit_stats(s8, q8, tid, wv, quad, ln15, lds2, S, S_A2, shard);
}
__global__ __launch_bounds__(256) void k_pass2(const void* __restrict__ u,
    const void* pg1, const void* pb1, const void* pw1,
    const void* og1, const void* ob1, const void* ow1,
    const void* pg2, const void* pb2, const void* pw2,
    const void* og2, const void* ob2, const void* ow2,
    float* __restrict__ S){
  __shared__ u16 X[256*XSTR];
  __shared__ u16 Wt[2*32*XSTR];
  __shared__ float Cb[64];
  __shared__ float lds2[512];
  __shared__ float mr[8];
  __shared__ int sf;
  int isf = detect_u((const u16*)u, threadIdx.x, &sf);
  if (isf) pass2_body<true >(u,pg1,pb1,pw1,og1,ob1,ow1,pg2,pb2,pw2,og2,ob2,ow2,S,X,Wt,Cb,lds2,mr);
  else     pass2_body<false>(u,pg1,pb1,pw1,og1,ob1,ow1,pg2,pb2,pw2,og2,ob2,ow2,S,X,Wt,Cb,lds2,mr);
}

// ---------------- pass3m (MAT): 512 blocks x 4 groups, dbuf prefetch ----------------
#define P3_LOADM(BUF, G, MT) { \
  size_t R = (size_t)(gbase + (G)*256 + rowbase + (MT)*16 + ln15); \
  fa[BUF][MT] = *(const half8*)&a2g [R*32 + quad*8]; \
  fo[BUF][MT] = *(const half8*)&o12g[R*32 + quad*8]; }
#define P3_LOAD(BUF, G) P3_LOADM(BUF,G,0) P3_LOADM(BUF,G,1) P3_LOADM(BUF,G,2) P3_LOADM(BUF,G,3)

template<bool F32>
__device__ __forceinline__ void pass3m_body(const int* __restrict__ mask,
    const void* pg3, const void* pb3, const void* pw3,
    const void* og3, const void* ob3, const void* ow3,
    const u16* __restrict__ o12g, const u16* __restrict__ a2g,
    float* __restrict__ x, float* __restrict__ S,
    u16* Wt, float* Cb, float* lds2)
{
  int tid = threadIdx.x;
  int wv = tid >> 6, lane = tid & 63;
  int ln15 = lane & 15, quad = lane >> 4;
  int gbase = blockIdx.x*1024;
  int shard = blockIdx.x & (NSH-1);
  int rowbase = wv*64;

  half8 fa[2][4], fo[2][4];
  P3_LOAD(0, 0)

  // L0 = 3O (stats S_A2), L1 = 3P (stats S_O12)
  fold2<F32>(S, S_A2, S_O12, og3,ob3,ow3, pg3,pb3,pw3, Wt, Cb, lds2);

  half8 w0s = *(const half8*)&Wt[(ln15     )*XSTR + quad*8];
  half8 w1s = *(const half8*)&Wt[(ln15 + 16)*XSTR + quad*8];
  half8 w0p = *(const half8*)&Wt[(32 + ln15     )*XSTR + quad*8];
  half8 w1p = *(const half8*)&Wt[(32 + ln15 + 16)*XSTR + quad*8];
  float b0s[4], b1s[4], b0p[4], b1p[4];
#pragma unroll
  for (int reg=0;reg<4;++reg){
    b0s[reg] = Cb[     quad*4 + reg]; b1s[reg] = Cb[16 + quad*4 + reg];
    b0p[reg] = Cb[32 + quad*4 + reg]; b1p[reg] = Cb[48 + quad*4 + reg];
  }

#pragma unroll
  for (int g=0; g<4; ++g){
    const int buf = g & 1;
    if (g < 3){ P3_LOAD(buf^1, g+1) }
    uint2 r0[4], r1[4];
#pragma unroll
    for (int Mt=0; Mt<4; ++Mt){
      size_t R = (size_t)(gbase + g*256 + rowbase + Mt*16 + ln15);
      r0[Mt] = *(const uint2*)&o12g[R*32 +      quad*4];
      r1[Mt] = *(const uint2*)&o12g[R*32 + 16 + quad*4];
    }
    int maskbase = gbase + g*256 + wv*64;
    u32 at_pk[16];
#pragma unroll
    for (int Mt=0; Mt<4; ++Mt){     // logits + softmax
      f32x4 c0 = {0.f,0.f,0.f,0.f}, c1 = {0.f,0.f,0.f,0.f};
      c0 = __builtin_amdgcn_mfma_f32_16x16x32_f16(w0s, fa[buf][Mt], c0, 0,0,0);
      c1 = __builtin_amdgcn_mfma_f32_16x16x32_f16(w1s, fa[buf][Mt], c1, 0,0,0);
      float l0[4], l1[4];
#pragma unroll
      for (int reg=0;reg<4;++reg){ l0[reg] = c0[reg]+b0s[reg]; l1[reg] = c1[reg]+b1s[reg]; }
      float mx = l0[0];
#pragma unroll
      for (int reg=1;reg<4;++reg) mx = fmaxf(mx, l0[reg]);
#pragma unroll
      for (int reg=0;reg<4;++reg) mx = fmaxf(mx, l1[reg]);
      mx = fmaxf(mx, __shfl_xor(mx, 16));
      mx = fmaxf(mx, __shfl_xor(mx, 32));
      float sum = 0.f;
#pragma unroll
      for (int reg=0;reg<4;++reg){ l0[reg] = __expf(l0[reg]-mx); sum += l0[reg]; }
#pragma unroll
      for (int reg=0;reg<4;++reg){ l1[reg] = __expf(l1[reg]-mx); sum += l1[reg]; }
      sum += __shfl_xor(sum, 16);
      sum += __shfl_xor(sum, 32);
      float inv = __builtin_amdgcn_rcpf(sum);
      bool mz = (mask[maskbase + Mt*16 + ln15] == 0);
#pragma unroll
      for (int reg=0;reg<4;++reg){
        l0[reg] *= inv; l1[reg] *= inv;
        if (mz){ l0[reg] = -__builtin_inff(); l1[reg] = -__builtin_inff(); }
      }
      at_pk[Mt*4+0] = pack2h(l0[0], l0[1]);
      at_pk[Mt*4+1] = pack2h(l0[2], l0[3]);
      at_pk[Mt*4+2] = pack2h(l1[0], l1[1]);
      at_pk[Mt*4+3] = pack2h(l1[2], l1[3]);
    }
    float ps[8];
#pragma unroll
    for (int i=0;i<8;++i) ps[i]=0.f;
#pragma unroll
    for (int Mt=0; Mt<4; ++Mt){     // (o3 + residual) * attn, pooled
      f32x4 c0 = {0.f,0.f,0.f,0.f}, c1 = {0.f,0.f,0.f,0.f};
      c0 = __builtin_amdgcn_mfma_f32_16x16x32_f16(w0p, fo[buf][Mt], c0, 0,0,0);
      c1 = __builtin_amdgcn_mfma_f32_16x16x32_f16(w1p, fo[buf][Mt], c1, 0,0,0);
      float o0[4], o1v[4];
      unpk4(r0[Mt], o0); unpk4(r1[Mt], o1v);
      float a0v[4], a1v[4];
      a0v[0]=lo16(at_pk[Mt*4+0]); a0v[1]=hi16(at_pk[Mt*4+0]);
      a0v[2]=lo16(at_pk[Mt*4+1]); a0v[3]=hi16(at_pk[Mt*4+1]);
      a1v[0]=lo16(at_pk[Mt*4+2]); a1v[1]=hi16(at_pk[Mt*4+2]);
      a1v[2]=lo16(at_pk[Mt*4+3]); a1v[3]=hi16(at_pk[Mt*4+3]);
#pragma unroll
      for (int reg=0;reg<4;++reg){
        float a = (o0[reg]  + tanh_fast(c0[reg]+b0p[reg])) * a0v[reg];
        float b = (o1v[reg] + tanh_fast(c1[reg]+b1p[reg])) * a1v[reg];
        ps[reg]   += a;
        ps[4+reg] += b;
      }
    }
#pragma unroll
    for (int i=0;i<8;++i) ps[i]=red16(ps[i]);
    __syncthreads();
    if (ln15 == 0){
#pragma unroll
      for (int rg=0; rg<4; ++rg){
        lds2[wv*32 + quad*4+rg]    = ps[rg];
        lds2[wv*32 + 16+quad*4+rg] = ps[4+rg];
      }
    }
    __syncthreads();
    if (tid < 64){
      int half = tid >> 5, j = tid & 31;
      float v = lds2[half*64 + j] + lds2[half*64 + 32 + j];
      x[((size_t)blockIdx.x*8 + g*2 + half)*32 + j] = v;
      float* Sh = S + shard*SHARD;
      atomicAdd(&Sh[S_X+j], v);
      atomicAdd(&Sh[S_X+32+j], v*v);
    }
  }
}
__global__ __launch_bounds__(256) void k_pass3m(const void* __restrict__ u, const int* __restrict__ mask,
    const void* pg3, const void* pb3, const void* pw3,
    const void* og3, const void* ob3, const void* ow3,
    const u16* o12g, const u16* a2g,
    float* __restrict__ x, float* __restrict__ S){
  __shared__ u16 Wt[2*32*XSTR];
  __shared__ float Cb[64];
  __shared__ float lds2[512];
  __shared__ int sf;
  int isf = detect_u((const u16*)u, threadIdx.x, &sf);
  if (isf) pass3m_body<true >(mask,pg3,pb3,pw3,og3,ob3,ow3,o12g,a2g,x,S,Wt,Cb,lds2);
  else     pass3m_body<false>(mask,pg3,pb3,pw3,og3,ob3,ow3,o12g,a2g,x,S,Wt,Cb,lds2);
}

// ---------------- pass3 (fallback, full recompute; grid 2048) ----------------
template<bool F32>
__device__ __forceinline__ void fold4(const float* __restrict__ S,
    int off0,int off1,int off2,int off3,
    const void* g0,const void* b0,const void* W0,
    const void* g1,const void* b1,const void* W1,
    const void* g2,const void* b2,const void* W2,
    const void* g3,const void* b3,const void* W3,
    u16* Wt, float* Cb, float* scr)
{
  int tid = threadIdx.x;
  __shared__ float scr2[256];
  if (tid < 128){
    int L = tid>>5, k = tid&31;
    const void* g = (L==0)?g0:(L==1)?g1:(L==2)?g2:g3;
    const void* b = (L==0)?b0:(L==1)?b1:(L==2)?b2:b3;
    int off = (L==0)?off0:(L==1)?off1:(L==2)?off2:off3;
    float s=0.f, q=0.f;
#pragma unroll
    for (int sh=0; sh<NSH; ++sh){
      s += S[sh*SHARD + off + k];
      q += S[sh*SHARD + off + 32 + k];
    }
    float m    = s*(1.0f/ROWS);
    float var  = q*(1.0f/ROWS) - m*m;
    float rstd = rsqrtf(var+EPS);
    float sc = rdp<F32>(g,k)*rstd;
    scr[tid]  = sc;
    scr2[tid] = rdp<F32>(b,k) - m*sc;
  }
  __syncthreads();
  if (tid < 128){
    int L = tid>>5, j = tid&31;
    const void* W = (L==0)?W0:(L==1)?W1:(L==2)?W2:W3;
    float c = 0.f;
#pragma unroll
    for (int k=0;k<32;++k){
      float Wv = rdp<F32>(W, j*32+k);
      Wt[(L*32+j)*XSTR + k] = f2h(Wv * scr[(L<<5)|k]);
      c += Wv * scr2[(L<<5)|k];
    }
    Cb[L*32+j] = c;
  }
  __syncthreads();
}

template<bool F32>
__device__ __forceinline__ void pass3_body(const void* __restrict__ u, const int* __restrict__ mask,
    const void* pg1, const void* pb1, const void* pw1,
    const void* og1, const void* ob1, const void* ow1,
    const void* pg2, const void* pb2, const void* pw2,
    const void* og2, const void* ob2, const void* ow2,
    const void* pg3, const void* pb3, const void* pw3,
    const void* og3, const void* ob3, const void* ow3,
    float* __restrict__ x, float* __restrict__ S,
    u16* X, u16* Wt, float* Cb, float* red2, float* mr)
{
  int tid = threadIdx.x;
  int wv = tid >> 6, lane = tid & 63;
  int r = blockIdx.x*256 + tid;
  float f[4], xn[4];
  load_u4<F32>(u,r,f);
  prep_u_par(S, mr, red2, tid);
  fold4<F32>(S, S_A1, S_A2, S_O1, S_O12,
             og2,ob2,ow2, og3,ob3,ow3, pg2,pb2,pw2, pg3,pb3,pw3,
             Wt, Cb, red2);

  u32 at_pk[16];
  int maskbase = blockIdx.x*256 + wv*64;

  bn_u_l<F32>(mr, og1, ob1, f, xn);
  chain1_out<F32,false>(xn, ow1, X + tid*XSTR, 0);
  mfma_layer<KIND_TANH>(X, Wt, Cb, 0, wv, lane, 0);
  {
    int ln15 = lane & 15, quad = lane >> 4;
    half8 w0 = *(const half8*)&Wt[(1*32 + ln15     )*XSTR + quad*8];
    half8 w1 = *(const half8*)&Wt[(1*32 + ln15 + 16)*XSTR + quad*8];
    float bias0[4], bias1[4];
#pragma unroll
    for (int reg=0;reg<4;++reg){
      bias0[reg] = Cb[32 +      quad*4 + reg];
      bias1[reg] = Cb[32 + 16 + quad*4 + reg];
    }
    int rowbase = wv*64;
#pragma unroll
    for (int Mt=0; Mt<4; ++Mt){
      int s = rowbase + Mt*16 + ln15;
      half8 bfr = *(const half8*)&X[s*XSTR + quad*8];
      f32x4 c0 = {0.f,0.f,0.f,0.f}, c1 = {0.f,0.f,0.f,0.f};
      c0 = __builtin_amdgcn_mfma_f32_16x16x32_f16(w0, bfr, c0, 0,0,0);
      c1 = __builtin_amdgcn_mfma_f32_16x16x32_f16(w1, bfr, c1, 0,0,0);
      float l0[4], l1[4];
#pragma unroll
      for (int reg=0;reg<4;++reg){ l0[reg] = c0[reg]+bias0[reg]; l1[reg] = c1[reg]+bias1[reg]; }
      float mx = l0[0];
#pragma unroll
      for (int reg=1;reg<4;++reg) mx = fmaxf(mx, l0[reg]);
#pragma unroll
      for (int reg=0;reg<4;++reg) mx = fmaxf(mx, l1[reg]);
      mx = fmaxf(mx, __shfl_xor(mx, 16));
      mx = fmaxf(mx, __shfl_xor(mx, 32));
      float sum = 0.f;
#pragma unroll
      for (int reg=0;reg<4;++reg){ l0[reg] = __expf(l0[reg]-mx); sum += l0[reg]; }
#pragma unroll
      for (int reg=0;reg<4;++reg){ l1[reg] = __expf(l1[reg]-mx); sum += l1[reg]; }
      sum += __shfl_xor(sum, 16);
      sum += __shfl_xor(sum, 32);
      float inv = __builtin_amdgcn_rcpf(sum);
      bool mz = (mask[maskbase + Mt*16 + ln15] == 0);
#pragma unroll
      for (int reg=0;reg<4;++reg){
        l0[reg] *= inv; l1[reg] *= inv;
        if (mz){ l0[reg] = -__builtin_inff(); l1[reg] = -__builtin_inff(); }
      }
      at_pk[Mt*4+0] = pack2h(l0[0], l0[1]);
      at_pk[Mt*4+1] = pack2h(l0[2], l0[3]);
      at_pk[Mt*4+2] = pack2h(l1[0], l1[1]);
      at_pk[Mt*4+3] = pack2h(l1[2], l1[3]);
    }
  }

  bn_u_l<F32>(mr, pg1, pb1, f, xn);
  chain1_out<F32,false>(xn, pw1, X + tid*XSTR, 0);
  mfma_layer<KIND_TANHRES   >(X, Wt, Cb, 2, wv, lane, 0);
  mfma_layer<KIND_TANHRES_ATREG>(X, Wt, Cb, 3, wv, lane, at_pk);

  __syncthreads();
  {
    int jj = tid & 31, cgrp = (tid >> 5) & 3, half = tid >> 7;
    float s2 = 0.f;
#pragma unroll
    for (int q2=0;q2<32;++q2) s2 += h2f(X[(half*128 + cgrp*32 + q2)*XSTR + jj]);
    red2[tid] = s2;
  }
  __syncthreads();
  if (tid < 64){
    int half = tid >> 5, j = tid & 31;
    float v = red2[half*128+j] + red2[half*128+32+j] + red2[half*128+64+j] + red2[half*128+96+j];
    x[(blockIdx.x*2 + half)*32 + j] = v;
    float* Sh = S + (blockIdx.x & (NSH-1))*SHARD;
    atomicAdd(&Sh[S_X+j], v);
    atomicAdd(&Sh[S_X+32+j], v*v);
  }
}
__global__ __launch_bounds__(256) void k_pass3(const void* __restrict__ u, const int* __restrict__ mask,
    const void* pg1, const void* pb1, const void* pw1,
    const void* og1, const void* ob1, const void* ow1,
    const void* pg2, const void* pb2, const void* pw2,
    const void* og2, const void* ob2, const void* ow2,
    const void* pg3, const void* pb3, const void* pw3,
    const void* og3, const void* ob3, const void* ow3,
    float* __restrict__ x, float* __restrict__ S){
  __shared__ u16 X [256*XSTR];
  __shared__ u16 Wt[4*32*XSTR];
  __shared__ float Cb[128];
  __shared__ float red2[256];
  __shared__ float mr[8];
  __shared__ int sf;
  int isf = detect_u((const u16*)u, threadIdx.x, &sf);
  if (isf) pass3_body<true >(u,mask,pg1,pb1,pw1,og1,ob1,ow1,pg2,pb2,pw2,og2,ob2,ow2,
                             pg3,pb3,pw3,og3,ob3,ow3,x,S,X,Wt,Cb,red2,mr);
  else     pass3_body<false>(u,mask,pg1,pb1,pw1,og1,ob1,ow1,pg2,pb2,pw2,og2,ob2,ow2,
                             pg3,pb3,pw3,og3,ob3,ow3,x,S,X,Wt,Cb,red2,mr);
}

// ---------------- theta chain: 4 small stream-ordered kernels ----------------
template<int NSH_IN>
__device__ __forceinline__ void theta_gather(const float* __restrict__ S, int off,
                                             float* scratch, float* lds2, int tid){
  int col = tid & 63, grp = tid >> 6;
  float t = 0.f;
#pragma unroll
  for (int i = 0; i < NSH_IN/4; ++i)
    t += S[(grp + i*4)*SHARD + off + col];
  scratch[tid] = t;
  __syncthreads();
  if (tid < 64)
    scratch[tid] = scratch[tid] + scratch[64+tid] + scratch[128+tid] + scratch[192+tid];
  __syncthreads();
  if (tid < 32){
    float m   = scratch[tid]*(1.0f/BROWS);
    float var = scratch[32+tid]*(1.0f/BROWS) - m*m;
    lds2[tid]    = m;
    lds2[32+tid] = rsqrtf(var + EPS);
  }
  __syncthreads();
}

template<bool F32>
__device__ __forceinline__ void theta_layer(float* v, const float* lds2,
    const void* g, const void* b, const void* W){
  float xn[32];
#pragma unroll
  for (int k=0;k<32;++k)
    xn[k] = (v[k] - lds2[k]) * (rdp<F32>(g,k)*lds2[32+k]) + rdp<F32>(b,k);
#pragma unroll
  for (int j=0;j<32;++j){
    float acc = 0.f;
#pragma unroll
    for (int k=0;k<32;++k) acc = fmaf(rdp<F32>(W, j*32+k), xn[k], acc);
    v[j] = tanh_fast(acc);
  }
}

template<bool F32, int NSH_IN>
__device__ __forceinline__ void theta_L_body(const float* __restrict__ xin,
    float* __restrict__ xout, float* __restrict__ S, int off_in, int off_out,
    const void* g, const void* b, const void* W, float* lds, float* lds2)
{
  int tid = threadIdx.x, blk = blockIdx.x;
  int r = blk*256 + tid;
  float v[32];
  {
    const float4* xr = (const float4*)&xin[(size_t)r*32];
#pragma unroll
    for (int k=0;k<8;++k){ float4 t = xr[k]; v[4*k]=t.x; v[4*k+1]=t.y; v[4*k+2]=t.z; v[4*k+3]=t.w; }
  }
  theta_gather<NSH_IN>(S, off_in, lds, lds2, tid);
  theta_layer<F32>(v, lds2, g, b, W);
  {
    float4* xw = (float4*)&xout[(size_t)r*32];
#pragma unroll
    for (int k=0;k<8;++k){ float4 t; t.x=v[4*k]; t.y=v[4*k+1]; t.z=v[4*k+2]; t.w=v[4*k+3]; xw[k]=t; }
  }
  float* Xp = lds + tid*33;
#pragma unroll
  for (int j=0;j<32;++j) Xp[j] = v[j];
  reduce_f32(lds, lds2, S, off_out, blk);   // shard = blk: zero contention
}
template<int NSH_IN>
__global__ __launch_bounds__(256) void k_theta_L(const void* __restrict__ u,
    const float* __restrict__ xin, float* __restrict__ xout,
    float* __restrict__ S, int off_in, int off_out,
    const void* g, const void* b, const void* W){
  __shared__ float lds[256*33];
  __shared__ float lds2[512];
  __shared__ int sf;
  int isf = detect_u((const u16*)u, threadIdx.x, &sf);
  if (isf) theta_L_body<true , NSH_IN>(xin, xout, S, off_in, off_out, g, b, W, lds, lds2);
  else     theta_L_body<false, NSH_IN>(xin, xout, S, off_in, off_out, g, b, W, lds, lds2);
}

template<bool F32>
__device__ __forceinline__ void theta_fin_body(const float* __restrict__ xin,
    float* __restrict__ S,
    const void* g4, const void* b4, const void* w4, const void* bb4,
    void* out, float* lds, float* lds2)
{
  int tid = threadIdx.x, blk = blockIdx.x;
  int r = blk*256 + tid;
  const float4* xr = (const float4*)&xin[(size_t)r*32];
  float4 t0 = xr[0], t1 = xr[1], t2 = xr[2], t3 = xr[3];
  float4 t4 = xr[4], t5 = xr[5], t6 = xr[6], t7 = xr[7];
  theta_gather<16>(S, S_X3, lds, lds2, tid);
  float vv[32];
  vv[0]=t0.x; vv[1]=t0.y; vv[2]=t0.z; vv[3]=t0.w;
  vv[4]=t1.x; vv[5]=t1.y; vv[6]=t1.z; vv[7]=t1.w;
  vv[8]=t2.x; vv[9]=t2.y; vv[10]=t2.z; vv[11]=t2.w;
  vv[12]=t3.x; vv[13]=t3.y; vv[14]=t3.z; vv[15]=t3.w;
  vv[16]=t4.x; vv[17]=t4.y; vv[18]=t4.z; vv[19]=t4.w;
  vv[20]=t5.x; vv[21]=t5.y; vv[22]=t5.z; vv[23]=t5.w;
  vv[24]=t6.x; vv[25]=t6.y; vv[26]=t6.z; vv[27]=t6.w;
  vv[28]=t7.x; vv[29]=t7.y; vv[30]=t7.z; vv[31]=t7.w;
  float acc = rdp<F32>(bb4, 0);
#pragma unroll
  for (int k=0;k<32;++k){
    float xnv = (vv[k] - lds2[k]) * (rdp<F32>(g4,k)*lds2[32+k]) + rdp<F32>(b4,k);
    acc = fmaf(rdp<F32>(w4,k), xnv, acc);
  }
  if (F32) ((float*)out)[r] = acc;
  else     ((u16*)out)[r]  = f2b(acc);
}
__global__ __launch_bounds__(256) void k_theta_fin(const void* __restrict__ u,
    const float* __restrict__ xin, float* __restrict__ S,
    const void* g4, const void* b4, const void* w4, const void* bb4,
    void* out){
  __shared__ float lds[256];
  __shared__ float lds2[512];
  __shared__ int sf;
  int isf = detect_u((const u16*)u, threadIdx.x, &sf);
  if (isf) theta_fin_body<true >(xin, S, g4, b4, w4, bb4, out, lds, lds2);
  else     theta_fin_body<false>(xin, S, g4, b4, w4, bb4, out, lds, lds2);
}

extern "C" void kernel_launch(void* const* d_in, const int* in_sizes, int n_in,
                              void* d_out, int out_size, void* d_ws, size_t ws_size,
                              hipStream_t stream)
{
  const void* u    = d_in[0];
  const int*  mask = (const int*)d_in[1];
  const void *pg1=d_in[2],  *pb1=d_in[3],  *pw1=d_in[4];
  const void *pg2=d_in[5],  *pb2=d_in[6],  *pw2=d_in[7];
  const void *pg3=d_in[8],  *pb3=d_in[9],  *pw3=d_in[10];
  const void *og1=d_in[11], *ob1=d_in[12], *ow1=d_in[13];
  const void *og2=d_in[14], *ob2=d_in[15], *ow2=d_in[16];
  const void *og3=d_in[17], *ob3=d_in[18], *ow3=d_in[19];
  const void *tg1=d_in[20], *tb1=d_in[21], *tw1=d_in[22];
  const void *tg2=d_in[23], *tb2=d_in[24], *tw2=d_in[25];
  const void *tg3=d_in[26], *tb3=d_in[27], *tw3=d_in[28];
  const void *tg4=d_in[29], *tb4=d_in[30], *tw4=d_in[31], *tbb4=d_in[32];

  char* ws = (char*)d_ws;
  float* S    = (float*)(ws + 4096);         // 64 shards x 1024 floats = 256 KB
  float* x    = (float*)(ws + 524288);       // 4096*32 f32 (512 KB)
  float* xb   = (float*)(ws + 1048576);      // ping-pong buffer (512 KB)

  const size_t MB = 1024*1024;
  u16* o12g = (u16*)(ws + 8*MB);             // 32 MB: o1 then (in-place) o12
  u16* a2g  = (u16*)(ws + 40*MB);            // 32 MB: a1 then (in-place) a2
  bool MAT = ws_size >= 73*MB;               // constant per process -> graph-safe

  (void)hipMemsetAsync(ws, 0, 4096 + NSH*SHARD*4, stream);  // zero sharded stats
  k_stats_u<<<1024, 256, 0, stream>>>(u, S);
  if (MAT){
    k_pass1<true ><<<512, 256, 0, stream>>>(u, pg1,pb1,pw1, og1,ob1,ow1, S, o12g, a2g);
    k_pass2m<<<512, 256, 0, stream>>>(u, pg2,pb2,pw2, og2,ob2,ow2, S, o12g, a2g);
    k_pass3m<<<512, 256, 0, stream>>>(u, mask, pg3,pb3,pw3, og3,ob3,ow3, o12g, a2g, x, S);
  } else {
    k_pass1<false><<<512, 256, 0, stream>>>(u, pg1,pb1,pw1, og1,ob1,ow1, S, o12g, a2g);
    k_pass2<<<2048, 256, 0, stream>>>(u, pg1,pb1,pw1, og1,ob1,ow1,
                                      pg2,pb2,pw2, og2,ob2,ow2, S);
    k_pass3<<<2048, 256, 0, stream>>>(u, mask, pg1,pb1,pw1, og1,ob1,ow1,
                                      pg2,pb2,pw2, og2,ob2,ow2,
                                      pg3,pb3,pw3, og3,ob3,ow3, x, S);
  }
  // theta chain: 4 tiny kernels; stream order supplies the global sync
  k_theta_L<64><<<16, 256, 0, stream>>>(u, x,  xb, S, S_X,  S_X1, tg1, tb1, tw1);
  k_theta_L<16><<<16, 256, 0, stream>>>(u, xb, x,  S, S_X1, S_X2, tg2, tb2, tw2);
  k_theta_L<16><<<16, 256, 0, stream>>>(u, x,  xb, S, S_X2, S_X3, tg3, tb3, tw3);
  k_theta_fin<<<16, 256, 0, stream>>>(u, xb, S, tg4, tb4, tw4, tbb4, d_out);
}